// Round 1
// baseline (2792.548 us; speedup 1.0000x reference)
//
#include <hip/hip_runtime.h>

// ---------------------------------------------------------------------------
// Encoder: 3-layer HeteroGraphConv(3 edge types) -> FC -> ReLU -> BatchNorm
// Strategy:
//   * build dst-CSR once per launch (int atomics + 3-kernel scan)
//   * per layer, per type: aggregate (pure gather, wave-per-node) -> z
//     then fp32 GEMM z @ W_e accumulated into gcout
//   * FC GEMM fused with ReLU + BN partial stats; BN finalize + apply
// ---------------------------------------------------------------------------

#define EPSV 1e-5f

// ---------------- degree counting ----------------
__global__ void deg_kernel(const int* __restrict__ src, const int* __restrict__ dst,
                           int* __restrict__ dout, int* __restrict__ din,
                           int E, int N, int total) {
    int i = blockIdx.x * 256 + threadIdx.x;
    if (i >= total) return;
    int t = i / E;
    atomicAdd(&dout[t * N + src[i]], 1);
    atomicAdd(&din[t * N + dst[i]], 1);
}

__global__ void rsqrt_kernel(const int* __restrict__ dout, const int* __restrict__ din,
                             float* __restrict__ dro, float* __restrict__ dri, int total) {
    int i = blockIdx.x * 256 + threadIdx.x;
    if (i >= total) return;
    int a = dout[i]; if (a < 1) a = 1;
    int b = din[i];  if (b < 1) b = 1;
    dro[i] = rsqrtf((float)a);
    dri[i] = rsqrtf((float)b);
}

// ---------------- prefix scan (3 kernels) for CSR row pointers -------------
__global__ void scan1_kernel(const int* __restrict__ din, int* __restrict__ csum,
                             int N, int nch) {
    __shared__ int s[256];
    int t = blockIdx.x / nch, c = blockIdx.x % nch;
    int idx = c * 256 + threadIdx.x;
    s[threadIdx.x] = (idx < N) ? din[t * N + idx] : 0;
    __syncthreads();
    for (int off = 128; off > 0; off >>= 1) {
        if (threadIdx.x < off) s[threadIdx.x] += s[threadIdx.x + off];
        __syncthreads();
    }
    if (threadIdx.x == 0) csum[blockIdx.x] = s[0];
}

__global__ void scan2_kernel(const int* __restrict__ csum, int* __restrict__ coff,
                             int* __restrict__ rowptr, int N, int nch) {
    int t = threadIdx.x;
    if (t >= 3) return;
    int base = 0;
    for (int c = 0; c < nch; ++c) {
        int i = t * nch + c;
        coff[i] = base;
        base += csum[i];
    }
    rowptr[t * (N + 1) + N] = base;
}

__global__ void scan3_kernel(const int* __restrict__ din, const int* __restrict__ coff,
                             int* __restrict__ rowptr, int N, int nch) {
    __shared__ int s[256];
    int t = blockIdx.x / nch, c = blockIdx.x % nch;
    int idx = c * 256 + threadIdx.x;
    int v = (idx < N) ? din[t * N + idx] : 0;
    s[threadIdx.x] = v;
    __syncthreads();
    for (int off = 1; off < 256; off <<= 1) {
        int add = (threadIdx.x >= off) ? s[threadIdx.x - off] : 0;
        __syncthreads();
        s[threadIdx.x] += add;
        __syncthreads();
    }
    if (idx < N) rowptr[t * (N + 1) + idx] = coff[blockIdx.x] + s[threadIdx.x] - v;
}

__global__ void fill_kernel(const int* __restrict__ src, const int* __restrict__ dst,
                            const int* __restrict__ rowptr, int* __restrict__ cursor,
                            int* __restrict__ esrc, int E, int N, int total) {
    int i = blockIdx.x * 256 + threadIdx.x;
    if (i >= total) return;
    int t = i / E;
    int d = dst[i];
    int slot = atomicAdd(&cursor[t * N + d], 1);
    esrc[(size_t)t * E + rowptr[t * (N + 1) + d] + slot] = src[i];
}

// ---------------- aggregation: z[d] = rsqrt(din[d]) * sum_e dro[s]*h[s] ----
__launch_bounds__(256)
__global__ void agg_kernel(const float* __restrict__ h, const int* __restrict__ rowptr,
                           const int* __restrict__ esrc, const float* __restrict__ dro,
                           const float* __restrict__ dri, float* __restrict__ z, int N) {
    int gw = (blockIdx.x * 256 + threadIdx.x) >> 6;   // wave id = dst node
    int lane = threadIdx.x & 63;
    if (gw >= N) return;
    int beg = rowptr[gw], end = rowptr[gw + 1];
    float ax = 0.f, ay = 0.f;
    int j = beg;
    for (; j + 4 <= end; j += 4) {
        int s0 = esrc[j], s1 = esrc[j + 1], s2 = esrc[j + 2], s3 = esrc[j + 3];
        float w0 = dro[s0], w1 = dro[s1], w2 = dro[s2], w3 = dro[s3];
        float2 v0 = *(const float2*)(h + (size_t)s0 * 128 + lane * 2);
        float2 v1 = *(const float2*)(h + (size_t)s1 * 128 + lane * 2);
        float2 v2 = *(const float2*)(h + (size_t)s2 * 128 + lane * 2);
        float2 v3 = *(const float2*)(h + (size_t)s3 * 128 + lane * 2);
        ax += w0 * v0.x + w1 * v1.x + w2 * v2.x + w3 * v3.x;
        ay += w0 * v0.y + w1 * v1.y + w2 * v2.y + w3 * v3.y;
    }
    for (; j < end; ++j) {
        int s0 = esrc[j];
        float w0 = dro[s0];
        float2 v0 = *(const float2*)(h + (size_t)s0 * 128 + lane * 2);
        ax += w0 * v0.x;
        ay += w0 * v0.y;
    }
    float sc = dri[gw];
    *(float2*)(z + (size_t)gw * 128 + lane * 2) = make_float2(ax * sc, ay * sc);
}

// ---------------- fp32 GEMM  C[M,128] (op)= A[M,128] @ B[128,128] ----------
// MODE 0: C  = A@B + (b0+b1+b2)          (first edge type)
// MODE 1: C += A@B                        (accumulate edge types)
// MODE 2: C  = relu(A@B + b0), bnsum[c] += col sums, bnsum[128+c] += col sumsq
template <int MODE>
__launch_bounds__(256, 2)
__global__ void gemm128(const float* __restrict__ A, const float* __restrict__ Bm,
                        const float* __restrict__ b0, const float* __restrict__ b1,
                        const float* __restrict__ b2, float* __restrict__ C,
                        float* __restrict__ bnsum, int M) {
    __shared__ float Ast[32][132];   // transposed A tile: Ast[k][m], padded
    __shared__ float Bs[32][132];    // B tile: Bs[k][n], padded
    __shared__ float red[256];       // MODE 2 column reduce

    const int tid = threadIdx.x;
    const int m0 = blockIdx.x * 128;
    const int rg = tid >> 4, cg = tid & 15;
    const int row = rg * 8, col = cg * 8;

    float acc[8][8] = {};

    for (int k0 = 0; k0 < 128; k0 += 32) {
        // stage global loads in regs (overlaps previous compute)
        float4 av[4];
        int ar[4], ac[4];
#pragma unroll
        for (int i = 0; i < 4; ++i) {
            int fi = i * 256 + tid;      // 0..1023
            int r = fi >> 3;             // 0..127
            int c4 = (fi & 7) * 4;       // 0,4,..28
            ar[i] = r; ac[i] = c4;
            int gr = m0 + r;
            av[i] = (gr < M) ? *(const float4*)(A + (size_t)gr * 128 + k0 + c4)
                             : make_float4(0.f, 0.f, 0.f, 0.f);
        }
        float4 bv[4];
#pragma unroll
        for (int i = 0; i < 4; ++i) {
            int fi = i * 256 + tid;
            int kr = fi >> 5;            // 0..31
            int c4 = (fi & 31) * 4;      // 0..124
            bv[i] = *(const float4*)(Bm + (size_t)(k0 + kr) * 128 + c4);
        }
        __syncthreads();
#pragma unroll
        for (int i = 0; i < 4; ++i) {
            Ast[ac[i] + 0][ar[i]] = av[i].x;
            Ast[ac[i] + 1][ar[i]] = av[i].y;
            Ast[ac[i] + 2][ar[i]] = av[i].z;
            Ast[ac[i] + 3][ar[i]] = av[i].w;
        }
#pragma unroll
        for (int i = 0; i < 4; ++i) {
            int fi = i * 256 + tid;
            int kr = fi >> 5;
            int c4 = (fi & 31) * 4;
            *(float4*)&Bs[kr][c4] = bv[i];
        }
        __syncthreads();
#pragma unroll
        for (int k = 0; k < 32; ++k) {
            float4 a0 = *(const float4*)&Ast[k][row];
            float4 a1 = *(const float4*)&Ast[k][row + 4];
            float4 p0 = *(const float4*)&Bs[k][col];
            float4 p1 = *(const float4*)&Bs[k][col + 4];
            float a[8] = {a0.x, a0.y, a0.z, a0.w, a1.x, a1.y, a1.z, a1.w};
            float b[8] = {p0.x, p0.y, p0.z, p0.w, p1.x, p1.y, p1.z, p1.w};
#pragma unroll
            for (int r = 0; r < 8; ++r)
#pragma unroll
                for (int c = 0; c < 8; ++c)
                    acc[r][c] += a[r] * b[c];
        }
        __syncthreads();
    }

    if (MODE == 0) {
        float badd[8];
#pragma unroll
        for (int c = 0; c < 8; ++c) badd[c] = b0[col + c] + b1[col + c] + b2[col + c];
#pragma unroll
        for (int r = 0; r < 8; ++r) {
            int gr = m0 + row + r;
            if (gr < M) {
                float* cp = C + (size_t)gr * 128 + col;
                float4 v0 = {acc[r][0] + badd[0], acc[r][1] + badd[1],
                             acc[r][2] + badd[2], acc[r][3] + badd[3]};
                float4 v1 = {acc[r][4] + badd[4], acc[r][5] + badd[5],
                             acc[r][6] + badd[6], acc[r][7] + badd[7]};
                *(float4*)cp = v0;
                *(float4*)(cp + 4) = v1;
            }
        }
    } else if (MODE == 1) {
#pragma unroll
        for (int r = 0; r < 8; ++r) {
            int gr = m0 + row + r;
            if (gr < M) {
                float* cp = C + (size_t)gr * 128 + col;
                float4 o0 = *(float4*)cp;
                float4 o1 = *(float4*)(cp + 4);
                o0.x += acc[r][0]; o0.y += acc[r][1]; o0.z += acc[r][2]; o0.w += acc[r][3];
                o1.x += acc[r][4]; o1.y += acc[r][5]; o1.z += acc[r][6]; o1.w += acc[r][7];
                *(float4*)cp = o0;
                *(float4*)(cp + 4) = o1;
            }
        }
    } else {  // MODE 2: FC + ReLU + BN partial stats
        float bias[8];
#pragma unroll
        for (int c = 0; c < 8; ++c) bias[c] = b0[col + c];
        float cs[8] = {}, cq[8] = {};
#pragma unroll
        for (int r = 0; r < 8; ++r) {
            int gr = m0 + row + r;
            if (gr < M) {
                float v[8];
#pragma unroll
                for (int c = 0; c < 8; ++c) {
                    float t = acc[r][c] + bias[c];
                    v[c] = t > 0.f ? t : 0.f;
                    cs[c] += v[c];
                    cq[c] += v[c] * v[c];
                }
                float* cp = C + (size_t)gr * 128 + col;
                float4 v0 = {v[0], v[1], v[2], v[3]};
                float4 v1 = {v[4], v[5], v[6], v[7]};
                *(float4*)cp = v0;
                *(float4*)(cp + 4) = v1;
            }
        }
        red[tid] = 0.f;
        __syncthreads();
#pragma unroll
        for (int c = 0; c < 8; ++c) {
            atomicAdd(&red[col + c], cs[c]);
        }
        __syncthreads();
        // red[0..127] = col sums; now sumsq via second pass
        float sred = red[tid & 127];  // hold
        __syncthreads();
        red[tid] = 0.f;
        __syncthreads();
#pragma unroll
        for (int c = 0; c < 8; ++c) {
            atomicAdd(&red[col + c], cq[c]);
        }
        __syncthreads();
        if (tid < 128) {
            atomicAdd(&bnsum[tid], sred);
            atomicAdd(&bnsum[128 + tid], red[tid]);
        }
    }
}

// ---------------- BN finalize + apply ----------------
__global__ void bn_fin(const float* __restrict__ bnsum, const float* __restrict__ gamma,
                       const float* __restrict__ beta, float* __restrict__ ss, int N) {
    int c = threadIdx.x;
    if (c >= 128) return;
    float invn = 1.0f / (float)N;
    float mean = bnsum[c] * invn;
    float var = bnsum[128 + c] * invn - mean * mean;
    float inv = rsqrtf(var + EPSV);
    float sc = gamma[c] * inv;
    ss[c] = sc;
    ss[128 + c] = beta[c] - mean * sc;
}

__global__ void bn_apply(float* __restrict__ h, const float* __restrict__ ss, int total4) {
    int i = blockIdx.x * 256 + threadIdx.x;
    if (i >= total4) return;
    int c4 = (i & 31) * 4;
    float4 sc = *(const float4*)&ss[c4];
    float4 sh = *(const float4*)&ss[128 + c4];
    float4 v = ((float4*)h)[i];
    v.x = v.x * sc.x + sh.x;
    v.y = v.y * sc.y + sh.y;
    v.z = v.z * sc.z + sh.z;
    v.w = v.w * sc.w + sh.w;
    ((float4*)h)[i] = v;
}

// ---------------------------------------------------------------------------
extern "C" void kernel_launch(void* const* d_in, const int* in_sizes, int n_in,
                              void* d_out, int out_size, void* d_ws, size_t ws_size,
                              hipStream_t stream) {
    const float* x    = (const float*)d_in[0];
    const int*   src  = (const int*)d_in[1];
    const int*   dst  = (const int*)d_in[2];
    const float* gcW0 = (const float*)d_in[3];
    const float* gcb0 = (const float*)d_in[4];
    const float* gcW  = (const float*)d_in[5];
    const float* gcb  = (const float*)d_in[6];
    const float* fcW  = (const float*)d_in[7];
    const float* fcb  = (const float*)d_in[8];
    const float* bng  = (const float*)d_in[9];
    const float* bnb  = (const float*)d_in[10];
    float* out = (float*)d_out;

    const int N = in_sizes[0] / 128;
    const int E = in_sizes[1] / 3;
    const int nch = (N + 255) / 256;
    const int totE = 3 * E;

    char* w = (char*)d_ws;
    auto alloc = [&](size_t bytes) -> char* {
        char* p = w;
        w += (bytes + 255) & ~(size_t)255;
        return p;
    };
    float* z      = (float*)alloc((size_t)N * 128 * 4);
    float* gcout  = (float*)alloc((size_t)N * 128 * 4);
    float* hA     = (float*)alloc((size_t)N * 128 * 4);
    float* dro    = (float*)alloc((size_t)3 * N * 4);
    float* dri    = (float*)alloc((size_t)3 * N * 4);
    int*   dout_i = (int*)alloc((size_t)3 * N * 4);
    int*   din_i  = (int*)alloc((size_t)3 * N * 4);
    int*   rowptr = (int*)alloc((size_t)3 * (N + 1) * 4);
    int*   cursor = (int*)alloc((size_t)3 * N * 4);
    int*   esrc   = (int*)alloc((size_t)3 * E * 4);
    int*   csum   = (int*)alloc((size_t)3 * nch * 4);
    int*   coff   = (int*)alloc((size_t)3 * nch * 4);
    float* bnsum  = (float*)alloc(256 * 4);
    float* ss     = (float*)alloc(256 * 4);

    // ---- CSR build (once; graph topology constant across layers) ----
    hipMemsetAsync(dout_i, 0, (size_t)3 * N * 4, stream);
    hipMemsetAsync(din_i, 0, (size_t)3 * N * 4, stream);
    hipMemsetAsync(cursor, 0, (size_t)3 * N * 4, stream);

    deg_kernel<<<(totE + 255) / 256, 256, 0, stream>>>(src, dst, dout_i, din_i, E, N, totE);
    rsqrt_kernel<<<(3 * N + 255) / 256, 256, 0, stream>>>(dout_i, din_i, dro, dri, 3 * N);
    scan1_kernel<<<3 * nch, 256, 0, stream>>>(din_i, csum, N, nch);
    scan2_kernel<<<1, 64, 0, stream>>>(csum, coff, rowptr, N, nch);
    scan3_kernel<<<3 * nch, 256, 0, stream>>>(din_i, coff, rowptr, N, nch);
    fill_kernel<<<(totE + 255) / 256, 256, 0, stream>>>(src, dst, rowptr, cursor, esrc, E, N, totE);

    // ---- layers ----
    const int gemmGrid = (N + 127) / 128;
    const int aggGrid = (N * 64 + 255) / 256;
    const float* hin = x;
    float* hnext[3] = {hA, out, out};

    for (int l = 0; l < 3; ++l) {
        const float* Wl = (l == 0) ? gcW0 : gcW + (size_t)(l - 1) * 3 * 128 * 128;
        const float* bl = (l == 0) ? gcb0 : gcb + (size_t)(l - 1) * 3 * 128;
        for (int e = 0; e < 3; ++e) {
            agg_kernel<<<aggGrid, 256, 0, stream>>>(hin, rowptr + e * (N + 1),
                                                    esrc + (size_t)e * E, dro + e * N,
                                                    dri + e * N, z, N);
            if (e == 0)
                gemm128<0><<<gemmGrid, 256, 0, stream>>>(z, Wl, bl, bl + 128, bl + 256,
                                                         gcout, nullptr, N);
            else
                gemm128<1><<<gemmGrid, 256, 0, stream>>>(z, Wl + (size_t)e * 128 * 128,
                                                         nullptr, nullptr, nullptr,
                                                         gcout, nullptr, N);
        }
        hipMemsetAsync(bnsum, 0, 256 * 4, stream);
        gemm128<2><<<gemmGrid, 256, 0, stream>>>(gcout, fcW + (size_t)l * 128 * 128,
                                                 fcb + (size_t)l * 128, nullptr, nullptr,
                                                 hnext[l], bnsum, N);
        bn_fin<<<1, 128, 0, stream>>>(bnsum, bng + (size_t)l * 128, bnb + (size_t)l * 128, ss, N);
        bn_apply<<<(N * 32 + 255) / 256, 256, 0, stream>>>(hnext[l], ss, N * 32);
        hin = hnext[l];
    }
}

// Round 2
// 2478.031 us; speedup vs baseline: 1.1269x; 1.1269x over previous
//
#include <hip/hip_runtime.h>

// ---------------------------------------------------------------------------
// Encoder: 3-layer HeteroGraphConv(3 edge types) -> FC -> ReLU -> BatchNorm
// Round 2:
//   * fused bucket CSR build (2 atomics/edge, no scan) w/ compact fallback
//   * agg: half-wave (32 lanes) per node, float4 gathers, 2 nodes/wave
//   * BN affine folded into next layer's aggregation (saves 2 bn_apply)
// ---------------------------------------------------------------------------

#define EPSV 1e-5f
#define BK 48   // bucket capacity; Poisson(16) tail => overflow prob ~1e-5 total

// ---------------- fused degree + bucket fill (bucket path) -----------------
__global__ void fill_bucket(const int* __restrict__ src, const int* __restrict__ dst,
                            int* __restrict__ dout, int* __restrict__ cnt,
                            int* __restrict__ esrcB, int E, int N) {
    int i = blockIdx.x * 256 + threadIdx.x;
    int t = blockIdx.y;
    if (i >= E) return;
    int s = src[(size_t)t * E + i];
    int d = dst[(size_t)t * E + i];
    atomicAdd(&dout[t * N + s], 1);
    int slot = atomicAdd(&cnt[t * N + d], 1);
    if (slot < BK) esrcB[((size_t)t * N + d) * BK + slot] = s;
}

// ---------------- degree counting (compact fallback path) ------------------
__global__ void deg_kernel(const int* __restrict__ src, const int* __restrict__ dst,
                           int* __restrict__ dout, int* __restrict__ din,
                           int E, int N, int total) {
    int i = blockIdx.x * 256 + threadIdx.x;
    if (i >= total) return;
    int t = i / E;
    atomicAdd(&dout[t * N + src[i]], 1);
    atomicAdd(&din[t * N + dst[i]], 1);
}

__global__ void rsqrt_kernel(const int* __restrict__ dout, const int* __restrict__ din,
                             float* __restrict__ dro, float* __restrict__ dri, int total) {
    int i = blockIdx.x * 256 + threadIdx.x;
    if (i >= total) return;
    int a = dout[i]; if (a < 1) a = 1;
    int b = din[i];  if (b < 1) b = 1;
    dro[i] = rsqrtf((float)a);
    dri[i] = rsqrtf((float)b);
}

// ---------------- prefix scan (compact fallback path) ----------------------
__global__ void scan1_kernel(const int* __restrict__ din, int* __restrict__ csum,
                             int N, int nch) {
    __shared__ int s[256];
    int t = blockIdx.x / nch, c = blockIdx.x % nch;
    int idx = c * 256 + threadIdx.x;
    s[threadIdx.x] = (idx < N) ? din[t * N + idx] : 0;
    __syncthreads();
    for (int off = 128; off > 0; off >>= 1) {
        if (threadIdx.x < off) s[threadIdx.x] += s[threadIdx.x + off];
        __syncthreads();
    }
    if (threadIdx.x == 0) csum[blockIdx.x] = s[0];
}

__global__ void scan2_kernel(const int* __restrict__ csum, int* __restrict__ coff,
                             int* __restrict__ rowptr, int N, int nch) {
    int t = threadIdx.x;
    if (t >= 3) return;
    int base = 0;
    for (int c = 0; c < nch; ++c) {
        int i = t * nch + c;
        coff[i] = base;
        base += csum[i];
    }
    rowptr[t * (N + 1) + N] = base;
}

__global__ void scan3_kernel(const int* __restrict__ din, const int* __restrict__ coff,
                             int* __restrict__ rowptr, int N, int nch) {
    __shared__ int s[256];
    int t = blockIdx.x / nch, c = blockIdx.x % nch;
    int idx = c * 256 + threadIdx.x;
    int v = (idx < N) ? din[t * N + idx] : 0;
    s[threadIdx.x] = v;
    __syncthreads();
    for (int off = 1; off < 256; off <<= 1) {
        int add = (threadIdx.x >= off) ? s[threadIdx.x - off] : 0;
        __syncthreads();
        s[threadIdx.x] += add;
        __syncthreads();
    }
    if (idx < N) rowptr[t * (N + 1) + idx] = coff[blockIdx.x] + s[threadIdx.x] - v;
}

__global__ void fill_kernel(const int* __restrict__ src, const int* __restrict__ dst,
                            const int* __restrict__ rowptr, int* __restrict__ cursor,
                            int* __restrict__ esrc, int E, int N, int total) {
    int i = blockIdx.x * 256 + threadIdx.x;
    if (i >= total) return;
    int t = i / E;
    int d = dst[i];
    int slot = atomicAdd(&cursor[t * N + d], 1);
    esrc[(size_t)t * E + rowptr[t * (N + 1) + d] + slot] = src[i];
}

// ---------------- aggregation ----------------------------------------------
// half-wave (32 lanes) per dst node, float4 per lane (full 128-ch row).
// AFF==0: input used raw; also emits wsum[d] = sum of dro over edges.
// AFF==1: input is pre-BN h; applies h' = a*h + b via linearity using wsum.
template <bool BUCKET, int AFF>
__launch_bounds__(256)
__global__ void agg_kernel(const float* __restrict__ h, const int* __restrict__ rowptr,
                           const int* __restrict__ cnts, const int* __restrict__ esrc,
                           const float* __restrict__ dro, const float* __restrict__ dri,
                           const float* __restrict__ aff, float* __restrict__ wsum,
                           float* __restrict__ z, int N) {
    int idx = blockIdx.x * 256 + threadIdx.x;
    int node = idx >> 5;
    int l2 = idx & 31;
    if (node >= N) return;
    int beg, cnt;
    if (BUCKET) {
        beg = node * BK;
        cnt = cnts[node];
        if (cnt > BK) cnt = BK;
    } else {
        beg = rowptr[node];
        cnt = rowptr[node + 1] - beg;
    }
    const float* hp = h + l2 * 4;
    float4 acc = make_float4(0.f, 0.f, 0.f, 0.f);
    float wacc = 0.f;
    int j = beg, end = beg + cnt;
    for (; j + 4 <= end; j += 4) {
        int s0 = esrc[j], s1 = esrc[j + 1], s2 = esrc[j + 2], s3 = esrc[j + 3];
        float w0 = dro[s0], w1 = dro[s1], w2 = dro[s2], w3 = dro[s3];
        float4 v0 = *(const float4*)(hp + (size_t)s0 * 128);
        float4 v1 = *(const float4*)(hp + (size_t)s1 * 128);
        float4 v2 = *(const float4*)(hp + (size_t)s2 * 128);
        float4 v3 = *(const float4*)(hp + (size_t)s3 * 128);
        acc.x += w0 * v0.x + w1 * v1.x + w2 * v2.x + w3 * v3.x;
        acc.y += w0 * v0.y + w1 * v1.y + w2 * v2.y + w3 * v3.y;
        acc.z += w0 * v0.z + w1 * v1.z + w2 * v2.z + w3 * v3.z;
        acc.w += w0 * v0.w + w1 * v1.w + w2 * v2.w + w3 * v3.w;
        if (AFF == 0) wacc += w0 + w1 + w2 + w3;
    }
    for (; j < end; ++j) {
        int s0 = esrc[j];
        float w0 = dro[s0];
        float4 v0 = *(const float4*)(hp + (size_t)s0 * 128);
        acc.x += w0 * v0.x;
        acc.y += w0 * v0.y;
        acc.z += w0 * v0.z;
        acc.w += w0 * v0.w;
        if (AFF == 0) wacc += w0;
    }
    float sc = dri[node];
    float4 r;
    if (AFF == 1) {
        float4 a = *(const float4*)(aff + l2 * 4);
        float4 b = *(const float4*)(aff + 128 + l2 * 4);
        float W = wsum[node];
        r.x = sc * (a.x * acc.x + b.x * W);
        r.y = sc * (a.y * acc.y + b.y * W);
        r.z = sc * (a.z * acc.z + b.z * W);
        r.w = sc * (a.w * acc.w + b.w * W);
    } else {
        r.x = acc.x * sc;
        r.y = acc.y * sc;
        r.z = acc.z * sc;
        r.w = acc.w * sc;
        if (l2 == 0) wsum[node] = wacc;
    }
    *(float4*)(z + (size_t)node * 128 + l2 * 4) = r;
}

// ---------------- fp32 GEMM  C[M,128] (op)= A[M,128] @ B[128,128] ----------
// MODE 0: C  = A@B + (b0+b1+b2)
// MODE 1: C += A@B
// MODE 2: C  = relu(A@B + b0), bnsum[c] += col sums, bnsum[128+c] += col sumsq
template <int MODE>
__launch_bounds__(256, 2)
__global__ void gemm128(const float* __restrict__ A, const float* __restrict__ Bm,
                        const float* __restrict__ b0, const float* __restrict__ b1,
                        const float* __restrict__ b2, float* __restrict__ C,
                        float* __restrict__ bnsum, int M) {
    __shared__ float Ast[32][132];
    __shared__ float Bs[32][132];
    __shared__ float red[256];

    const int tid = threadIdx.x;
    const int m0 = blockIdx.x * 128;
    const int rg = tid >> 4, cg = tid & 15;
    const int row = rg * 8, col = cg * 8;

    float acc[8][8] = {};

    for (int k0 = 0; k0 < 128; k0 += 32) {
        float4 av[4];
        int ar[4], ac[4];
#pragma unroll
        for (int i = 0; i < 4; ++i) {
            int fi = i * 256 + tid;
            int r = fi >> 3;
            int c4 = (fi & 7) * 4;
            ar[i] = r; ac[i] = c4;
            int gr = m0 + r;
            av[i] = (gr < M) ? *(const float4*)(A + (size_t)gr * 128 + k0 + c4)
                             : make_float4(0.f, 0.f, 0.f, 0.f);
        }
        float4 bv[4];
#pragma unroll
        for (int i = 0; i < 4; ++i) {
            int fi = i * 256 + tid;
            int kr = fi >> 5;
            int c4 = (fi & 31) * 4;
            bv[i] = *(const float4*)(Bm + (size_t)(k0 + kr) * 128 + c4);
        }
        __syncthreads();
#pragma unroll
        for (int i = 0; i < 4; ++i) {
            Ast[ac[i] + 0][ar[i]] = av[i].x;
            Ast[ac[i] + 1][ar[i]] = av[i].y;
            Ast[ac[i] + 2][ar[i]] = av[i].z;
            Ast[ac[i] + 3][ar[i]] = av[i].w;
        }
#pragma unroll
        for (int i = 0; i < 4; ++i) {
            int fi = i * 256 + tid;
            int kr = fi >> 5;
            int c4 = (fi & 31) * 4;
            *(float4*)&Bs[kr][c4] = bv[i];
        }
        __syncthreads();
#pragma unroll
        for (int k = 0; k < 32; ++k) {
            float4 a0 = *(const float4*)&Ast[k][row];
            float4 a1 = *(const float4*)&Ast[k][row + 4];
            float4 p0 = *(const float4*)&Bs[k][col];
            float4 p1 = *(const float4*)&Bs[k][col + 4];
            float a[8] = {a0.x, a0.y, a0.z, a0.w, a1.x, a1.y, a1.z, a1.w};
            float b[8] = {p0.x, p0.y, p0.z, p0.w, p1.x, p1.y, p1.z, p1.w};
#pragma unroll
            for (int r = 0; r < 8; ++r)
#pragma unroll
                for (int c = 0; c < 8; ++c)
                    acc[r][c] += a[r] * b[c];
        }
        __syncthreads();
    }

    if (MODE == 0) {
        float badd[8];
#pragma unroll
        for (int c = 0; c < 8; ++c) badd[c] = b0[col + c] + b1[col + c] + b2[col + c];
#pragma unroll
        for (int r = 0; r < 8; ++r) {
            int gr = m0 + row + r;
            if (gr < M) {
                float* cp = C + (size_t)gr * 128 + col;
                float4 v0 = {acc[r][0] + badd[0], acc[r][1] + badd[1],
                             acc[r][2] + badd[2], acc[r][3] + badd[3]};
                float4 v1 = {acc[r][4] + badd[4], acc[r][5] + badd[5],
                             acc[r][6] + badd[6], acc[r][7] + badd[7]};
                *(float4*)cp = v0;
                *(float4*)(cp + 4) = v1;
            }
        }
    } else if (MODE == 1) {
#pragma unroll
        for (int r = 0; r < 8; ++r) {
            int gr = m0 + row + r;
            if (gr < M) {
                float* cp = C + (size_t)gr * 128 + col;
                float4 o0 = *(float4*)cp;
                float4 o1 = *(float4*)(cp + 4);
                o0.x += acc[r][0]; o0.y += acc[r][1]; o0.z += acc[r][2]; o0.w += acc[r][3];
                o1.x += acc[r][4]; o1.y += acc[r][5]; o1.z += acc[r][6]; o1.w += acc[r][7];
                *(float4*)cp = o0;
                *(float4*)(cp + 4) = o1;
            }
        }
    } else {
        float bias[8];
#pragma unroll
        for (int c = 0; c < 8; ++c) bias[c] = b0[col + c];
        float cs[8] = {}, cq[8] = {};
#pragma unroll
        for (int r = 0; r < 8; ++r) {
            int gr = m0 + row + r;
            if (gr < M) {
                float v[8];
#pragma unroll
                for (int c = 0; c < 8; ++c) {
                    float t = acc[r][c] + bias[c];
                    v[c] = t > 0.f ? t : 0.f;
                    cs[c] += v[c];
                    cq[c] += v[c] * v[c];
                }
                float* cp = C + (size_t)gr * 128 + col;
                float4 v0 = {v[0], v[1], v[2], v[3]};
                float4 v1 = {v[4], v[5], v[6], v[7]};
                *(float4*)cp = v0;
                *(float4*)(cp + 4) = v1;
            }
        }
        red[tid] = 0.f;
        __syncthreads();
#pragma unroll
        for (int c = 0; c < 8; ++c) atomicAdd(&red[col + c], cs[c]);
        __syncthreads();
        float sred = red[tid & 127];
        __syncthreads();
        red[tid] = 0.f;
        __syncthreads();
#pragma unroll
        for (int c = 0; c < 8; ++c) atomicAdd(&red[col + c], cq[c]);
        __syncthreads();
        if (tid < 128) {
            atomicAdd(&bnsum[tid], sred);
            atomicAdd(&bnsum[128 + tid], red[tid]);
        }
    }
}

// ---------------- BN finalize + apply ----------------
__global__ void bn_fin(const float* __restrict__ bnsum, const float* __restrict__ gamma,
                       const float* __restrict__ beta, float* __restrict__ ss, int N) {
    int c = threadIdx.x;
    if (c >= 128) return;
    float invn = 1.0f / (float)N;
    float mean = bnsum[c] * invn;
    float var = bnsum[128 + c] * invn - mean * mean;
    float inv = rsqrtf(var + EPSV);
    float sc = gamma[c] * inv;
    ss[c] = sc;
    ss[128 + c] = beta[c] - mean * sc;
}

__global__ void bn_apply(float* __restrict__ h, const float* __restrict__ ss, int total4) {
    int i = blockIdx.x * 256 + threadIdx.x;
    if (i >= total4) return;
    int c4 = (i & 31) * 4;
    float4 sc = *(const float4*)&ss[c4];
    float4 sh = *(const float4*)&ss[128 + c4];
    float4 v = ((float4*)h)[i];
    v.x = v.x * sc.x + sh.x;
    v.y = v.y * sc.y + sh.y;
    v.z = v.z * sc.z + sh.z;
    v.w = v.w * sc.w + sh.w;
    ((float4*)h)[i] = v;
}

// ---------------------------------------------------------------------------
extern "C" void kernel_launch(void* const* d_in, const int* in_sizes, int n_in,
                              void* d_out, int out_size, void* d_ws, size_t ws_size,
                              hipStream_t stream) {
    const float* x    = (const float*)d_in[0];
    const int*   src  = (const int*)d_in[1];
    const int*   dst  = (const int*)d_in[2];
    const float* gcW0 = (const float*)d_in[3];
    const float* gcb0 = (const float*)d_in[4];
    const float* gcW  = (const float*)d_in[5];
    const float* gcb  = (const float*)d_in[6];
    const float* fcW  = (const float*)d_in[7];
    const float* fcb  = (const float*)d_in[8];
    const float* bng  = (const float*)d_in[9];
    const float* bnb  = (const float*)d_in[10];
    float* out = (float*)d_out;

    const int N = in_sizes[0] / 128;
    const int E = in_sizes[1] / 3;
    const int nch = (N + 255) / 256;
    const int totE = 3 * E;

    char* w = (char*)d_ws;
    auto alloc = [&](size_t bytes) -> char* {
        char* p = w;
        w += (bytes + 255) & ~(size_t)255;
        return p;
    };
    // common buffers
    float* zA     = (float*)alloc((size_t)N * 128 * 4);
    float* zB     = (float*)alloc((size_t)N * 128 * 4);
    float* gcout  = (float*)alloc((size_t)N * 128 * 4);
    float* dro    = (float*)alloc((size_t)3 * N * 4);
    float* dri    = (float*)alloc((size_t)3 * N * 4);
    int*   dout_i = (int*)alloc((size_t)3 * N * 4);
    int*   cnt_i  = (int*)alloc((size_t)3 * N * 4);   // bucket: slot cursor == in-degree
    float* wsum   = (float*)alloc((size_t)3 * N * 4);
    float* bnsum  = (float*)alloc(256 * 4);
    float* ss0    = (float*)alloc(256 * 4);
    float* ss1    = (float*)alloc(256 * 4);
    float* ss2    = (float*)alloc(256 * 4);
    size_t commonBytes = (size_t)(w - (char*)d_ws);

    const size_t bucketBytes = ((size_t)3 * N * BK * 4 + 255) & ~(size_t)255;
    const bool useBucket = (commonBytes + bucketBytes) <= ws_size;

    int* esrcB  = nullptr;   // bucket path
    int* esrc   = nullptr;   // compact path
    int* rowptr = nullptr;
    int* cursor = nullptr;
    int* csum   = nullptr;
    int* coff   = nullptr;
    if (useBucket) {
        esrcB = (int*)alloc((size_t)3 * N * BK * 4);
    } else {
        esrc   = (int*)alloc((size_t)3 * E * 4);
        rowptr = (int*)alloc((size_t)3 * (N + 1) * 4);
        cursor = (int*)alloc((size_t)3 * N * 4);
        csum   = (int*)alloc((size_t)3 * nch * 4);
        coff   = (int*)alloc((size_t)3 * nch * 4);
    }

    // ---- CSR/bucket build ----
    hipMemsetAsync(dout_i, 0, (size_t)3 * N * 4, stream);
    hipMemsetAsync(cnt_i, 0, (size_t)3 * N * 4, stream);
    if (useBucket) {
        dim3 fg((E + 255) / 256, 3);
        fill_bucket<<<fg, 256, 0, stream>>>(src, dst, dout_i, cnt_i, esrcB, E, N);
    } else {
        hipMemsetAsync(cursor, 0, (size_t)3 * N * 4, stream);
        deg_kernel<<<(totE + 255) / 256, 256, 0, stream>>>(src, dst, dout_i, cnt_i, E, N, totE);
        scan1_kernel<<<3 * nch, 256, 0, stream>>>(cnt_i, csum, N, nch);
        scan2_kernel<<<1, 64, 0, stream>>>(csum, coff, rowptr, N, nch);
        scan3_kernel<<<3 * nch, 256, 0, stream>>>(cnt_i, coff, rowptr, N, nch);
        fill_kernel<<<(totE + 255) / 256, 256, 0, stream>>>(src, dst, rowptr, cursor, esrc, E, N, totE);
    }
    rsqrt_kernel<<<(3 * N + 255) / 256, 256, 0, stream>>>(dout_i, cnt_i, dro, dri, 3 * N);

    // ---- layers ----
    const int gemmGrid = (N + 127) / 128;
    const int aggGrid = (N * 32 + 255) / 256;
    float* ssl[3] = {ss0, ss1, ss2};

    // buffer plan: L0: x -> zA(ztmp) -> gcout -> zA(hpre0)
    //              L1: zA -> zB -> gcout -> zB(hpre1)
    //              L2: zB -> zA -> gcout -> out (+bn_apply)
    const float* hin = x;
    float* ztmp[3] = {zA, zB, zA};
    float* hout[3] = {zA, zB, out};

    for (int l = 0; l < 3; ++l) {
        const float* Wl = (l == 0) ? gcW0 : gcW + (size_t)(l - 1) * 3 * 128 * 128;
        const float* bl = (l == 0) ? gcb0 : gcb + (size_t)(l - 1) * 3 * 128;
        const float* aff = (l == 0) ? nullptr : ssl[l - 1];
        for (int e = 0; e < 3; ++e) {
            const int* cntp = cnt_i + e * N;
            const int* rpp  = useBucket ? nullptr : rowptr + e * (N + 1);
            const int* esp  = useBucket ? esrcB + (size_t)e * N * BK : esrc + (size_t)e * E;
            if (useBucket) {
                if (l == 0)
                    agg_kernel<true, 0><<<aggGrid, 256, 0, stream>>>(
                        hin, rpp, cntp, esp, dro + e * N, dri + e * N, aff, wsum + e * N, ztmp[l], N);
                else
                    agg_kernel<true, 1><<<aggGrid, 256, 0, stream>>>(
                        hin, rpp, cntp, esp, dro + e * N, dri + e * N, aff, wsum + e * N, ztmp[l], N);
            } else {
                if (l == 0)
                    agg_kernel<false, 0><<<aggGrid, 256, 0, stream>>>(
                        hin, rpp, cntp, esp, dro + e * N, dri + e * N, aff, wsum + e * N, ztmp[l], N);
                else
                    agg_kernel<false, 1><<<aggGrid, 256, 0, stream>>>(
                        hin, rpp, cntp, esp, dro + e * N, dri + e * N, aff, wsum + e * N, ztmp[l], N);
            }
            if (e == 0)
                gemm128<0><<<gemmGrid, 256, 0, stream>>>(ztmp[l], Wl, bl, bl + 128, bl + 256,
                                                         gcout, nullptr, N);
            else
                gemm128<1><<<gemmGrid, 256, 0, stream>>>(ztmp[l], Wl + (size_t)e * 128 * 128,
                                                         nullptr, nullptr, nullptr,
                                                         gcout, nullptr, N);
        }
        hipMemsetAsync(bnsum, 0, 256 * 4, stream);
        gemm128<2><<<gemmGrid, 256, 0, stream>>>(gcout, fcW + (size_t)l * 128 * 128,
                                                 fcb + (size_t)l * 128, nullptr, nullptr,
                                                 hout[l], bnsum, N);
        bn_fin<<<1, 128, 0, stream>>>(bnsum, bng + (size_t)l * 128, bnb + (size_t)l * 128,
                                      ssl[l], N);
        if (l == 2)
            bn_apply<<<(N * 32 + 255) / 256, 256, 0, stream>>>(hout[l], ssl[l], N * 32);
        hin = hout[l];
    }
}

// Round 3
// 2119.248 us; speedup vs baseline: 1.3177x; 1.1693x over previous
//
#include <hip/hip_runtime.h>

// ---------------------------------------------------------------------------
// Encoder: 3-layer HeteroGraphConv(3 edge types) -> FC -> ReLU -> BatchNorm
// Round 3:
//   * counting-sort CSR build (LDS histograms; ~460k global atomics total
//     instead of 9.6M device-scope per-edge atomics); degrees free from the
//     fine histograms
//   * per-layer GEMM fusion: gemm_gc2 (K=256, in-place) + accumulate GEMM
//   * BN affine folded into next layer's aggregation (unchanged from R2)
// ---------------------------------------------------------------------------

#define EPSV 1e-5f
#define CH 8192      // edges per block in coarse passes
#define MAXNB 512    // max coarse bins (N <= 131072)

// ---------------- build phase 1: coarse histograms (both keys) -------------
__global__ void coarse_hist(const int* __restrict__ src, const int* __restrict__ dst,
                            int* __restrict__ chd, int* __restrict__ chs,
                            int E, int NB) {
    __shared__ int hd[MAXNB], hs[MAXNB];
    int t = blockIdx.y;
    for (int i = threadIdx.x; i < NB; i += 256) { hd[i] = 0; hs[i] = 0; }
    __syncthreads();
    int base = blockIdx.x * CH;
    int end = base + CH < E ? base + CH : E;
    const int* sp = src + (size_t)t * E;
    const int* dp = dst + (size_t)t * E;
    for (int i = base + threadIdx.x; i < end; i += 256) {
        atomicAdd(&hd[dp[i] >> 8], 1);
        atomicAdd(&hs[sp[i] >> 8], 1);
    }
    __syncthreads();
    for (int b = threadIdx.x; b < NB; b += 256) {
        if (hd[b]) atomicAdd(&chd[t * NB + b], hd[b]);
        if (hs[b]) atomicAdd(&chs[t * NB + b], hs[b]);
    }
}

// ---------------- build phase 2: scan coarse bins -> offsets + cursors -----
__global__ void scan_off(const int* __restrict__ chd, const int* __restrict__ chs,
                         int* __restrict__ offd, int* __restrict__ offs,
                         int* __restrict__ gcd, int* __restrict__ gcs,
                         int* __restrict__ rowptr, int NB, int N, int E) {
    __shared__ int s[MAXNB];
    int tid = threadIdx.x;
    for (int a = 0; a < 6; ++a) {
        const int* h = (a < 3) ? chd + a * NB : chs + (a - 3) * NB;
        int* off = (a < 3) ? offd + a * (NB + 1) : offs + (a - 3) * (NB + 1);
        int* gc = (a < 3) ? gcd + a * NB : gcs + (a - 3) * NB;
        s[tid] = (tid < NB) ? h[tid] : 0;
        __syncthreads();
        for (int o = 1; o < MAXNB; o <<= 1) {
            int v = (tid >= o) ? s[tid - o] : 0;
            __syncthreads();
            s[tid] += v;
            __syncthreads();
        }
        if (tid < NB) {
            off[tid + 1] = s[tid];
            if (tid == 0) off[0] = 0;
        }
        __syncthreads();
        if (tid < NB) gc[tid] = off[tid];
        __syncthreads();
    }
    if (tid < 3) rowptr[tid * (N + 1) + N] = E;
}

// ---------------- build phase 3: scatter edges to coarse bins --------------
__global__ void scatter_coarse(const int* __restrict__ src, const int* __restrict__ dst,
                               int* __restrict__ gcd, int* __restrict__ gcs,
                               int* __restrict__ dbuf, unsigned char* __restrict__ sbuf,
                               int E, int NB) {
    __shared__ int hd[MAXNB], hs[MAXNB], bd[MAXNB], bs[MAXNB];
    int t = blockIdx.y;
    for (int i = threadIdx.x; i < NB; i += 256) { hd[i] = 0; hs[i] = 0; }
    __syncthreads();
    int base = blockIdx.x * CH;
    int end = base + CH < E ? base + CH : E;
    const int* sp = src + (size_t)t * E;
    const int* dp = dst + (size_t)t * E;
    for (int i = base + threadIdx.x; i < end; i += 256) {
        atomicAdd(&hd[dp[i] >> 8], 1);
        atomicAdd(&hs[sp[i] >> 8], 1);
    }
    __syncthreads();
    for (int b = threadIdx.x; b < NB; b += 256) {
        bd[b] = hd[b] ? atomicAdd(&gcd[t * NB + b], hd[b]) : 0;
        bs[b] = hs[b] ? atomicAdd(&gcs[t * NB + b], hs[b]) : 0;
        hd[b] = 0;
        hs[b] = 0;
    }
    __syncthreads();
    for (int i = base + threadIdx.x; i < end; i += 256) {
        int sv = sp[i], dv = dp[i];
        int pb = dv >> 8;
        int pos = bd[pb] + atomicAdd(&hd[pb], 1);
        dbuf[(size_t)t * E + pos] = (sv << 8) | (dv & 255);
        int sb = sv >> 8;
        int ps = bs[sb] + atomicAdd(&hs[sb], 1);
        sbuf[(size_t)t * E + ps] = (unsigned char)(sv & 255);
    }
}

// ---------------- build phase 4a: fine sort by dst -> compact CSR ----------
__global__ void fine_dst(const int* __restrict__ dbuf, const int* __restrict__ offd,
                         int* __restrict__ esrc, int* __restrict__ rowptr,
                         float* __restrict__ dri, int E, int N, int NB) {
    __shared__ int h[256], sc[256], cur[256];
    int b = blockIdx.x, t = blockIdx.y;
    int tid = threadIdx.x;
    h[tid] = 0;
    __syncthreads();
    int beg = offd[t * (NB + 1) + b], end = offd[t * (NB + 1) + b + 1];
    const int* dp = dbuf + (size_t)t * E;
    for (int i = beg + tid; i < end; i += 256) atomicAdd(&h[dp[i] & 255], 1);
    __syncthreads();
    sc[tid] = h[tid];
    __syncthreads();
    for (int o = 1; o < 256; o <<= 1) {
        int v = (tid >= o) ? sc[tid - o] : 0;
        __syncthreads();
        sc[tid] += v;
        __syncthreads();
    }
    int excl = sc[tid] - h[tid];
    cur[tid] = excl;
    int node = b * 256 + tid;
    if (node < N) {
        rowptr[t * (N + 1) + node] = beg + excl;
        int dg = h[tid] < 1 ? 1 : h[tid];
        dri[(size_t)t * N + node] = rsqrtf((float)dg);
    }
    __syncthreads();
    for (int i = beg + tid; i < end; i += 256) {
        int v = dp[i];
        int f = v & 255;
        int pos = beg + atomicAdd(&cur[f], 1);
        esrc[(size_t)t * E + pos] = v >> 8;
    }
}

// ---------------- build phase 4b: fine histogram by src -> dro -------------
__global__ void fine_src(const unsigned char* __restrict__ sbuf, const int* __restrict__ offs,
                         float* __restrict__ dro, int E, int N, int NB) {
    __shared__ int h[256];
    int b = blockIdx.x, t = blockIdx.y;
    int tid = threadIdx.x;
    h[tid] = 0;
    __syncthreads();
    int beg = offs[t * (NB + 1) + b], end = offs[t * (NB + 1) + b + 1];
    const unsigned char* sp = sbuf + (size_t)t * E;
    for (int i = beg + tid; i < end; i += 256) atomicAdd(&h[sp[i]], 1);
    __syncthreads();
    int node = b * 256 + tid;
    if (node < N) {
        int dg = h[tid] < 1 ? 1 : h[tid];
        dro[(size_t)t * N + node] = rsqrtf((float)dg);
    }
}

// ---------------- aggregation ----------------------------------------------
// half-wave (32 lanes) per dst node, float4 per lane (full 128-ch row).
// AFF==0: raw input; also emits wsum[d] = sum of dro over edges.
// AFF==1: input is pre-BN h; applies h' = a*h + b via linearity using wsum.
template <int AFF>
__launch_bounds__(256)
__global__ void agg_kernel(const float* __restrict__ h, const int* __restrict__ rowptr,
                           const int* __restrict__ esrc, const float* __restrict__ dro,
                           const float* __restrict__ dri, const float* __restrict__ aff,
                           float* __restrict__ wsum, float* __restrict__ z, int N) {
    int idx = blockIdx.x * 256 + threadIdx.x;
    int node = idx >> 5;
    int l2 = idx & 31;
    if (node >= N) return;
    int beg = rowptr[node];
    int end = rowptr[node + 1];
    const float* hp = h + l2 * 4;
    float4 acc = make_float4(0.f, 0.f, 0.f, 0.f);
    float wacc = 0.f;
    int j = beg;
    for (; j + 4 <= end; j += 4) {
        int s0 = esrc[j], s1 = esrc[j + 1], s2 = esrc[j + 2], s3 = esrc[j + 3];
        float w0 = dro[s0], w1 = dro[s1], w2 = dro[s2], w3 = dro[s3];
        float4 v0 = *(const float4*)(hp + (size_t)s0 * 128);
        float4 v1 = *(const float4*)(hp + (size_t)s1 * 128);
        float4 v2 = *(const float4*)(hp + (size_t)s2 * 128);
        float4 v3 = *(const float4*)(hp + (size_t)s3 * 128);
        acc.x += w0 * v0.x + w1 * v1.x + w2 * v2.x + w3 * v3.x;
        acc.y += w0 * v0.y + w1 * v1.y + w2 * v2.y + w3 * v3.y;
        acc.z += w0 * v0.z + w1 * v1.z + w2 * v2.z + w3 * v3.z;
        acc.w += w0 * v0.w + w1 * v1.w + w2 * v2.w + w3 * v3.w;
        if (AFF == 0) wacc += w0 + w1 + w2 + w3;
    }
    for (; j < end; ++j) {
        int s0 = esrc[j];
        float w0 = dro[s0];
        float4 v0 = *(const float4*)(hp + (size_t)s0 * 128);
        acc.x += w0 * v0.x;
        acc.y += w0 * v0.y;
        acc.z += w0 * v0.z;
        acc.w += w0 * v0.w;
        if (AFF == 0) wacc += w0;
    }
    float scl = dri[node];
    float4 r;
    if (AFF == 1) {
        float4 a = *(const float4*)(aff + l2 * 4);
        float4 bb = *(const float4*)(aff + 128 + l2 * 4);
        float W = wsum[node];
        r.x = scl * (a.x * acc.x + bb.x * W);
        r.y = scl * (a.y * acc.y + bb.y * W);
        r.z = scl * (a.z * acc.z + bb.z * W);
        r.w = scl * (a.w * acc.w + bb.w * W);
    } else {
        r.x = acc.x * scl;
        r.y = acc.y * scl;
        r.z = acc.z * scl;
        r.w = acc.w * scl;
        if (l2 == 0) wsum[node] = wacc;
    }
    *(float4*)(z + (size_t)node * 128 + l2 * 4) = r;
}

// ---------------- fused 2-type GEMM: z1io = z0@W0 + z1io@W1 + (b0+b1+b2) ---
// In-place into z1io: each block reads all its A-rows (chunks 0..7) before
// the epilogue writes the same rows; rows are block-partitioned.
__launch_bounds__(256, 2)
__global__ void gemm_gc2(const float* __restrict__ z0, float* __restrict__ z1io,
                         const float* __restrict__ W01, const float* __restrict__ b3,
                         int M) {
    __shared__ float Ast[32][132];
    __shared__ float Bs[32][132];
    const int tid = threadIdx.x;
    const int m0 = blockIdx.x * 128;
    const int rg = tid >> 4, cg = tid & 15;
    const int row = rg * 8, col = cg * 8;
    float acc[8][8] = {};

    for (int ch = 0; ch < 8; ++ch) {
        const float* Zc = (ch < 4) ? z0 : z1io;
        const int k0 = (ch & 3) * 32;
        float4 av[4];
        int ar[4], ac[4];
#pragma unroll
        for (int i = 0; i < 4; ++i) {
            int fi = i * 256 + tid;
            int r = fi >> 3;
            int c4 = (fi & 7) * 4;
            ar[i] = r; ac[i] = c4;
            int gr = m0 + r;
            av[i] = (gr < M) ? *(const float4*)(Zc + (size_t)gr * 128 + k0 + c4)
                             : make_float4(0.f, 0.f, 0.f, 0.f);
        }
        float4 bv[4];
#pragma unroll
        for (int i = 0; i < 4; ++i) {
            int fi = i * 256 + tid;
            int kr = fi >> 5;
            int c4 = (fi & 31) * 4;
            bv[i] = *(const float4*)(W01 + (size_t)(ch * 32 + kr) * 128 + c4);
        }
        __syncthreads();
#pragma unroll
        for (int i = 0; i < 4; ++i) {
            Ast[ac[i] + 0][ar[i]] = av[i].x;
            Ast[ac[i] + 1][ar[i]] = av[i].y;
            Ast[ac[i] + 2][ar[i]] = av[i].z;
            Ast[ac[i] + 3][ar[i]] = av[i].w;
        }
#pragma unroll
        for (int i = 0; i < 4; ++i) {
            int fi = i * 256 + tid;
            int kr = fi >> 5;
            int c4 = (fi & 31) * 4;
            *(float4*)&Bs[kr][c4] = bv[i];
        }
        __syncthreads();
#pragma unroll
        for (int k = 0; k < 32; ++k) {
            float4 a0 = *(const float4*)&Ast[k][row];
            float4 a1 = *(const float4*)&Ast[k][row + 4];
            float4 p0 = *(const float4*)&Bs[k][col];
            float4 p1 = *(const float4*)&Bs[k][col + 4];
            float a[8] = {a0.x, a0.y, a0.z, a0.w, a1.x, a1.y, a1.z, a1.w};
            float b[8] = {p0.x, p0.y, p0.z, p0.w, p1.x, p1.y, p1.z, p1.w};
#pragma unroll
            for (int r = 0; r < 8; ++r)
#pragma unroll
                for (int c = 0; c < 8; ++c)
                    acc[r][c] += a[r] * b[c];
        }
        __syncthreads();
    }

    float badd[8];
#pragma unroll
    for (int c = 0; c < 8; ++c)
        badd[c] = b3[col + c] + b3[128 + col + c] + b3[256 + col + c];
#pragma unroll
    for (int r = 0; r < 8; ++r) {
        int gr = m0 + row + r;
        if (gr < M) {
            float* cp = z1io + (size_t)gr * 128 + col;
            float4 v0 = {acc[r][0] + badd[0], acc[r][1] + badd[1],
                         acc[r][2] + badd[2], acc[r][3] + badd[3]};
            float4 v1 = {acc[r][4] + badd[4], acc[r][5] + badd[5],
                         acc[r][6] + badd[6], acc[r][7] + badd[7]};
            *(float4*)cp = v0;
            *(float4*)(cp + 4) = v1;
        }
    }
}

// ---------------- fp32 GEMM  C[M,128] (op)= A[M,128] @ B[128,128] ----------
// MODE 1: C += A@B
// MODE 2: C  = relu(A@B + b0), bnsum[c] += col sums, bnsum[128+c] += col sumsq
template <int MODE>
__launch_bounds__(256, 2)
__global__ void gemm128(const float* __restrict__ A, const float* __restrict__ Bm,
                        const float* __restrict__ b0, float* __restrict__ C,
                        float* __restrict__ bnsum, int M) {
    __shared__ float Ast[32][132];
    __shared__ float Bs[32][132];
    __shared__ float red[256];

    const int tid = threadIdx.x;
    const int m0 = blockIdx.x * 128;
    const int rg = tid >> 4, cg = tid & 15;
    const int row = rg * 8, col = cg * 8;

    float acc[8][8] = {};

    for (int k0 = 0; k0 < 128; k0 += 32) {
        float4 av[4];
        int ar[4], ac[4];
#pragma unroll
        for (int i = 0; i < 4; ++i) {
            int fi = i * 256 + tid;
            int r = fi >> 3;
            int c4 = (fi & 7) * 4;
            ar[i] = r; ac[i] = c4;
            int gr = m0 + r;
            av[i] = (gr < M) ? *(const float4*)(A + (size_t)gr * 128 + k0 + c4)
                             : make_float4(0.f, 0.f, 0.f, 0.f);
        }
        float4 bv[4];
#pragma unroll
        for (int i = 0; i < 4; ++i) {
            int fi = i * 256 + tid;
            int kr = fi >> 5;
            int c4 = (fi & 31) * 4;
            bv[i] = *(const float4*)(Bm + (size_t)(k0 + kr) * 128 + c4);
        }
        __syncthreads();
#pragma unroll
        for (int i = 0; i < 4; ++i) {
            Ast[ac[i] + 0][ar[i]] = av[i].x;
            Ast[ac[i] + 1][ar[i]] = av[i].y;
            Ast[ac[i] + 2][ar[i]] = av[i].z;
            Ast[ac[i] + 3][ar[i]] = av[i].w;
        }
#pragma unroll
        for (int i = 0; i < 4; ++i) {
            int fi = i * 256 + tid;
            int kr = fi >> 5;
            int c4 = (fi & 31) * 4;
            *(float4*)&Bs[kr][c4] = bv[i];
        }
        __syncthreads();
#pragma unroll
        for (int k = 0; k < 32; ++k) {
            float4 a0 = *(const float4*)&Ast[k][row];
            float4 a1 = *(const float4*)&Ast[k][row + 4];
            float4 p0 = *(const float4*)&Bs[k][col];
            float4 p1 = *(const float4*)&Bs[k][col + 4];
            float a[8] = {a0.x, a0.y, a0.z, a0.w, a1.x, a1.y, a1.z, a1.w};
            float b[8] = {p0.x, p0.y, p0.z, p0.w, p1.x, p1.y, p1.z, p1.w};
#pragma unroll
            for (int r = 0; r < 8; ++r)
#pragma unroll
                for (int c = 0; c < 8; ++c)
                    acc[r][c] += a[r] * b[c];
        }
        __syncthreads();
    }

    if (MODE == 1) {
#pragma unroll
        for (int r = 0; r < 8; ++r) {
            int gr = m0 + row + r;
            if (gr < M) {
                float* cp = C + (size_t)gr * 128 + col;
                float4 o0 = *(float4*)cp;
                float4 o1 = *(float4*)(cp + 4);
                o0.x += acc[r][0]; o0.y += acc[r][1]; o0.z += acc[r][2]; o0.w += acc[r][3];
                o1.x += acc[r][4]; o1.y += acc[r][5]; o1.z += acc[r][6]; o1.w += acc[r][7];
                *(float4*)cp = o0;
                *(float4*)(cp + 4) = o1;
            }
        }
    } else {
        float bias[8];
#pragma unroll
        for (int c = 0; c < 8; ++c) bias[c] = b0[col + c];
        float cs[8] = {}, cq[8] = {};
#pragma unroll
        for (int r = 0; r < 8; ++r) {
            int gr = m0 + row + r;
            if (gr < M) {
                float v[8];
#pragma unroll
                for (int c = 0; c < 8; ++c) {
                    float t = acc[r][c] + bias[c];
                    v[c] = t > 0.f ? t : 0.f;
                    cs[c] += v[c];
                    cq[c] += v[c] * v[c];
                }
                float* cp = C + (size_t)gr * 128 + col;
                float4 v0 = {v[0], v[1], v[2], v[3]};
                float4 v1 = {v[4], v[5], v[6], v[7]};
                *(float4*)cp = v0;
                *(float4*)(cp + 4) = v1;
            }
        }
        red[tid] = 0.f;
        __syncthreads();
#pragma unroll
        for (int c = 0; c < 8; ++c) atomicAdd(&red[col + c], cs[c]);
        __syncthreads();
        float sred = red[tid & 127];
        __syncthreads();
        red[tid] = 0.f;
        __syncthreads();
#pragma unroll
        for (int c = 0; c < 8; ++c) atomicAdd(&red[col + c], cq[c]);
        __syncthreads();
        if (tid < 128) {
            atomicAdd(&bnsum[tid], sred);
            atomicAdd(&bnsum[128 + tid], red[tid]);
        }
    }
}

// ---------------- BN finalize + apply ----------------
__global__ void bn_fin(const float* __restrict__ bnsum, const float* __restrict__ gamma,
                       const float* __restrict__ beta, float* __restrict__ ss, int N) {
    int c = threadIdx.x;
    if (c >= 128) return;
    float invn = 1.0f / (float)N;
    float mean = bnsum[c] * invn;
    float var = bnsum[128 + c] * invn - mean * mean;
    float inv = rsqrtf(var + EPSV);
    float sc = gamma[c] * inv;
    ss[c] = sc;
    ss[128 + c] = beta[c] - mean * sc;
}

__global__ void bn_apply(float* __restrict__ h, const float* __restrict__ ss, int total4) {
    int i = blockIdx.x * 256 + threadIdx.x;
    if (i >= total4) return;
    int c4 = (i & 31) * 4;
    float4 sc = *(const float4*)&ss[c4];
    float4 sh = *(const float4*)&ss[128 + c4];
    float4 v = ((float4*)h)[i];
    v.x = v.x * sc.x + sh.x;
    v.y = v.y * sc.y + sh.y;
    v.z = v.z * sc.z + sh.z;
    v.w = v.w * sc.w + sh.w;
    ((float4*)h)[i] = v;
}

// ---------------------------------------------------------------------------
extern "C" void kernel_launch(void* const* d_in, const int* in_sizes, int n_in,
                              void* d_out, int out_size, void* d_ws, size_t ws_size,
                              hipStream_t stream) {
    const float* x    = (const float*)d_in[0];
    const int*   src  = (const int*)d_in[1];
    const int*   dst  = (const int*)d_in[2];
    const float* gcW0 = (const float*)d_in[3];
    const float* gcb0 = (const float*)d_in[4];
    const float* gcW  = (const float*)d_in[5];
    const float* gcb  = (const float*)d_in[6];
    const float* fcW  = (const float*)d_in[7];
    const float* fcb  = (const float*)d_in[8];
    const float* bng  = (const float*)d_in[9];
    const float* bnb  = (const float*)d_in[10];
    float* out = (float*)d_out;

    const int N = in_sizes[0] / 128;
    const int E = in_sizes[1] / 3;
    const int NB = (N + 255) / 256;   // <= MAXNB for this problem size

    char* w = (char*)d_ws;
    auto alloc = [&](size_t bytes) -> char* {
        char* p = w;
        w += (bytes + 255) & ~(size_t)255;
        return p;
    };
    float* r0   = (float*)alloc((size_t)N * 128 * 4);
    float* r1   = (float*)alloc((size_t)N * 128 * 4);
    float* rC   = (float*)alloc((size_t)N * 128 * 4);
    int*   esrc = (int*)alloc((size_t)3 * E * 4);
    int*   dbuf = (int*)alloc((size_t)3 * E * 4);
    unsigned char* sbuf = (unsigned char*)alloc((size_t)3 * E);
    int*   rowptr = (int*)alloc((size_t)3 * (N + 1) * 4);
    float* dro  = (float*)alloc((size_t)3 * N * 4);
    float* dri  = (float*)alloc((size_t)3 * N * 4);
    float* wsum = (float*)alloc((size_t)3 * N * 4);
    int*   chd  = (int*)alloc((size_t)3 * NB * 4);
    int*   chs  = (int*)alloc((size_t)3 * NB * 4);
    int*   offd = (int*)alloc((size_t)3 * (NB + 1) * 4);
    int*   offs = (int*)alloc((size_t)3 * (NB + 1) * 4);
    int*   gcd  = (int*)alloc((size_t)3 * NB * 4);
    int*   gcs  = (int*)alloc((size_t)3 * NB * 4);
    float* bnsum = (float*)alloc(256 * 4);
    float* ss0  = (float*)alloc(256 * 4);
    float* ss1  = (float*)alloc(256 * 4);
    float* ss2  = (float*)alloc(256 * 4);

    // ---- counting-sort CSR build ----
    hipMemsetAsync(chd, 0, (size_t)3 * NB * 4, stream);
    hipMemsetAsync(chs, 0, (size_t)3 * NB * 4, stream);
    dim3 cg((E + CH - 1) / CH, 3);
    coarse_hist<<<cg, 256, 0, stream>>>(src, dst, chd, chs, E, NB);
    scan_off<<<1, MAXNB, 0, stream>>>(chd, chs, offd, offs, gcd, gcs, rowptr, NB, N, E);
    scatter_coarse<<<cg, 256, 0, stream>>>(src, dst, gcd, gcs, dbuf, sbuf, E, NB);
    dim3 fg(NB, 3);
    fine_dst<<<fg, 256, 0, stream>>>(dbuf, offd, esrc, rowptr, dri, E, N, NB);
    fine_src<<<fg, 256, 0, stream>>>(sbuf, offs, dro, E, N, NB);

    // ---- layers ----
    const int gemmGrid = (N + 127) / 128;
    const int aggGrid = (N * 32 + 255) / 256;
    float* ssl[3] = {ss0, ss1, ss2};
    const float* hin = x;

    for (int l = 0; l < 3; ++l) {
        const float* Wl = (l == 0) ? gcW0 : gcW + (size_t)(l - 1) * 3 * 128 * 128;
        const float* bl = (l == 0) ? gcb0 : gcb + (size_t)(l - 1) * 3 * 128;
        const float* aff = (l == 0) ? nullptr : ssl[l - 1];

        auto agg = [&](int e, float* zt) {
            const int* rpp = rowptr + e * (N + 1);
            const int* esp = esrc + (size_t)e * E;
            if (l == 0)
                agg_kernel<0><<<aggGrid, 256, 0, stream>>>(hin, rpp, esp, dro + e * N,
                                                           dri + e * N, aff, wsum + e * N, zt, N);
            else
                agg_kernel<1><<<aggGrid, 256, 0, stream>>>(hin, rpp, esp, dro + e * N,
                                                           dri + e * N, aff, wsum + e * N, zt, N);
        };

        agg(0, r0);
        agg(1, r1);
        gemm_gc2<<<gemmGrid, 256, 0, stream>>>(r0, r1, Wl, bl, N);   // r1 = z0@W0+z1@W1+Σb
        agg(2, r0);
        gemm128<1><<<gemmGrid, 256, 0, stream>>>(r0, Wl + 2 * 128 * 128, nullptr, r1, nullptr, N);

        hipMemsetAsync(bnsum, 0, 256 * 4, stream);
        float* fcTarget = (l == 2) ? out : rC;
        gemm128<2><<<gemmGrid, 256, 0, stream>>>(r1, fcW + (size_t)l * 128 * 128,
                                                 fcb + (size_t)l * 128, fcTarget, bnsum, N);
        bn_fin<<<1, 128, 0, stream>>>(bnsum, bng + (size_t)l * 128, bnb + (size_t)l * 128,
                                      ssl[l], N);
        if (l == 2)
            bn_apply<<<(N * 32 + 255) / 256, 256, 0, stream>>>(out, ssl[l], N * 32);
        hin = fcTarget;
    }
}

// Round 4
// 1616.856 us; speedup vs baseline: 1.7271x; 1.3107x over previous
//
#include <hip/hip_runtime.h>

// ---------------------------------------------------------------------------
// Encoder: 3-layer HeteroGraphConv(3 edge types) -> FC -> ReLU -> BatchNorm
// Round 4:
//   * aggregation gathers from a bf16 post-BN copy of h (halves gather bytes);
//     BN affine applied in the cvt pass (drops wsum/AFF folding)
//   * GEMMs: XOR-swizzled flat LDS (kills 4-way bank conflicts) + split
//     row/col thread tile {4 @ base, 4 @ base+64}; launch_bounds(256,3)
//   * counting-sort CSR build unchanged; dbuf/sbuf overlap rC (lifetimes)
// ---------------------------------------------------------------------------

#define EPSV 1e-5f
#define CH 8192      // edges per block in coarse passes
#define MAXNB 512    // max coarse bins (N <= 131072)

// ---------------- build phase 1: coarse histograms (both keys) -------------
__global__ void coarse_hist(const int* __restrict__ src, const int* __restrict__ dst,
                            int* __restrict__ chd, int* __restrict__ chs,
                            int E, int NB) {
    __shared__ int hd[MAXNB], hs[MAXNB];
    int t = blockIdx.y;
    for (int i = threadIdx.x; i < NB; i += 256) { hd[i] = 0; hs[i] = 0; }
    __syncthreads();
    int base = blockIdx.x * CH;
    int end = base + CH < E ? base + CH : E;
    const int* sp = src + (size_t)t * E;
    const int* dp = dst + (size_t)t * E;
    for (int i = base + threadIdx.x; i < end; i += 256) {
        atomicAdd(&hd[dp[i] >> 8], 1);
        atomicAdd(&hs[sp[i] >> 8], 1);
    }
    __syncthreads();
    for (int b = threadIdx.x; b < NB; b += 256) {
        if (hd[b]) atomicAdd(&chd[t * NB + b], hd[b]);
        if (hs[b]) atomicAdd(&chs[t * NB + b], hs[b]);
    }
}

// ---------------- build phase 2: scan coarse bins -> offsets + cursors -----
__global__ void scan_off(const int* __restrict__ chd, const int* __restrict__ chs,
                         int* __restrict__ offd, int* __restrict__ offs,
                         int* __restrict__ gcd, int* __restrict__ gcs,
                         int* __restrict__ rowptr, int NB, int N, int E) {
    __shared__ int s[MAXNB];
    int tid = threadIdx.x;
    for (int a = 0; a < 6; ++a) {
        const int* h = (a < 3) ? chd + a * NB : chs + (a - 3) * NB;
        int* off = (a < 3) ? offd + a * (NB + 1) : offs + (a - 3) * (NB + 1);
        int* gc = (a < 3) ? gcd + a * NB : gcs + (a - 3) * NB;
        s[tid] = (tid < NB) ? h[tid] : 0;
        __syncthreads();
        for (int o = 1; o < MAXNB; o <<= 1) {
            int v = (tid >= o) ? s[tid - o] : 0;
            __syncthreads();
            s[tid] += v;
            __syncthreads();
        }
        if (tid < NB) {
            off[tid + 1] = s[tid];
            if (tid == 0) off[0] = 0;
        }
        __syncthreads();
        if (tid < NB) gc[tid] = off[tid];
        __syncthreads();
    }
    if (tid < 3) rowptr[tid * (N + 1) + N] = E;
}

// ---------------- build phase 3: scatter edges to coarse bins --------------
__global__ void scatter_coarse(const int* __restrict__ src, const int* __restrict__ dst,
                               int* __restrict__ gcd, int* __restrict__ gcs,
                               int* __restrict__ dbuf, unsigned char* __restrict__ sbuf,
                               int E, int NB) {
    __shared__ int hd[MAXNB], hs[MAXNB], bd[MAXNB], bs[MAXNB];
    int t = blockIdx.y;
    for (int i = threadIdx.x; i < NB; i += 256) { hd[i] = 0; hs[i] = 0; }
    __syncthreads();
    int base = blockIdx.x * CH;
    int end = base + CH < E ? base + CH : E;
    const int* sp = src + (size_t)t * E;
    const int* dp = dst + (size_t)t * E;
    for (int i = base + threadIdx.x; i < end; i += 256) {
        atomicAdd(&hd[dp[i] >> 8], 1);
        atomicAdd(&hs[sp[i] >> 8], 1);
    }
    __syncthreads();
    for (int b = threadIdx.x; b < NB; b += 256) {
        bd[b] = hd[b] ? atomicAdd(&gcd[t * NB + b], hd[b]) : 0;
        bs[b] = hs[b] ? atomicAdd(&gcs[t * NB + b], hs[b]) : 0;
        hd[b] = 0;
        hs[b] = 0;
    }
    __syncthreads();
    for (int i = base + threadIdx.x; i < end; i += 256) {
        int sv = sp[i], dv = dp[i];
        int pb = dv >> 8;
        int pos = bd[pb] + atomicAdd(&hd[pb], 1);
        dbuf[(size_t)t * E + pos] = (sv << 8) | (dv & 255);
        int sb = sv >> 8;
        int ps = bs[sb] + atomicAdd(&hs[sb], 1);
        sbuf[(size_t)t * E + ps] = (unsigned char)(sv & 255);
    }
}

// ---------------- build phase 4a: fine sort by dst -> compact CSR ----------
__global__ void fine_dst(const int* __restrict__ dbuf, const int* __restrict__ offd,
                         int* __restrict__ esrc, int* __restrict__ rowptr,
                         float* __restrict__ dri, int E, int N, int NB) {
    __shared__ int h[256], sc[256], cur[256];
    int b = blockIdx.x, t = blockIdx.y;
    int tid = threadIdx.x;
    h[tid] = 0;
    __syncthreads();
    int beg = offd[t * (NB + 1) + b], end = offd[t * (NB + 1) + b + 1];
    const int* dp = dbuf + (size_t)t * E;
    for (int i = beg + tid; i < end; i += 256) atomicAdd(&h[dp[i] & 255], 1);
    __syncthreads();
    sc[tid] = h[tid];
    __syncthreads();
    for (int o = 1; o < 256; o <<= 1) {
        int v = (tid >= o) ? sc[tid - o] : 0;
        __syncthreads();
        sc[tid] += v;
        __syncthreads();
    }
    int excl = sc[tid] - h[tid];
    cur[tid] = excl;
    int node = b * 256 + tid;
    if (node < N) {
        rowptr[t * (N + 1) + node] = beg + excl;
        int dg = h[tid] < 1 ? 1 : h[tid];
        dri[(size_t)t * N + node] = rsqrtf((float)dg);
    }
    __syncthreads();
    for (int i = beg + tid; i < end; i += 256) {
        int v = dp[i];
        int f = v & 255;
        int pos = beg + atomicAdd(&cur[f], 1);
        esrc[(size_t)t * E + pos] = v >> 8;
    }
}

// ---------------- build phase 4b: fine histogram by src -> dro -------------
__global__ void fine_src(const unsigned char* __restrict__ sbuf, const int* __restrict__ offs,
                         float* __restrict__ dro, int E, int N, int NB) {
    __shared__ int h[256];
    int b = blockIdx.x, t = blockIdx.y;
    int tid = threadIdx.x;
    h[tid] = 0;
    __syncthreads();
    int beg = offs[t * (NB + 1) + b], end = offs[t * (NB + 1) + b + 1];
    const unsigned char* sp = sbuf + (size_t)t * E;
    for (int i = beg + tid; i < end; i += 256) atomicAdd(&h[sp[i]], 1);
    __syncthreads();
    int node = b * 256 + tid;
    if (node < N) {
        int dg = h[tid] < 1 ? 1 : h[tid];
        dro[(size_t)t * N + node] = rsqrtf((float)dg);
    }
}

// ---------------- fp32 -> bf16 convert (+ optional BN affine) --------------
__device__ __forceinline__ unsigned int bfr(float f) {
    unsigned int u = __float_as_uint(f);
    return (u + 0x7FFFu + ((u >> 16) & 1u)) >> 16;   // RNE
}
__device__ __forceinline__ unsigned int pack2(float lo, float hi) {
    return bfr(lo) | (bfr(hi) << 16);
}

__global__ void cvt_bf16(const float* __restrict__ h, const float* __restrict__ ss,
                         unsigned short* __restrict__ h2, int total8) {
    int i = blockIdx.x * 256 + threadIdx.x;
    if (i >= total8) return;
    const float4* hp = (const float4*)h + (size_t)i * 2;
    float4 v0 = hp[0], v1 = hp[1];
    if (ss) {
        int cb = (i & 15) * 8;
        float4 a0 = *(const float4*)&ss[cb];
        float4 a1 = *(const float4*)&ss[cb + 4];
        float4 b0 = *(const float4*)&ss[128 + cb];
        float4 b1 = *(const float4*)&ss[128 + cb + 4];
        v0.x = v0.x * a0.x + b0.x; v0.y = v0.y * a0.y + b0.y;
        v0.z = v0.z * a0.z + b0.z; v0.w = v0.w * a0.w + b0.w;
        v1.x = v1.x * a1.x + b1.x; v1.y = v1.y * a1.y + b1.y;
        v1.z = v1.z * a1.z + b1.z; v1.w = v1.w * a1.w + b1.w;
    }
    uint4 o;
    o.x = pack2(v0.x, v0.y);
    o.y = pack2(v0.z, v0.w);
    o.z = pack2(v1.x, v1.y);
    o.w = pack2(v1.z, v1.w);
    ((uint4*)h2)[i] = o;
}

// ---------------- aggregation (bf16 gather) --------------------------------
// half-wave (32 lanes) per dst node; uint2 (4 bf16) per lane.
__device__ __forceinline__ float blo(unsigned int u) { return __uint_as_float(u << 16); }
__device__ __forceinline__ float bhi(unsigned int u) { return __uint_as_float(u & 0xFFFF0000u); }

__launch_bounds__(256)
__global__ void agg_kernel(const unsigned short* __restrict__ h2, const int* __restrict__ rowptr,
                           const int* __restrict__ esrc, const float* __restrict__ dro,
                           const float* __restrict__ dri, float* __restrict__ z, int N) {
    int idx = blockIdx.x * 256 + threadIdx.x;
    int node = idx >> 5;
    int l2 = idx & 31;
    if (node >= N) return;
    int beg = rowptr[node];
    int end = rowptr[node + 1];
    const uint2* hp = (const uint2*)h2 + l2;   // row s at hp[s*32]
    float4 acc = make_float4(0.f, 0.f, 0.f, 0.f);
    int j = beg;
    for (; j + 4 <= end; j += 4) {
        int s0 = esrc[j], s1 = esrc[j + 1], s2 = esrc[j + 2], s3 = esrc[j + 3];
        float w0 = dro[s0], w1 = dro[s1], w2 = dro[s2], w3 = dro[s3];
        uint2 u0 = hp[(size_t)s0 * 32];
        uint2 u1 = hp[(size_t)s1 * 32];
        uint2 u2 = hp[(size_t)s2 * 32];
        uint2 u3 = hp[(size_t)s3 * 32];
        acc.x += w0 * blo(u0.x) + w1 * blo(u1.x) + w2 * blo(u2.x) + w3 * blo(u3.x);
        acc.y += w0 * bhi(u0.x) + w1 * bhi(u1.x) + w2 * bhi(u2.x) + w3 * bhi(u3.x);
        acc.z += w0 * blo(u0.y) + w1 * blo(u1.y) + w2 * blo(u2.y) + w3 * blo(u3.y);
        acc.w += w0 * bhi(u0.y) + w1 * bhi(u1.y) + w2 * bhi(u2.y) + w3 * bhi(u3.y);
    }
    for (; j < end; ++j) {
        int s0 = esrc[j];
        float w0 = dro[s0];
        uint2 u0 = hp[(size_t)s0 * 32];
        acc.x += w0 * blo(u0.x);
        acc.y += w0 * bhi(u0.x);
        acc.z += w0 * blo(u0.y);
        acc.w += w0 * bhi(u0.y);
    }
    float scl = dri[node];
    acc.x *= scl; acc.y *= scl; acc.z *= scl; acc.w *= scl;
    *(float4*)(z + (size_t)node * 128 + l2 * 4) = acc;
}

// ---------------- GEMM common: XOR-swizzled LDS ----------------------------
// As/Bs flat [32*128]; element (k,m) at k*128 + (m ^ ((k>>2)<<3)).
// Thread tile: rows {rg*4+0..3, rg*4+64..67}, cols {cg*4+0..3, cg*4+64..67}.
__device__ __forceinline__ int sidx(int k, int m) { return k * 128 + (m ^ ((k >> 2) << 3)); }

// ---------------- fused 2-type GEMM: z1io = z0@W0 + z1io@W1 + (b0+b1+b2) ---
__launch_bounds__(256, 3)
__global__ void gemm_gc2(const float* __restrict__ z0, float* __restrict__ z1io,
                         const float* __restrict__ W01, const float* __restrict__ b3,
                         int M) {
    __shared__ float As[32 * 128];
    __shared__ float Bs[32 * 128];
    const int tid = threadIdx.x;
    const int m0 = blockIdx.x * 128;
    const int rg = tid >> 4, cg = tid & 15;
    const int r0 = rg * 4, c0 = cg * 4;
    float acc[8][8] = {};

    for (int ch = 0; ch < 8; ++ch) {
        const float* Zc = (ch < 4) ? z0 : z1io;
        const int k0 = (ch & 3) * 32;
        float4 av[4];
        int ar[4], ak[4];
#pragma unroll
        for (int i = 0; i < 4; ++i) {
            int fi = i * 256 + tid;
            int r = fi >> 3;
            int c4 = (fi & 7) * 4;
            ar[i] = r; ak[i] = c4;
            int gr = m0 + r;
            av[i] = (gr < M) ? *(const float4*)(Zc + (size_t)gr * 128 + k0 + c4)
                             : make_float4(0.f, 0.f, 0.f, 0.f);
        }
        float4 bv[4];
        int bk[4], bn[4];
#pragma unroll
        for (int i = 0; i < 4; ++i) {
            int fi = i * 256 + tid;
            bk[i] = fi >> 5;
            bn[i] = (fi & 31) * 4;
            bv[i] = *(const float4*)(W01 + (size_t)(ch * 32 + bk[i]) * 128 + bn[i]);
        }
        __syncthreads();
#pragma unroll
        for (int i = 0; i < 4; ++i) {
            As[sidx(ak[i] + 0, ar[i])] = av[i].x;
            As[sidx(ak[i] + 1, ar[i])] = av[i].y;
            As[sidx(ak[i] + 2, ar[i])] = av[i].z;
            As[sidx(ak[i] + 3, ar[i])] = av[i].w;
        }
#pragma unroll
        for (int i = 0; i < 4; ++i)
            *(float4*)&Bs[sidx(bk[i], bn[i])] = bv[i];
        __syncthreads();
#pragma unroll
        for (int k = 0; k < 32; ++k) {
            const int xr = (k >> 2) << 3;
            const int offa = k * 128 + (r0 ^ xr);
            const int offb = k * 128 + (c0 ^ xr);
            float4 a0 = *(const float4*)&As[offa];
            float4 a1 = *(const float4*)&As[offa + 64];
            float4 p0 = *(const float4*)&Bs[offb];
            float4 p1 = *(const float4*)&Bs[offb + 64];
            float a[8] = {a0.x, a0.y, a0.z, a0.w, a1.x, a1.y, a1.z, a1.w};
            float b[8] = {p0.x, p0.y, p0.z, p0.w, p1.x, p1.y, p1.z, p1.w};
#pragma unroll
            for (int r = 0; r < 8; ++r)
#pragma unroll
                for (int c = 0; c < 8; ++c)
                    acc[r][c] += a[r] * b[c];
        }
        __syncthreads();
    }

    float badd[8];
#pragma unroll
    for (int c = 0; c < 8; ++c) {
        int col = (c < 4) ? c0 + c : 64 + c0 + c - 4;
        badd[c] = b3[col] + b3[128 + col] + b3[256 + col];
    }
#pragma unroll
    for (int r = 0; r < 8; ++r) {
        int gr = m0 + r0 + (r & 3) + ((r >= 4) ? 64 : 0);
        if (gr < M) {
            float* cp = z1io + (size_t)gr * 128;
            float4 v0 = {acc[r][0] + badd[0], acc[r][1] + badd[1],
                         acc[r][2] + badd[2], acc[r][3] + badd[3]};
            float4 v1 = {acc[r][4] + badd[4], acc[r][5] + badd[5],
                         acc[r][6] + badd[6], acc[r][7] + badd[7]};
            *(float4*)(cp + c0) = v0;
            *(float4*)(cp + 64 + c0) = v1;
        }
    }
}

// ---------------- fp32 GEMM  C[M,128] (op)= A[M,128] @ B[128,128] ----------
// MODE 1: C += A@B
// MODE 2: C  = relu(A@B + b0), bnsum[c] += col sums, bnsum[128+c] += col sumsq
template <int MODE>
__launch_bounds__(256, 3)
__global__ void gemm128(const float* __restrict__ A, const float* __restrict__ Bm,
                        const float* __restrict__ b0, float* __restrict__ C,
                        float* __restrict__ bnsum, int M) {
    __shared__ float As[32 * 128];
    __shared__ float Bs[32 * 128];
    __shared__ float red[256];

    const int tid = threadIdx.x;
    const int m0 = blockIdx.x * 128;
    const int rg = tid >> 4, cg = tid & 15;
    const int r0 = rg * 4, c0 = cg * 4;
    float acc[8][8] = {};

    for (int k0 = 0; k0 < 128; k0 += 32) {
        float4 av[4];
        int ar[4], ak[4];
#pragma unroll
        for (int i = 0; i < 4; ++i) {
            int fi = i * 256 + tid;
            int r = fi >> 3;
            int c4 = (fi & 7) * 4;
            ar[i] = r; ak[i] = c4;
            int gr = m0 + r;
            av[i] = (gr < M) ? *(const float4*)(A + (size_t)gr * 128 + k0 + c4)
                             : make_float4(0.f, 0.f, 0.f, 0.f);
        }
        float4 bv[4];
        int bk[4], bn[4];
#pragma unroll
        for (int i = 0; i < 4; ++i) {
            int fi = i * 256 + tid;
            bk[i] = fi >> 5;
            bn[i] = (fi & 31) * 4;
            bv[i] = *(const float4*)(Bm + (size_t)(k0 + bk[i]) * 128 + bn[i]);
        }
        __syncthreads();
#pragma unroll
        for (int i = 0; i < 4; ++i) {
            As[sidx(ak[i] + 0, ar[i])] = av[i].x;
            As[sidx(ak[i] + 1, ar[i])] = av[i].y;
            As[sidx(ak[i] + 2, ar[i])] = av[i].z;
            As[sidx(ak[i] + 3, ar[i])] = av[i].w;
        }
#pragma unroll
        for (int i = 0; i < 4; ++i)
            *(float4*)&Bs[sidx(bk[i], bn[i])] = bv[i];
        __syncthreads();
#pragma unroll
        for (int k = 0; k < 32; ++k) {
            const int xr = (k >> 2) << 3;
            const int offa = k * 128 + (r0 ^ xr);
            const int offb = k * 128 + (c0 ^ xr);
            float4 a0 = *(const float4*)&As[offa];
            float4 a1 = *(const float4*)&As[offa + 64];
            float4 p0 = *(const float4*)&Bs[offb];
            float4 p1 = *(const float4*)&Bs[offb + 64];
            float a[8] = {a0.x, a0.y, a0.z, a0.w, a1.x, a1.y, a1.z, a1.w};
            float b[8] = {p0.x, p0.y, p0.z, p0.w, p1.x, p1.y, p1.z, p1.w};
#pragma unroll
            for (int r = 0; r < 8; ++r)
#pragma unroll
                for (int c = 0; c < 8; ++c)
                    acc[r][c] += a[r] * b[c];
        }
        __syncthreads();
    }

    if (MODE == 1) {
#pragma unroll
        for (int r = 0; r < 8; ++r) {
            int gr = m0 + r0 + (r & 3) + ((r >= 4) ? 64 : 0);
            if (gr < M) {
                float* cp = C + (size_t)gr * 128;
                float4 o0 = *(float4*)(cp + c0);
                float4 o1 = *(float4*)(cp + 64 + c0);
                o0.x += acc[r][0]; o0.y += acc[r][1]; o0.z += acc[r][2]; o0.w += acc[r][3];
                o1.x += acc[r][4]; o1.y += acc[r][5]; o1.z += acc[r][6]; o1.w += acc[r][7];
                *(float4*)(cp + c0) = o0;
                *(float4*)(cp + 64 + c0) = o1;
            }
        }
    } else {
        float bias[8];
#pragma unroll
        for (int c = 0; c < 8; ++c) {
            int col = (c < 4) ? c0 + c : 64 + c0 + c - 4;
            bias[c] = b0[col];
        }
        float cs[8] = {}, cq[8] = {};
#pragma unroll
        for (int r = 0; r < 8; ++r) {
            int gr = m0 + r0 + (r & 3) + ((r >= 4) ? 64 : 0);
            if (gr < M) {
                float v[8];
#pragma unroll
                for (int c = 0; c < 8; ++c) {
                    float t = acc[r][c] + bias[c];
                    v[c] = t > 0.f ? t : 0.f;
                    cs[c] += v[c];
                    cq[c] += v[c] * v[c];
                }
                float* cp = C + (size_t)gr * 128;
                float4 v0 = {v[0], v[1], v[2], v[3]};
                float4 v1 = {v[4], v[5], v[6], v[7]};
                *(float4*)(cp + c0) = v0;
                *(float4*)(cp + 64 + c0) = v1;
            }
        }
        red[tid] = 0.f;
        __syncthreads();
#pragma unroll
        for (int c = 0; c < 8; ++c) {
            int col = (c < 4) ? c0 + c : 64 + c0 + c - 4;
            atomicAdd(&red[col], cs[c]);
        }
        __syncthreads();
        float sred = red[tid & 127];
        __syncthreads();
        red[tid] = 0.f;
        __syncthreads();
#pragma unroll
        for (int c = 0; c < 8; ++c) {
            int col = (c < 4) ? c0 + c : 64 + c0 + c - 4;
            atomicAdd(&red[col], cq[c]);
        }
        __syncthreads();
        if (tid < 128) {
            atomicAdd(&bnsum[tid], sred);
            atomicAdd(&bnsum[128 + tid], red[tid]);
        }
    }
}

// ---------------- BN finalize + apply ----------------
__global__ void bn_fin(const float* __restrict__ bnsum, const float* __restrict__ gamma,
                       const float* __restrict__ beta, float* __restrict__ ss, int N) {
    int c = threadIdx.x;
    if (c >= 128) return;
    float invn = 1.0f / (float)N;
    float mean = bnsum[c] * invn;
    float var = bnsum[128 + c] * invn - mean * mean;
    float inv = rsqrtf(var + EPSV);
    float sc = gamma[c] * inv;
    ss[c] = sc;
    ss[128 + c] = beta[c] - mean * sc;
}

__global__ void bn_apply(float* __restrict__ h, const float* __restrict__ ss, int total4) {
    int i = blockIdx.x * 256 + threadIdx.x;
    if (i >= total4) return;
    int c4 = (i & 31) * 4;
    float4 sc = *(const float4*)&ss[c4];
    float4 sh = *(const float4*)&ss[128 + c4];
    float4 v = ((float4*)h)[i];
    v.x = v.x * sc.x + sh.x;
    v.y = v.y * sc.y + sh.y;
    v.z = v.z * sc.z + sh.z;
    v.w = v.w * sc.w + sh.w;
    ((float4*)h)[i] = v;
}

// ---------------------------------------------------------------------------
extern "C" void kernel_launch(void* const* d_in, const int* in_sizes, int n_in,
                              void* d_out, int out_size, void* d_ws, size_t ws_size,
                              hipStream_t stream) {
    const float* x    = (const float*)d_in[0];
    const int*   src  = (const int*)d_in[1];
    const int*   dst  = (const int*)d_in[2];
    const float* gcW0 = (const float*)d_in[3];
    const float* gcb0 = (const float*)d_in[4];
    const float* gcW  = (const float*)d_in[5];
    const float* gcb  = (const float*)d_in[6];
    const float* fcW  = (const float*)d_in[7];
    const float* fcb  = (const float*)d_in[8];
    const float* bng  = (const float*)d_in[9];
    const float* bnb  = (const float*)d_in[10];
    float* out = (float*)d_out;

    const int N = in_sizes[0] / 128;
    const int E = in_sizes[1] / 3;
    const int NB = (N + 255) / 256;   // <= MAXNB for this problem size

    char* w = (char*)d_ws;
    auto alloc = [&](size_t bytes) -> char* {
        char* p = w;
        w += (bytes + 255) & ~(size_t)255;
        return p;
    };
    float* r0   = (float*)alloc((size_t)N * 128 * 4);
    float* r1   = (float*)alloc((size_t)N * 128 * 4);
    float* rC   = (float*)alloc((size_t)N * 128 * 4);
    unsigned short* h2 = (unsigned short*)alloc((size_t)N * 128 * 2);
    int*   esrc = (int*)alloc((size_t)3 * E * 4);
    int*   rowptr = (int*)alloc((size_t)3 * (N + 1) * 4);
    float* dro  = (float*)alloc((size_t)3 * N * 4);
    float* dri  = (float*)alloc((size_t)3 * N * 4);
    int*   chd  = (int*)alloc((size_t)3 * NB * 4);
    int*   chs  = (int*)alloc((size_t)3 * NB * 4);
    int*   offd = (int*)alloc((size_t)3 * (NB + 1) * 4);
    int*   offs = (int*)alloc((size_t)3 * (NB + 1) * 4);
    int*   gcd  = (int*)alloc((size_t)3 * NB * 4);
    int*   gcs  = (int*)alloc((size_t)3 * NB * 4);
    float* bnsum = (float*)alloc(256 * 4);
    float* ss0  = (float*)alloc(256 * 4);
    float* ss1  = (float*)alloc(256 * 4);
    float* ss2  = (float*)alloc(256 * 4);
    // build-only buffers overlap rC (rC first written by layer-0 FC, after build)
    int* dbuf = (int*)rC;
    unsigned char* sbuf = (unsigned char*)(rC + (size_t)N * 128 / 2);  // offset 25.6MB region

    // ---- counting-sort CSR build ----
    hipMemsetAsync(chd, 0, (size_t)3 * NB * 4, stream);
    hipMemsetAsync(chs, 0, (size_t)3 * NB * 4, stream);
    dim3 cg2((E + CH - 1) / CH, 3);
    coarse_hist<<<cg2, 256, 0, stream>>>(src, dst, chd, chs, E, NB);
    scan_off<<<1, MAXNB, 0, stream>>>(chd, chs, offd, offs, gcd, gcs, rowptr, NB, N, E);
    scatter_coarse<<<cg2, 256, 0, stream>>>(src, dst, gcd, gcs, dbuf, sbuf, E, NB);
    dim3 fg(NB, 3);
    fine_dst<<<fg, 256, 0, stream>>>(dbuf, offd, esrc, rowptr, dri, E, N, NB);
    fine_src<<<fg, 256, 0, stream>>>(sbuf, offs, dro, E, N, NB);

    // ---- layers ----
    const int gemmGrid = (N + 127) / 128;
    const int aggGrid = (N * 32 + 255) / 256;
    const int cvtGrid = (N * 16 + 255) / 256;
    float* ssl[3] = {ss0, ss1, ss2};

    // initial bf16 copy of x (no affine)
    cvt_bf16<<<cvtGrid, 256, 0, stream>>>(x, nullptr, h2, N * 16);

    for (int l = 0; l < 3; ++l) {
        const float* Wl = (l == 0) ? gcW0 : gcW + (size_t)(l - 1) * 3 * 128 * 128;
        const float* bl = (l == 0) ? gcb0 : gcb + (size_t)(l - 1) * 3 * 128;

        auto agg = [&](int e, float* zt) {
            agg_kernel<<<aggGrid, 256, 0, stream>>>(h2, rowptr + e * (N + 1),
                                                    esrc + (size_t)e * E, dro + e * N,
                                                    dri + e * N, zt, N);
        };

        agg(0, r0);
        agg(1, r1);
        gemm_gc2<<<gemmGrid, 256, 0, stream>>>(r0, r1, Wl, bl, N);   // r1 = z0@W0+z1@W1+Σb
        agg(2, r0);
        gemm128<1><<<gemmGrid, 256, 0, stream>>>(r0, Wl + 2 * 128 * 128, nullptr, r1, nullptr, N);

        hipMemsetAsync(bnsum, 0, 256 * 4, stream);
        float* fcTarget = (l == 2) ? out : rC;
        gemm128<2><<<gemmGrid, 256, 0, stream>>>(r1, fcW + (size_t)l * 128 * 128,
                                                 fcb + (size_t)l * 128, fcTarget, bnsum, N);
        bn_fin<<<1, 128, 0, stream>>>(bnsum, bng + (size_t)l * 128, bnb + (size_t)l * 128,
                                      ssl[l], N);
        if (l < 2)
            cvt_bf16<<<cvtGrid, 256, 0, stream>>>(rC, ssl[l], h2, N * 16);  // post-BN bf16
        else
            bn_apply<<<(N * 32 + 255) / 256, 256, 0, stream>>>(out, ssl[l], N * 32);
    }
}

// Round 5
// 1076.371 us; speedup vs baseline: 2.5944x; 1.5021x over previous
//
#include <hip/hip_runtime.h>

// ---------------------------------------------------------------------------
// Encoder: 3-layer HeteroGraphConv(3 edge types) -> FC -> ReLU -> BatchNorm
// Round 5:
//   * ALL GEMMs -> bf16 MFMA (16x16x32), fp32 accumulate, no-LDS main loop:
//     A-frags from global bf16 rows, B-frags from fragment-packed weights
//   * hetero GEMM fused across 3 edge types (K=384), epilogue writes bf16
//   * FC fused ReLU+BN-stats; writes bf16 into h2 (l<2) or fp32 out (l=2)
//   * agg emits bf16 z directly; counting-sort CSR build unchanged
// ---------------------------------------------------------------------------

#define EPSV 1e-5f
#define CH 8192      // edges per block in coarse passes
#define MAXNB 512    // max coarse bins (N <= 131072)

typedef __attribute__((ext_vector_type(8))) short s8v;   // 8 bf16 = 4 VGPR
typedef __attribute__((ext_vector_type(4))) float f4v;   // 4 f32 acc

// ---------------- build phase 1: coarse histograms (both keys) -------------
__global__ void coarse_hist(const int* __restrict__ src, const int* __restrict__ dst,
                            int* __restrict__ chd, int* __restrict__ chs,
                            int E, int NB) {
    __shared__ int hd[MAXNB], hs[MAXNB];
    int t = blockIdx.y;
    for (int i = threadIdx.x; i < NB; i += 256) { hd[i] = 0; hs[i] = 0; }
    __syncthreads();
    int base = blockIdx.x * CH;
    int end = base + CH < E ? base + CH : E;
    const int* sp = src + (size_t)t * E;
    const int* dp = dst + (size_t)t * E;
    for (int i = base + threadIdx.x; i < end; i += 256) {
        atomicAdd(&hd[dp[i] >> 8], 1);
        atomicAdd(&hs[sp[i] >> 8], 1);
    }
    __syncthreads();
    for (int b = threadIdx.x; b < NB; b += 256) {
        if (hd[b]) atomicAdd(&chd[t * NB + b], hd[b]);
        if (hs[b]) atomicAdd(&chs[t * NB + b], hs[b]);
    }
}

// ---------------- build phase 2: scan coarse bins -> offsets + cursors -----
__global__ void scan_off(const int* __restrict__ chd, const int* __restrict__ chs,
                         int* __restrict__ offd, int* __restrict__ offs,
                         int* __restrict__ gcd, int* __restrict__ gcs,
                         int* __restrict__ rowptr, int NB, int N, int E) {
    __shared__ int s[MAXNB];
    int tid = threadIdx.x;
    for (int a = 0; a < 6; ++a) {
        const int* h = (a < 3) ? chd + a * NB : chs + (a - 3) * NB;
        int* off = (a < 3) ? offd + a * (NB + 1) : offs + (a - 3) * (NB + 1);
        int* gc = (a < 3) ? gcd + a * NB : gcs + (a - 3) * NB;
        s[tid] = (tid < NB) ? h[tid] : 0;
        __syncthreads();
        for (int o = 1; o < MAXNB; o <<= 1) {
            int v = (tid >= o) ? s[tid - o] : 0;
            __syncthreads();
            s[tid] += v;
            __syncthreads();
        }
        if (tid < NB) {
            off[tid + 1] = s[tid];
            if (tid == 0) off[0] = 0;
        }
        __syncthreads();
        if (tid < NB) gc[tid] = off[tid];
        __syncthreads();
    }
    if (tid < 3) rowptr[tid * (N + 1) + N] = E;
}

// ---------------- build phase 3: scatter edges to coarse bins --------------
__global__ void scatter_coarse(const int* __restrict__ src, const int* __restrict__ dst,
                               int* __restrict__ gcd, int* __restrict__ gcs,
                               int* __restrict__ dbuf, unsigned char* __restrict__ sbuf,
                               int E, int NB) {
    __shared__ int hd[MAXNB], hs[MAXNB], bd[MAXNB], bs[MAXNB];
    int t = blockIdx.y;
    for (int i = threadIdx.x; i < NB; i += 256) { hd[i] = 0; hs[i] = 0; }
    __syncthreads();
    int base = blockIdx.x * CH;
    int end = base + CH < E ? base + CH : E;
    const int* sp = src + (size_t)t * E;
    const int* dp = dst + (size_t)t * E;
    for (int i = base + threadIdx.x; i < end; i += 256) {
        atomicAdd(&hd[dp[i] >> 8], 1);
        atomicAdd(&hs[sp[i] >> 8], 1);
    }
    __syncthreads();
    for (int b = threadIdx.x; b < NB; b += 256) {
        bd[b] = hd[b] ? atomicAdd(&gcd[t * NB + b], hd[b]) : 0;
        bs[b] = hs[b] ? atomicAdd(&gcs[t * NB + b], hs[b]) : 0;
        hd[b] = 0;
        hs[b] = 0;
    }
    __syncthreads();
    for (int i = base + threadIdx.x; i < end; i += 256) {
        int sv = sp[i], dv = dp[i];
        int pb = dv >> 8;
        int pos = bd[pb] + atomicAdd(&hd[pb], 1);
        dbuf[(size_t)t * E + pos] = (sv << 8) | (dv & 255);
        int sb = sv >> 8;
        int ps = bs[sb] + atomicAdd(&hs[sb], 1);
        sbuf[(size_t)t * E + ps] = (unsigned char)(sv & 255);
    }
}

// ---------------- build phase 4a: fine sort by dst -> compact CSR ----------
__global__ void fine_dst(const int* __restrict__ dbuf, const int* __restrict__ offd,
                         int* __restrict__ esrc, int* __restrict__ rowptr,
                         float* __restrict__ dri, int E, int N, int NB) {
    __shared__ int h[256], sc[256], cur[256];
    int b = blockIdx.x, t = blockIdx.y;
    int tid = threadIdx.x;
    h[tid] = 0;
    __syncthreads();
    int beg = offd[t * (NB + 1) + b], end = offd[t * (NB + 1) + b + 1];
    const int* dp = dbuf + (size_t)t * E;
    for (int i = beg + tid; i < end; i += 256) atomicAdd(&h[dp[i] & 255], 1);
    __syncthreads();
    sc[tid] = h[tid];
    __syncthreads();
    for (int o = 1; o < 256; o <<= 1) {
        int v = (tid >= o) ? sc[tid - o] : 0;
        __syncthreads();
        sc[tid] += v;
        __syncthreads();
    }
    int excl = sc[tid] - h[tid];
    cur[tid] = excl;
    int node = b * 256 + tid;
    if (node < N) {
        rowptr[t * (N + 1) + node] = beg + excl;
        int dg = h[tid] < 1 ? 1 : h[tid];
        dri[(size_t)t * N + node] = rsqrtf((float)dg);
    }
    __syncthreads();
    for (int i = beg + tid; i < end; i += 256) {
        int v = dp[i];
        int f = v & 255;
        int pos = beg + atomicAdd(&cur[f], 1);
        esrc[(size_t)t * E + pos] = v >> 8;
    }
}

// ---------------- build phase 4b: fine histogram by src -> dro -------------
__global__ void fine_src(const unsigned char* __restrict__ sbuf, const int* __restrict__ offs,
                         float* __restrict__ dro, int E, int N, int NB) {
    __shared__ int h[256];
    int b = blockIdx.x, t = blockIdx.y;
    int tid = threadIdx.x;
    h[tid] = 0;
    __syncthreads();
    int beg = offs[t * (NB + 1) + b], end = offs[t * (NB + 1) + b + 1];
    const unsigned char* sp = sbuf + (size_t)t * E;
    for (int i = beg + tid; i < end; i += 256) atomicAdd(&h[sp[i]], 1);
    __syncthreads();
    int node = b * 256 + tid;
    if (node < N) {
        int dg = h[tid] < 1 ? 1 : h[tid];
        dro[(size_t)t * N + node] = rsqrtf((float)dg);
    }
}

// ---------------- bf16 helpers ----------------
__device__ __forceinline__ unsigned int bfr(float f) {
    unsigned int u = __float_as_uint(f);
    return (u + 0x7FFFu + ((u >> 16) & 1u)) >> 16;   // RNE
}
__device__ __forceinline__ unsigned int pack2(float lo, float hi) {
    return bfr(lo) | (bfr(hi) << 16);
}
__device__ __forceinline__ float blo(unsigned int u) { return __uint_as_float(u << 16); }
__device__ __forceinline__ float bhi(unsigned int u) { return __uint_as_float(u & 0xFFFF0000u); }

// ---------------- fp32 -> bf16 convert (initial x copy) --------------------
__global__ void cvt_bf16(const float* __restrict__ h, unsigned short* __restrict__ h2,
                         int total8) {
    int i = blockIdx.x * 256 + threadIdx.x;
    if (i >= total8) return;
    const float4* hp = (const float4*)h + (size_t)i * 2;
    float4 v0 = hp[0], v1 = hp[1];
    uint4 o;
    o.x = pack2(v0.x, v0.y);
    o.y = pack2(v0.z, v0.w);
    o.z = pack2(v1.x, v1.y);
    o.w = pack2(v1.z, v1.w);
    ((uint4*)h2)[i] = o;
}

// ---------------- weight packing: fragment-ordered bf16 --------------------
// packed elem p = ks*4096 + nt*512 + lane*8 + j  <-  W[ks*32+(lane>>4)*8+j][nt*16+(lane&15)]
__global__ void pack_w(const float* __restrict__ gcW0, const float* __restrict__ gcW,
                       const float* __restrict__ fcW, unsigned short* __restrict__ Wg,
                       unsigned short* __restrict__ Wf) {
    int mat = blockIdx.x;   // 0..8 = gc (l*3+e), 9..11 = fc layer
    const float* srcp;
    unsigned short* dstp;
    if (mat < 9) {
        int l = mat / 3, e = mat % 3;
        srcp = (l == 0) ? gcW0 + (size_t)e * 16384
                        : gcW + ((size_t)(l - 1) * 3 + e) * 16384;
        dstp = Wg + (size_t)mat * 16384;
    } else {
        srcp = fcW + (size_t)(mat - 9) * 16384;
        dstp = Wf + (size_t)(mat - 9) * 16384;
    }
    for (int p = threadIdx.x; p < 16384; p += 256) {
        int j = p & 7;
        int ln = (p >> 3) & 63;
        int nt = (p >> 9) & 7;
        int ks = p >> 12;
        int k = ks * 32 + (ln >> 4) * 8 + j;
        int n = nt * 16 + (ln & 15);
        dstp[p] = (unsigned short)bfr(srcp[k * 128 + n]);
    }
}

// ---------------- aggregation (bf16 gather -> bf16 z) ----------------------
__launch_bounds__(256)
__global__ void agg_kernel(const unsigned short* __restrict__ h2, const int* __restrict__ rowptr,
                           const int* __restrict__ esrc, const float* __restrict__ dro,
                           const float* __restrict__ dri, unsigned short* __restrict__ z, int N) {
    int idx = blockIdx.x * 256 + threadIdx.x;
    int node = idx >> 5;
    int l2 = idx & 31;
    if (node >= N) return;
    int beg = rowptr[node];
    int end = rowptr[node + 1];
    const uint2* hp = (const uint2*)h2 + l2;   // row s at hp[s*32]
    float4 acc = make_float4(0.f, 0.f, 0.f, 0.f);
    int j = beg;
    for (; j + 4 <= end; j += 4) {
        int s0 = esrc[j], s1 = esrc[j + 1], s2 = esrc[j + 2], s3 = esrc[j + 3];
        float w0 = dro[s0], w1 = dro[s1], w2 = dro[s2], w3 = dro[s3];
        uint2 u0 = hp[(size_t)s0 * 32];
        uint2 u1 = hp[(size_t)s1 * 32];
        uint2 u2 = hp[(size_t)s2 * 32];
        uint2 u3 = hp[(size_t)s3 * 32];
        acc.x += w0 * blo(u0.x) + w1 * blo(u1.x) + w2 * blo(u2.x) + w3 * blo(u3.x);
        acc.y += w0 * bhi(u0.x) + w1 * bhi(u1.x) + w2 * bhi(u2.x) + w3 * bhi(u3.x);
        acc.z += w0 * blo(u0.y) + w1 * blo(u1.y) + w2 * blo(u2.y) + w3 * blo(u3.y);
        acc.w += w0 * bhi(u0.y) + w1 * bhi(u1.y) + w2 * bhi(u2.y) + w3 * bhi(u3.y);
    }
    for (; j < end; ++j) {
        int s0 = esrc[j];
        float w0 = dro[s0];
        uint2 u0 = hp[(size_t)s0 * 32];
        acc.x += w0 * blo(u0.x);
        acc.y += w0 * bhi(u0.x);
        acc.z += w0 * blo(u0.y);
        acc.w += w0 * bhi(u0.y);
    }
    float scl = dri[node];
    uint2 o;
    o.x = pack2(acc.x * scl, acc.y * scl);
    o.y = pack2(acc.z * scl, acc.w * scl);
    *(uint2*)(z + (size_t)node * 128 + l2 * 4) = o;
}

// ---------------- hetero MFMA GEMM: C = [z0|z1|z2] @ Wcat + sum(bias) ------
// 128x128 block, 4 waves (2x2), each 64x64; no LDS, no barriers.
__launch_bounds__(256)
__global__ void mfma_gc(const unsigned short* __restrict__ z0,
                        const unsigned short* __restrict__ z1,
                        const unsigned short* __restrict__ z2,
                        const unsigned short* __restrict__ Wp,
                        const float* __restrict__ b3,
                        unsigned short* __restrict__ C, int M) {
    const int tid = threadIdx.x;
    const int l = tid & 63;
    const int wv = tid >> 6;
    const int wm = wv >> 1, wn = wv & 1;
    const int m0 = blockIdx.x * 128;
    const int lr = l & 15;
    const int lk = (l >> 4) * 8;
    f4v acc[4][4];
#pragma unroll
    for (int i = 0; i < 4; ++i)
#pragma unroll
        for (int j = 0; j < 4; ++j) acc[i][j] = (f4v){0.f, 0.f, 0.f, 0.f};

    int rowb[4];
#pragma unroll
    for (int mt = 0; mt < 4; ++mt) {
        int r = m0 + wm * 64 + mt * 16 + lr;
        rowb[mt] = (r < M) ? r : (M - 1);
    }
#pragma unroll
    for (int e = 0; e < 3; ++e) {
        const unsigned short* zp = (e == 0) ? z0 : (e == 1) ? z1 : z2;
        const unsigned short* wp = Wp + (size_t)e * 16384;
#pragma unroll
        for (int ks = 0; ks < 4; ++ks) {
            s8v a[4], b[4];
#pragma unroll
            for (int mt = 0; mt < 4; ++mt)
                a[mt] = *(const s8v*)(zp + (size_t)rowb[mt] * 128 + ks * 32 + lk);
#pragma unroll
            for (int nt = 0; nt < 4; ++nt)
                b[nt] = *(const s8v*)(wp + ks * 4096 + (wn * 4 + nt) * 512 + l * 8);
#pragma unroll
            for (int mt = 0; mt < 4; ++mt)
#pragma unroll
                for (int nt = 0; nt < 4; ++nt)
                    acc[mt][nt] = __builtin_amdgcn_mfma_f32_16x16x32_bf16(
                        a[mt], b[nt], acc[mt][nt], 0, 0, 0);
        }
    }
    float bs[4];
    int col[4];
#pragma unroll
    for (int nt = 0; nt < 4; ++nt) {
        col[nt] = wn * 64 + nt * 16 + lr;
        bs[nt] = b3[col[nt]] + b3[128 + col[nt]] + b3[256 + col[nt]];
    }
#pragma unroll
    for (int mt = 0; mt < 4; ++mt) {
#pragma unroll
        for (int r = 0; r < 4; ++r) {
            int row = m0 + wm * 64 + mt * 16 + (l >> 4) * 4 + r;
            if (row < M) {
                unsigned short* cp = C + (size_t)row * 128;
#pragma unroll
                for (int nt = 0; nt < 4; ++nt)
                    cp[col[nt]] = (unsigned short)bfr(acc[mt][nt][r] + bs[nt]);
            }
        }
    }
}

// ---------------- FC MFMA GEMM + ReLU + BN stats ---------------------------
// MODE 0: write bf16 (pre-BN h) into outb; MODE 1: write fp32 into outf.
template <int MODE>
__launch_bounds__(256)
__global__ void mfma_fc(const unsigned short* __restrict__ A,
                        const unsigned short* __restrict__ Wp,
                        const float* __restrict__ bias,
                        unsigned short* __restrict__ outb, float* __restrict__ outf,
                        float* __restrict__ bnsum, int M) {
    __shared__ float red[256];
    const int tid = threadIdx.x;
    const int l = tid & 63;
    const int wv = tid >> 6;
    const int wm = wv >> 1, wn = wv & 1;
    const int m0 = blockIdx.x * 128;
    const int lr = l & 15;
    const int lk = (l >> 4) * 8;
    f4v acc[4][4];
#pragma unroll
    for (int i = 0; i < 4; ++i)
#pragma unroll
        for (int j = 0; j < 4; ++j) acc[i][j] = (f4v){0.f, 0.f, 0.f, 0.f};

    int rowb[4];
#pragma unroll
    for (int mt = 0; mt < 4; ++mt) {
        int r = m0 + wm * 64 + mt * 16 + lr;
        rowb[mt] = (r < M) ? r : (M - 1);
    }
#pragma unroll
    for (int ks = 0; ks < 4; ++ks) {
        s8v a[4], b[4];
#pragma unroll
        for (int mt = 0; mt < 4; ++mt)
            a[mt] = *(const s8v*)(A + (size_t)rowb[mt] * 128 + ks * 32 + lk);
#pragma unroll
        for (int nt = 0; nt < 4; ++nt)
            b[nt] = *(const s8v*)(Wp + ks * 4096 + (wn * 4 + nt) * 512 + l * 8);
#pragma unroll
        for (int mt = 0; mt < 4; ++mt)
#pragma unroll
            for (int nt = 0; nt < 4; ++nt)
                acc[mt][nt] = __builtin_amdgcn_mfma_f32_16x16x32_bf16(
                    a[mt], b[nt], acc[mt][nt], 0, 0, 0);
    }

    float bv[4], cs[4] = {}, cq[4] = {};
    int col[4];
#pragma unroll
    for (int nt = 0; nt < 4; ++nt) {
        col[nt] = wn * 64 + nt * 16 + lr;
        bv[nt] = bias[col[nt]];
    }
#pragma unroll
    for (int mt = 0; mt < 4; ++mt) {
#pragma unroll
        for (int r = 0; r < 4; ++r) {
            int row = m0 + wm * 64 + mt * 16 + (l >> 4) * 4 + r;
            if (row < M) {
#pragma unroll
                for (int nt = 0; nt < 4; ++nt) {
                    float v = acc[mt][nt][r] + bv[nt];
                    v = v > 0.f ? v : 0.f;
                    cs[nt] += v;
                    cq[nt] += v * v;
                    if (MODE == 0)
                        outb[(size_t)row * 128 + col[nt]] = (unsigned short)bfr(v);
                    else
                        outf[(size_t)row * 128 + col[nt]] = v;
                }
            }
        }
    }
    red[tid] = 0.f;
    __syncthreads();
#pragma unroll
    for (int nt = 0; nt < 4; ++nt) {
        atomicAdd(&red[col[nt]], cs[nt]);
        atomicAdd(&red[128 + col[nt]], cq[nt]);
    }
    __syncthreads();
    if (tid < 128) {
        atomicAdd(&bnsum[tid], red[tid]);
        atomicAdd(&bnsum[128 + tid], red[128 + tid]);
    }
}

// ---------------- BN finalize / apply ----------------
__global__ void bn_fin(const float* __restrict__ bnsum, const float* __restrict__ gamma,
                       const float* __restrict__ beta, float* __restrict__ ss, int N) {
    int c = threadIdx.x;
    if (c >= 128) return;
    float invn = 1.0f / (float)N;
    float mean = bnsum[c] * invn;
    float var = bnsum[128 + c] * invn - mean * mean;
    float inv = rsqrtf(var + EPSV);
    float sc = gamma[c] * inv;
    ss[c] = sc;
    ss[128 + c] = beta[c] - mean * sc;
}

// in-place BN affine on bf16 h2
__global__ void bn_affine_bf16(unsigned short* __restrict__ h2, const float* __restrict__ ss,
                               int total8) {
    int i = blockIdx.x * 256 + threadIdx.x;
    if (i >= total8) return;
    uint4 v = ((const uint4*)h2)[i];
    int cb = (i & 15) * 8;
    float4 a0 = *(const float4*)&ss[cb];
    float4 a1 = *(const float4*)&ss[cb + 4];
    float4 b0 = *(const float4*)&ss[128 + cb];
    float4 b1 = *(const float4*)&ss[128 + cb + 4];
    uint4 o;
    o.x = pack2(blo(v.x) * a0.x + b0.x, bhi(v.x) * a0.y + b0.y);
    o.y = pack2(blo(v.y) * a0.z + b0.z, bhi(v.y) * a0.w + b0.w);
    o.z = pack2(blo(v.z) * a1.x + b1.x, bhi(v.z) * a1.y + b1.y);
    o.w = pack2(blo(v.w) * a1.z + b1.z, bhi(v.w) * a1.w + b1.w);
    ((uint4*)h2)[i] = o;
}

__global__ void bn_apply(float* __restrict__ h, const float* __restrict__ ss, int total4) {
    int i = blockIdx.x * 256 + threadIdx.x;
    if (i >= total4) return;
    int c4 = (i & 31) * 4;
    float4 sc = *(const float4*)&ss[c4];
    float4 sh = *(const float4*)&ss[128 + c4];
    float4 v = ((float4*)h)[i];
    v.x = v.x * sc.x + sh.x;
    v.y = v.y * sc.y + sh.y;
    v.z = v.z * sc.z + sh.z;
    v.w = v.w * sc.w + sh.w;
    ((float4*)h)[i] = v;
}

// ---------------------------------------------------------------------------
extern "C" void kernel_launch(void* const* d_in, const int* in_sizes, int n_in,
                              void* d_out, int out_size, void* d_ws, size_t ws_size,
                              hipStream_t stream) {
    const float* x    = (const float*)d_in[0];
    const int*   src  = (const int*)d_in[1];
    const int*   dst  = (const int*)d_in[2];
    const float* gcW0 = (const float*)d_in[3];
    const float* gcb0 = (const float*)d_in[4];
    const float* gcW  = (const float*)d_in[5];
    const float* gcb  = (const float*)d_in[6];
    const float* fcW  = (const float*)d_in[7];
    const float* fcb  = (const float*)d_in[8];
    const float* bng  = (const float*)d_in[9];
    const float* bnb  = (const float*)d_in[10];
    float* out = (float*)d_out;

    const int N = in_sizes[0] / 128;
    const int E = in_sizes[1] / 3;
    const int NB = (N + 255) / 256;   // <= MAXNB for this problem size

    char* w = (char*)d_ws;
    auto alloc = [&](size_t bytes) -> char* {
        char* p = w;
        w += (bytes + 255) & ~(size_t)255;
        return p;
    };
    unsigned short* z0    = (unsigned short*)alloc((size_t)N * 128 * 2);
    unsigned short* z1    = (unsigned short*)alloc((size_t)N * 128 * 2);
    unsigned short* z2    = (unsigned short*)alloc((size_t)N * 128 * 2);
    unsigned short* gcout = (unsigned short*)alloc((size_t)N * 128 * 2);
    unsigned short* h2    = (unsigned short*)alloc((size_t)N * 128 * 2);
    unsigned short* Wg    = (unsigned short*)alloc((size_t)9 * 16384 * 2);
    unsigned short* Wf    = (unsigned short*)alloc((size_t)3 * 16384 * 2);
    int*   esrc   = (int*)alloc((size_t)3 * E * 4);
    int*   rowptr = (int*)alloc((size_t)3 * (N + 1) * 4);
    float* dro    = (float*)alloc((size_t)3 * N * 4);
    float* dri    = (float*)alloc((size_t)3 * N * 4);
    int*   chd    = (int*)alloc((size_t)3 * NB * 4);
    int*   chs    = (int*)alloc((size_t)3 * NB * 4);
    int*   offd   = (int*)alloc((size_t)3 * (NB + 1) * 4);
    int*   offs   = (int*)alloc((size_t)3 * (NB + 1) * 4);
    int*   gcd    = (int*)alloc((size_t)3 * NB * 4);
    int*   gcs    = (int*)alloc((size_t)3 * NB * 4);
    float* bnsum  = (float*)alloc(256 * 4);
    float* ss0    = (float*)alloc(256 * 4);
    float* ss1    = (float*)alloc(256 * 4);
    float* ss2    = (float*)alloc(256 * 4);
    // build-only buffers alias layer buffers (build completes before first use)
    int* dbuf = (int*)gcout;                 // needs 3E*4 = 19.2MB <= 25.6MB
    unsigned char* sbuf = (unsigned char*)z2;  // needs 3E = 4.8MB

    // ---- counting-sort CSR build ----
    hipMemsetAsync(chd, 0, (size_t)3 * NB * 4, stream);
    hipMemsetAsync(chs, 0, (size_t)3 * NB * 4, stream);
    dim3 cg2((E + CH - 1) / CH, 3);
    coarse_hist<<<cg2, 256, 0, stream>>>(src, dst, chd, chs, E, NB);
    scan_off<<<1, MAXNB, 0, stream>>>(chd, chs, offd, offs, gcd, gcs, rowptr, NB, N, E);
    scatter_coarse<<<cg2, 256, 0, stream>>>(src, dst, gcd, gcs, dbuf, sbuf, E, NB);
    dim3 fg(NB, 3);
    fine_dst<<<fg, 256, 0, stream>>>(dbuf, offd, esrc, rowptr, dri, E, N, NB);
    fine_src<<<fg, 256, 0, stream>>>(sbuf, offs, dro, E, N, NB);

    // ---- weight packing + initial bf16 x ----
    pack_w<<<12, 256, 0, stream>>>(gcW0, gcW, fcW, Wg, Wf);
    const int cvtGrid = (N * 16 + 255) / 256;
    cvt_bf16<<<cvtGrid, 256, 0, stream>>>(x, h2, N * 16);

    // ---- layers ----
    const int gemmGrid = (N + 127) / 128;
    const int aggGrid = (N * 32 + 255) / 256;
    float* ssl[3] = {ss0, ss1, ss2};
    unsigned short* zb[3] = {z0, z1, z2};

    for (int l = 0; l < 3; ++l) {
        const float* bl = (l == 0) ? gcb0 : gcb + (size_t)(l - 1) * 3 * 128;
        for (int e = 0; e < 3; ++e)
            agg_kernel<<<aggGrid, 256, 0, stream>>>(h2, rowptr + e * (N + 1),
                                                    esrc + (size_t)e * E, dro + e * N,
                                                    dri + e * N, zb[e], N);
        mfma_gc<<<gemmGrid, 256, 0, stream>>>(z0, z1, z2, Wg + (size_t)l * 3 * 16384,
                                              bl, gcout, N);
        hipMemsetAsync(bnsum, 0, 256 * 4, stream);
        if (l < 2)
            mfma_fc<0><<<gemmGrid, 256, 0, stream>>>(gcout, Wf + (size_t)l * 16384,
                                                     fcb + (size_t)l * 128, h2, nullptr,
                                                     bnsum, N);
        else
            mfma_fc<1><<<gemmGrid, 256, 0, stream>>>(gcout, Wf + (size_t)l * 16384,
                                                     fcb + (size_t)l * 128, nullptr, out,
                                                     bnsum, N);
        bn_fin<<<1, 128, 0, stream>>>(bnsum, bng + (size_t)l * 128, bnb + (size_t)l * 128,
                                      ssl[l], N);
        if (l < 2)
            bn_affine_bf16<<<cvtGrid, 256, 0, stream>>>(h2, ssl[l], N * 16);
        else
            bn_apply<<<(N * 32 + 255) / 256, 256, 0, stream>>>(out, ssl[l], N * 32);
    }
}

// Round 6
// 997.338 us; speedup vs baseline: 2.8000x; 1.0792x over previous
//
#include <hip/hip_runtime.h>

// ---------------------------------------------------------------------------
// Encoder: 3-layer HeteroGraphConv(3 edge types) -> FC -> ReLU -> BatchNorm
// Round 6:
//   * multi-split scatter_coarse: LDS reorder -> coalesced bin-run writes
//     (write-allocate traffic ~5-8x down)
//   * fine_dst: LDS-staged bin sort -> linear esrc writes
//   * agg: 16 lanes/node, uint4 loads, 8 rows in flight, 3 types per dispatch
//   * bn_fin folded into bn_affine_bf16 / bn_apply (LDS-computed scale/shift)
//   * MFMA GEMMs (16x16x32 bf16) unchanged from round 5
// ---------------------------------------------------------------------------

#define EPSV 1e-5f
#define CH 4096      // edges per block in coarse passes
#define MAXNB 512    // max coarse bins (N <= 131072)

typedef __attribute__((ext_vector_type(8))) short s8v;   // 8 bf16 = 4 VGPR
typedef __attribute__((ext_vector_type(4))) float f4v;   // 4 f32 acc

// ---------------- build phase 1: coarse histograms (both keys) -------------
__global__ void coarse_hist(const int* __restrict__ src, const int* __restrict__ dst,
                            int* __restrict__ chd, int* __restrict__ chs,
                            int E, int NB) {
    __shared__ int hd[MAXNB], hs[MAXNB];
    int t = blockIdx.y;
    for (int i = threadIdx.x; i < MAXNB; i += 256) { hd[i] = 0; hs[i] = 0; }
    __syncthreads();
    int base = blockIdx.x * CH;
    int end = base + CH < E ? base + CH : E;
    const int* sp = src + (size_t)t * E;
    const int* dp = dst + (size_t)t * E;
    for (int i = base + threadIdx.x; i < end; i += 256) {
        atomicAdd(&hd[dp[i] >> 8], 1);
        atomicAdd(&hs[sp[i] >> 8], 1);
    }
    __syncthreads();
    for (int b = threadIdx.x; b < NB; b += 256) {
        if (hd[b]) atomicAdd(&chd[t * NB + b], hd[b]);
        if (hs[b]) atomicAdd(&chs[t * NB + b], hs[b]);
    }
}

// ---------------- build phase 2: scan coarse bins -> offsets + cursors -----
__global__ void scan_off(const int* __restrict__ chd, const int* __restrict__ chs,
                         int* __restrict__ offd, int* __restrict__ offs,
                         int* __restrict__ gcd, int* __restrict__ gcs,
                         int* __restrict__ rowptr, int NB, int N, int E) {
    __shared__ int s[MAXNB];
    int tid = threadIdx.x;
    for (int a = 0; a < 6; ++a) {
        const int* h = (a < 3) ? chd + a * NB : chs + (a - 3) * NB;
        int* off = (a < 3) ? offd + a * (NB + 1) : offs + (a - 3) * (NB + 1);
        int* gc = (a < 3) ? gcd + a * NB : gcs + (a - 3) * NB;
        s[tid] = (tid < NB) ? h[tid] : 0;
        __syncthreads();
        for (int o = 1; o < MAXNB; o <<= 1) {
            int v = (tid >= o) ? s[tid - o] : 0;
            __syncthreads();
            s[tid] += v;
            __syncthreads();
        }
        if (tid < NB) {
            off[tid + 1] = s[tid];
            if (tid == 0) off[0] = 0;
        }
        __syncthreads();
        if (tid < NB) gc[tid] = off[tid];
        __syncthreads();
    }
    if (tid < 3) rowptr[tid * (N + 1) + N] = E;
}

// ---------------- build phase 3: multi-split scatter (LDS reorder) ---------
__launch_bounds__(256)
__global__ void scatter_coarse(const int* __restrict__ src, const int* __restrict__ dst,
                               int* __restrict__ gcd, int* __restrict__ gcs,
                               int* __restrict__ dbuf, unsigned char* __restrict__ sbuf,
                               int E, int NB) {
    __shared__ int hd[MAXNB], hs[MAXNB];     // counts -> local cursors
    __shared__ int lod[MAXNB], los[MAXNB];   // inclusive scans
    __shared__ int bd[MAXNB], bs[MAXNB];     // global bases
    __shared__ int rbi[CH];                  // reordered dst records
    __shared__ unsigned char rbs[CH];        // reordered src low bytes
    const int tid = threadIdx.x;
    const int t = blockIdx.y;
    const int base = blockIdx.x * CH;
    const int end = base + CH < E ? base + CH : E;
    const int cnt = end - base;
    const int* sp = src + (size_t)t * E;
    const int* dp = dst + (size_t)t * E;

    for (int i = tid; i < MAXNB; i += 256) { hd[i] = 0; hs[i] = 0; }
    __syncthreads();
    for (int i = base + tid; i < end; i += 256) {
        atomicAdd(&hd[dp[i] >> 8], 1);
        atomicAdd(&hs[sp[i] >> 8], 1);
    }
    __syncthreads();
    // reserve global ranges
    for (int b = tid; b < NB; b += 256) {
        bd[b] = hd[b] ? atomicAdd(&gcd[t * NB + b], hd[b]) : 0;
        bs[b] = hs[b] ? atomicAdd(&gcs[t * NB + b], hs[b]) : 0;
    }
    // copy counts for scan
    lod[tid] = hd[tid]; lod[tid + 256] = hd[tid + 256];
    los[tid] = hs[tid]; los[tid + 256] = hs[tid + 256];
    __syncthreads();
    // Hillis-Steele inclusive scan over 512 (both arrays)
    for (int o = 1; o < MAXNB; o <<= 1) {
        int a0 = lod[tid], a1 = lod[tid + 256];
        int b0 = los[tid], b1 = los[tid + 256];
        int p0 = (tid >= o) ? lod[tid - o] : 0;
        int p1 = lod[tid + 256 - o];
        int q0 = (tid >= o) ? los[tid - o] : 0;
        int q1 = los[tid + 256 - o];
        __syncthreads();
        lod[tid] = a0 + p0; lod[tid + 256] = a1 + p1;
        los[tid] = b0 + q0; los[tid + 256] = b1 + q1;
        __syncthreads();
    }
    // convert hd/hs to local exclusive cursors
    hd[tid] = lod[tid] - hd[tid]; hd[tid + 256] = lod[tid + 256] - hd[tid + 256];
    hs[tid] = los[tid] - hs[tid]; hs[tid + 256] = los[tid + 256] - hs[tid + 256];
    __syncthreads();
    // LDS scatter
    for (int i = base + tid; i < end; i += 256) {
        int sv = sp[i], dv = dp[i];
        int lp = atomicAdd(&hd[dv >> 8], 1);
        rbi[lp] = (sv << 8) | (dv & 255);
        int ls = atomicAdd(&hs[sv >> 8], 1);
        rbs[ls] = (unsigned char)(sv & 255);
    }
    __syncthreads();
    // coalesced write-out; bin of local idx via binary search on inclusive scan
    for (int i = tid; i < cnt; i += 256) {
        int lo = 0, hi = NB - 1;
        while (lo < hi) { int mid = (lo + hi) >> 1; if (lod[mid] > i) hi = mid; else lo = mid + 1; }
        int excl = lo ? lod[lo - 1] : 0;
        dbuf[(size_t)t * E + bd[lo] + (i - excl)] = rbi[i];
    }
    for (int i = tid; i < cnt; i += 256) {
        int lo = 0, hi = NB - 1;
        while (lo < hi) { int mid = (lo + hi) >> 1; if (los[mid] > i) hi = mid; else lo = mid + 1; }
        int excl = lo ? los[lo - 1] : 0;
        sbuf[(size_t)t * E + bs[lo] + (i - excl)] = rbs[i];
    }
}

// ---------------- build phase 4a: fine sort by dst -> compact CSR ----------
#define FDCAP 6656
__global__ void fine_dst(const int* __restrict__ dbuf, const int* __restrict__ offd,
                         int* __restrict__ esrc, int* __restrict__ rowptr,
                         float* __restrict__ dri, int E, int N, int NB) {
    __shared__ int h[256], sc[256], cur[256];
    __shared__ int rb[FDCAP];
    int b = blockIdx.x, t = blockIdx.y;
    int tid = threadIdx.x;
    h[tid] = 0;
    __syncthreads();
    int beg = offd[t * (NB + 1) + b], end = offd[t * (NB + 1) + b + 1];
    int cnt = end - beg;
    const int* dp = dbuf + (size_t)t * E;
    for (int i = beg + tid; i < end; i += 256) atomicAdd(&h[dp[i] & 255], 1);
    __syncthreads();
    sc[tid] = h[tid];
    __syncthreads();
    for (int o = 1; o < 256; o <<= 1) {
        int v = (tid >= o) ? sc[tid - o] : 0;
        __syncthreads();
        sc[tid] += v;
        __syncthreads();
    }
    int excl = sc[tid] - h[tid];
    cur[tid] = excl;
    int node = b * 256 + tid;
    if (node < N) {
        rowptr[t * (N + 1) + node] = beg + excl;
        int dg = h[tid] < 1 ? 1 : h[tid];
        dri[(size_t)t * N + node] = rsqrtf((float)dg);
    }
    __syncthreads();
    if (cnt <= FDCAP) {
        for (int i = beg + tid; i < end; i += 256) {
            int v = dp[i];
            int p = atomicAdd(&cur[v & 255], 1);
            rb[p] = v >> 8;
        }
        __syncthreads();
        for (int i = tid; i < cnt; i += 256) esrc[(size_t)t * E + beg + i] = rb[i];
    } else {
        for (int i = beg + tid; i < end; i += 256) {
            int v = dp[i];
            int p = beg + atomicAdd(&cur[v & 255], 1);
            esrc[(size_t)t * E + p] = v >> 8;
        }
    }
}

// ---------------- build phase 4b: fine histogram by src -> dro -------------
__global__ void fine_src(const unsigned char* __restrict__ sbuf, const int* __restrict__ offs,
                         float* __restrict__ dro, int E, int N, int NB) {
    __shared__ int h[256];
    int b = blockIdx.x, t = blockIdx.y;
    int tid = threadIdx.x;
    h[tid] = 0;
    __syncthreads();
    int beg = offs[t * (NB + 1) + b], end = offs[t * (NB + 1) + b + 1];
    const unsigned char* sp = sbuf + (size_t)t * E;
    for (int i = beg + tid; i < end; i += 256) atomicAdd(&h[sp[i]], 1);
    __syncthreads();
    int node = b * 256 + tid;
    if (node < N) {
        int dg = h[tid] < 1 ? 1 : h[tid];
        dro[(size_t)t * N + node] = rsqrtf((float)dg);
    }
}

// ---------------- bf16 helpers ----------------
__device__ __forceinline__ unsigned int bfr(float f) {
    unsigned int u = __float_as_uint(f);
    return (u + 0x7FFFu + ((u >> 16) & 1u)) >> 16;   // RNE
}
__device__ __forceinline__ unsigned int pack2(float lo, float hi) {
    return bfr(lo) | (bfr(hi) << 16);
}
__device__ __forceinline__ float blo(unsigned int u) { return __uint_as_float(u << 16); }
__device__ __forceinline__ float bhi(unsigned int u) { return __uint_as_float(u & 0xFFFF0000u); }

// ---------------- fp32 -> bf16 convert (initial x copy) --------------------
__global__ void cvt_bf16(const float* __restrict__ h, unsigned short* __restrict__ h2,
                         int total8) {
    int i = blockIdx.x * 256 + threadIdx.x;
    if (i >= total8) return;
    const float4* hp = (const float4*)h + (size_t)i * 2;
    float4 v0 = hp[0], v1 = hp[1];
    uint4 o;
    o.x = pack2(v0.x, v0.y);
    o.y = pack2(v0.z, v0.w);
    o.z = pack2(v1.x, v1.y);
    o.w = pack2(v1.z, v1.w);
    ((uint4*)h2)[i] = o;
}

// ---------------- weight packing: fragment-ordered bf16 --------------------
__global__ void pack_w(const float* __restrict__ gcW0, const float* __restrict__ gcW,
                       const float* __restrict__ fcW, unsigned short* __restrict__ Wg,
                       unsigned short* __restrict__ Wf) {
    int mat = blockIdx.x;   // 0..8 = gc (l*3+e), 9..11 = fc layer
    const float* srcp;
    unsigned short* dstp;
    if (mat < 9) {
        int l = mat / 3, e = mat % 3;
        srcp = (l == 0) ? gcW0 + (size_t)e * 16384
                        : gcW + ((size_t)(l - 1) * 3 + e) * 16384;
        dstp = Wg + (size_t)mat * 16384;
    } else {
        srcp = fcW + (size_t)(mat - 9) * 16384;
        dstp = Wf + (size_t)(mat - 9) * 16384;
    }
    for (int p = threadIdx.x; p < 16384; p += 256) {
        int j = p & 7;
        int ln = (p >> 3) & 63;
        int nt = (p >> 9) & 7;
        int ks = p >> 12;
        int k = ks * 32 + (ln >> 4) * 8 + j;
        int n = nt * 16 + (ln & 15);
        dstp[p] = (unsigned short)bfr(srcp[k * 128 + n]);
    }
}

// ---------------- aggregation: 16 lanes/node, uint4, 8 rows in flight ------
__launch_bounds__(256)
__global__ void agg_kernel(const unsigned short* __restrict__ h2, const int* __restrict__ rowptrB,
                           const int* __restrict__ esrcB, const float* __restrict__ droB,
                           const float* __restrict__ driB, unsigned short* __restrict__ zB,
                           int N, int E) {
    const int e = blockIdx.y;
    const int* rowptr = rowptrB + e * (N + 1);
    const int* esrc = esrcB + (size_t)e * E;
    const float* dro = droB + (size_t)e * N;
    const float* dri = driB + (size_t)e * N;
    unsigned short* z = zB + (size_t)e * N * 128;

    int idx = blockIdx.x * 256 + threadIdx.x;
    int node = idx >> 4;
    int lq = idx & 15;
    if (node >= N) return;
    int beg = rowptr[node], end = rowptr[node + 1];
    const uint4* hp = (const uint4*)h2 + lq;   // row s at hp[s*16]
    float a0 = 0.f, a1 = 0.f, a2 = 0.f, a3 = 0.f, a4 = 0.f, a5 = 0.f, a6 = 0.f, a7 = 0.f;
    int j = beg;
    for (; j + 8 <= end; j += 8) {
        int s[8];
#pragma unroll
        for (int q = 0; q < 8; ++q) s[q] = esrc[j + q];
        uint4 u[8];
#pragma unroll
        for (int q = 0; q < 8; ++q) u[q] = hp[(size_t)s[q] * 16];
        float w[8];
#pragma unroll
        for (int q = 0; q < 8; ++q) w[q] = dro[s[q]];
#pragma unroll
        for (int q = 0; q < 8; ++q) {
            a0 += w[q] * blo(u[q].x); a1 += w[q] * bhi(u[q].x);
            a2 += w[q] * blo(u[q].y); a3 += w[q] * bhi(u[q].y);
            a4 += w[q] * blo(u[q].z); a5 += w[q] * bhi(u[q].z);
            a6 += w[q] * blo(u[q].w); a7 += w[q] * bhi(u[q].w);
        }
    }
    for (; j + 4 <= end; j += 4) {
        int s[4];
#pragma unroll
        for (int q = 0; q < 4; ++q) s[q] = esrc[j + q];
        uint4 u[4];
#pragma unroll
        for (int q = 0; q < 4; ++q) u[q] = hp[(size_t)s[q] * 16];
        float w[4];
#pragma unroll
        for (int q = 0; q < 4; ++q) w[q] = dro[s[q]];
#pragma unroll
        for (int q = 0; q < 4; ++q) {
            a0 += w[q] * blo(u[q].x); a1 += w[q] * bhi(u[q].x);
            a2 += w[q] * blo(u[q].y); a3 += w[q] * bhi(u[q].y);
            a4 += w[q] * blo(u[q].z); a5 += w[q] * bhi(u[q].z);
            a6 += w[q] * blo(u[q].w); a7 += w[q] * bhi(u[q].w);
        }
    }
    for (; j < end; ++j) {
        int s0 = esrc[j];
        float w0 = dro[s0];
        uint4 u0 = hp[(size_t)s0 * 16];
        a0 += w0 * blo(u0.x); a1 += w0 * bhi(u0.x);
        a2 += w0 * blo(u0.y); a3 += w0 * bhi(u0.y);
        a4 += w0 * blo(u0.z); a5 += w0 * bhi(u0.z);
        a6 += w0 * blo(u0.w); a7 += w0 * bhi(u0.w);
    }
    float scl = dri[node];
    uint4 o;
    o.x = pack2(a0 * scl, a1 * scl);
    o.y = pack2(a2 * scl, a3 * scl);
    o.z = pack2(a4 * scl, a5 * scl);
    o.w = pack2(a6 * scl, a7 * scl);
    ((uint4*)z)[(size_t)node * 16 + lq] = o;
}

// ---------------- hetero MFMA GEMM: C = [z0|z1|z2] @ Wcat + sum(bias) ------
__launch_bounds__(256)
__global__ void mfma_gc(const unsigned short* __restrict__ zB,
                        const unsigned short* __restrict__ Wp,
                        const float* __restrict__ b3,
                        unsigned short* __restrict__ C, int M) {
    const int tid = threadIdx.x;
    const int l = tid & 63;
    const int wv = tid >> 6;
    const int wm = wv >> 1, wn = wv & 1;
    const int m0 = blockIdx.x * 128;
    const int lr = l & 15;
    const int lk = (l >> 4) * 8;
    f4v acc[4][4];
#pragma unroll
    for (int i = 0; i < 4; ++i)
#pragma unroll
        for (int j = 0; j < 4; ++j) acc[i][j] = (f4v){0.f, 0.f, 0.f, 0.f};

    int rowb[4];
#pragma unroll
    for (int mt = 0; mt < 4; ++mt) {
        int r = m0 + wm * 64 + mt * 16 + lr;
        rowb[mt] = (r < M) ? r : (M - 1);
    }
#pragma unroll
    for (int e = 0; e < 3; ++e) {
        const unsigned short* zp = zB + (size_t)e * M * 128;
        const unsigned short* wp = Wp + (size_t)e * 16384;
#pragma unroll
        for (int ks = 0; ks < 4; ++ks) {
            s8v a[4], b[4];
#pragma unroll
            for (int mt = 0; mt < 4; ++mt)
                a[mt] = *(const s8v*)(zp + (size_t)rowb[mt] * 128 + ks * 32 + lk);
#pragma unroll
            for (int nt = 0; nt < 4; ++nt)
                b[nt] = *(const s8v*)(wp + ks * 4096 + (wn * 4 + nt) * 512 + l * 8);
#pragma unroll
            for (int mt = 0; mt < 4; ++mt)
#pragma unroll
                for (int nt = 0; nt < 4; ++nt)
                    acc[mt][nt] = __builtin_amdgcn_mfma_f32_16x16x32_bf16(
                        a[mt], b[nt], acc[mt][nt], 0, 0, 0);
        }
    }
    float bs[4];
    int col[4];
#pragma unroll
    for (int nt = 0; nt < 4; ++nt) {
        col[nt] = wn * 64 + nt * 16 + lr;
        bs[nt] = b3[col[nt]] + b3[128 + col[nt]] + b3[256 + col[nt]];
    }
#pragma unroll
    for (int mt = 0; mt < 4; ++mt) {
#pragma unroll
        for (int r = 0; r < 4; ++r) {
            int row = m0 + wm * 64 + mt * 16 + (l >> 4) * 4 + r;
            if (row < M) {
                unsigned short* cp = C + (size_t)row * 128;
#pragma unroll
                for (int nt = 0; nt < 4; ++nt)
                    cp[col[nt]] = (unsigned short)bfr(acc[mt][nt][r] + bs[nt]);
            }
        }
    }
}

// ---------------- FC MFMA GEMM + ReLU + BN stats ---------------------------
template <int MODE>
__launch_bounds__(256)
__global__ void mfma_fc(const unsigned short* __restrict__ A,
                        const unsigned short* __restrict__ Wp,
                        const float* __restrict__ bias,
                        unsigned short* __restrict__ outb, float* __restrict__ outf,
                        float* __restrict__ bnsum, int M) {
    __shared__ float red[256];
    const int tid = threadIdx.x;
    const int l = tid & 63;
    const int wv = tid >> 6;
    const int wm = wv >> 1, wn = wv & 1;
    const int m0 = blockIdx.x * 128;
    const int lr = l & 15;
    const int lk = (l >> 4) * 8;
    f4v acc[4][4];
#pragma unroll
    for (int i = 0; i < 4; ++i)
#pragma unroll
        for (int j = 0; j < 4; ++j) acc[i][j] = (f4v){0.f, 0.f, 0.f, 0.f};

    int rowb[4];
#pragma unroll
    for (int mt = 0; mt < 4; ++mt) {
        int r = m0 + wm * 64 + mt * 16 + lr;
        rowb[mt] = (r < M) ? r : (M - 1);
    }
#pragma unroll
    for (int ks = 0; ks < 4; ++ks) {
        s8v a[4], b[4];
#pragma unroll
        for (int mt = 0; mt < 4; ++mt)
            a[mt] = *(const s8v*)(A + (size_t)rowb[mt] * 128 + ks * 32 + lk);
#pragma unroll
        for (int nt = 0; nt < 4; ++nt)
            b[nt] = *(const s8v*)(Wp + ks * 4096 + (wn * 4 + nt) * 512 + l * 8);
#pragma unroll
        for (int mt = 0; mt < 4; ++mt)
#pragma unroll
            for (int nt = 0; nt < 4; ++nt)
                acc[mt][nt] = __builtin_amdgcn_mfma_f32_16x16x32_bf16(
                    a[mt], b[nt], acc[mt][nt], 0, 0, 0);
    }

    float bv[4], cs[4] = {}, cq[4] = {};
    int col[4];
#pragma unroll
    for (int nt = 0; nt < 4; ++nt) {
        col[nt] = wn * 64 + nt * 16 + lr;
        bv[nt] = bias[col[nt]];
    }
#pragma unroll
    for (int mt = 0; mt < 4; ++mt) {
#pragma unroll
        for (int r = 0; r < 4; ++r) {
            int row = m0 + wm * 64 + mt * 16 + (l >> 4) * 4 + r;
            if (row < M) {
#pragma unroll
                for (int nt = 0; nt < 4; ++nt) {
                    float v = acc[mt][nt][r] + bv[nt];
                    v = v > 0.f ? v : 0.f;
                    cs[nt] += v;
                    cq[nt] += v * v;
                    if (MODE == 0)
                        outb[(size_t)row * 128 + col[nt]] = (unsigned short)bfr(v);
                    else
                        outf[(size_t)row * 128 + col[nt]] = v;
                }
            }
        }
    }
    red[tid] = 0.f;
    __syncthreads();
#pragma unroll
    for (int nt = 0; nt < 4; ++nt) {
        atomicAdd(&red[col[nt]], cs[nt]);
        atomicAdd(&red[128 + col[nt]], cq[nt]);
    }
    __syncthreads();
    if (tid < 128) {
        atomicAdd(&bnsum[tid], red[tid]);
        atomicAdd(&bnsum[128 + tid], red[128 + tid]);
    }
}

// ---------------- BN affine (stats->scale/shift inline) --------------------
__global__ void bn_affine_bf16(unsigned short* __restrict__ h2, const float* __restrict__ bnsum,
                               const float* __restrict__ gamma, const float* __restrict__ beta,
                               float invn, int total8) {
    __shared__ float lss[256];
    int tid = threadIdx.x;
    if (tid < 128) {
        float mean = bnsum[tid] * invn;
        float var = bnsum[128 + tid] * invn - mean * mean;
        float sc = gamma[tid] * rsqrtf(var + EPSV);
        lss[tid] = sc;
        lss[128 + tid] = beta[tid] - mean * sc;
    }
    __syncthreads();
    int i = blockIdx.x * 256 + tid;
    if (i >= total8) return;
    uint4 v = ((const uint4*)h2)[i];
    int cb = (i & 15) * 8;
    float4 a0 = *(const float4*)&lss[cb];
    float4 a1 = *(const float4*)&lss[cb + 4];
    float4 b0 = *(const float4*)&lss[128 + cb];
    float4 b1 = *(const float4*)&lss[128 + cb + 4];
    uint4 o;
    o.x = pack2(blo(v.x) * a0.x + b0.x, bhi(v.x) * a0.y + b0.y);
    o.y = pack2(blo(v.y) * a0.z + b0.z, bhi(v.y) * a0.w + b0.w);
    o.z = pack2(blo(v.z) * a1.x + b1.x, bhi(v.z) * a1.y + b1.y);
    o.w = pack2(blo(v.w) * a1.z + b1.z, bhi(v.w) * a1.w + b1.w);
    ((uint4*)h2)[i] = o;
}

__global__ void bn_apply(float* __restrict__ h, const float* __restrict__ bnsum,
                         const float* __restrict__ gamma, const float* __restrict__ beta,
                         float invn, int total4) {
    __shared__ float lss[256];
    int tid = threadIdx.x;
    if (tid < 128) {
        float mean = bnsum[tid] * invn;
        float var = bnsum[128 + tid] * invn - mean * mean;
        float sc = gamma[tid] * rsqrtf(var + EPSV);
        lss[tid] = sc;
        lss[128 + tid] = beta[tid] - mean * sc;
    }
    __syncthreads();
    int i = blockIdx.x * 256 + tid;
    if (i >= total4) return;
    int c4 = (i & 31) * 4;
    float4 sc = *(const float4*)&lss[c4];
    float4 sh = *(const float4*)&lss[128 + c4];
    float4 v = ((float4*)h)[i];
    v.x = v.x * sc.x + sh.x;
    v.y = v.y * sc.y + sh.y;
    v.z = v.z * sc.z + sh.z;
    v.w = v.w * sc.w + sh.w;
    ((float4*)h)[i] = v;
}

// ---------------------------------------------------------------------------
extern "C" void kernel_launch(void* const* d_in, const int* in_sizes, int n_in,
                              void* d_out, int out_size, void* d_ws, size_t ws_size,
                              hipStream_t stream) {
    const float* x    = (const float*)d_in[0];
    const int*   src  = (const int*)d_in[1];
    const int*   dst  = (const int*)d_in[2];
    const float* gcW0 = (const float*)d_in[3];
    const float* gcb0 = (const float*)d_in[4];
    const float* gcW  = (const float*)d_in[5];
    const float* gcb  = (const float*)d_in[6];
    const float* fcW  = (const float*)d_in[7];
    const float* fcb  = (const float*)d_in[8];
    const float* bng  = (const float*)d_in[9];
    const float* bnb  = (const float*)d_in[10];
    float* out = (float*)d_out;

    const int N = in_sizes[0] / 128;
    const int E = in_sizes[1] / 3;
    const int NB = (N + 255) / 256;   // <= MAXNB for this problem size

    char* w = (char*)d_ws;
    auto alloc = [&](size_t bytes) -> char* {
        char* p = w;
        w += (bytes + 255) & ~(size_t)255;
        return p;
    };
    unsigned short* zB    = (unsigned short*)alloc((size_t)3 * N * 128 * 2);  // z0|z1|z2
    unsigned short* gcout = (unsigned short*)alloc((size_t)N * 128 * 2);
    unsigned short* h2    = (unsigned short*)alloc((size_t)N * 128 * 2);
    unsigned short* Wg    = (unsigned short*)alloc((size_t)9 * 16384 * 2);
    unsigned short* Wf    = (unsigned short*)alloc((size_t)3 * 16384 * 2);
    int*   esrc   = (int*)alloc((size_t)3 * E * 4);
    int*   rowptr = (int*)alloc((size_t)3 * (N + 1) * 4);
    float* dro    = (float*)alloc((size_t)3 * N * 4);
    float* dri    = (float*)alloc((size_t)3 * N * 4);
    int*   chd    = (int*)alloc((size_t)3 * NB * 4);
    int*   chs    = (int*)alloc((size_t)3 * NB * 4);
    int*   offd   = (int*)alloc((size_t)3 * (NB + 1) * 4);
    int*   offs   = (int*)alloc((size_t)3 * (NB + 1) * 4);
    int*   gcd    = (int*)alloc((size_t)3 * NB * 4);
    int*   gcs    = (int*)alloc((size_t)3 * NB * 4);
    float* bnsum  = (float*)alloc(256 * 4);
    // build-only buffers alias layer buffers (build completes before first use)
    int* dbuf = (int*)zB;                         // needs 3E*4 = 19.2MB <= 76.8MB
    unsigned char* sbuf = (unsigned char*)gcout;  // needs 3E = 4.8MB <= 25.6MB

    // ---- counting-sort CSR build ----
    hipMemsetAsync(chd, 0, (size_t)3 * NB * 4, stream);
    hipMemsetAsync(chs, 0, (size_t)3 * NB * 4, stream);
    dim3 cg2((E + CH - 1) / CH, 3);
    coarse_hist<<<cg2, 256, 0, stream>>>(src, dst, chd, chs, E, NB);
    scan_off<<<1, MAXNB, 0, stream>>>(chd, chs, offd, offs, gcd, gcs, rowptr, NB, N, E);
    scatter_coarse<<<cg2, 256, 0, stream>>>(src, dst, gcd, gcs, dbuf, sbuf, E, NB);
    dim3 fg(NB, 3);
    fine_dst<<<fg, 256, 0, stream>>>(dbuf, offd, esrc, rowptr, dri, E, N, NB);
    fine_src<<<fg, 256, 0, stream>>>(sbuf, offs, dro, E, N, NB);

    // ---- weight packing + initial bf16 x ----
    pack_w<<<12, 256, 0, stream>>>(gcW0, gcW, fcW, Wg, Wf);
    const int cvtGrid = (N * 16 + 255) / 256;
    cvt_bf16<<<cvtGrid, 256, 0, stream>>>(x, h2, N * 16);

    // ---- layers ----
    const int gemmGrid = (N + 127) / 128;
    const float invn = 1.0f / (float)N;
    dim3 aggG((N * 16 + 255) / 256, 3);

    for (int l = 0; l < 3; ++l) {
        const float* bl = (l == 0) ? gcb0 : gcb + (size_t)(l - 1) * 3 * 128;
        agg_kernel<<<aggG, 256, 0, stream>>>(h2, rowptr, esrc, dro, dri, zB, N, E);
        mfma_gc<<<gemmGrid, 256, 0, stream>>>(zB, Wg + (size_t)l * 3 * 16384, bl, gcout, N);
        hipMemsetAsync(bnsum, 0, 256 * 4, stream);
        if (l < 2)
            mfma_fc<0><<<gemmGrid, 256, 0, stream>>>(gcout, Wf + (size_t)l * 16384,
                                                     fcb + (size_t)l * 128, h2, nullptr,
                                                     bnsum, N);
        else
            mfma_fc<1><<<gemmGrid, 256, 0, stream>>>(gcout, Wf + (size_t)l * 16384,
                                                     fcb + (size_t)l * 128, nullptr, out,
                                                     bnsum, N);
        if (l < 2)
            bn_affine_bf16<<<cvtGrid, 256, 0, stream>>>(h2, bnsum, bng + (size_t)l * 128,
                                                        bnb + (size_t)l * 128, invn, N * 16);
        else
            bn_apply<<<(N * 32 + 255) / 256, 256, 0, stream>>>(out, bnsum,
                                                               bng + (size_t)l * 128,
                                                               bnb + (size_t)l * 128, invn,
                                                               N * 32);
    }
}

// Round 7
// 991.553 us; speedup vs baseline: 2.8163x; 1.0058x over previous
//
#include <hip/hip_runtime.h>

// ---------------------------------------------------------------------------
// Encoder: 3-layer HeteroGraphConv(3 edge types) -> FC -> ReLU -> BatchNorm
// Round 7:
//   * fused edge records esrcw = int2{src, bits(dro[src])} built in fine_dst
//     (fine_src runs first) -> agg loses the per-edge random dro loads
//   * BN affine folded into agg via linearity (wacc = sum of edge weights,
//     accumulated inline); bn_affine_bf16 passes deleted; h2 single-write
//   * multi-split scatter / LDS-staged fine sort / MFMA GEMMs unchanged
// ---------------------------------------------------------------------------

#define EPSV 1e-5f
#define CH 4096      // edges per block in coarse passes
#define MAXNB 512    // max coarse bins (N <= 131072)

typedef __attribute__((ext_vector_type(8))) short s8v;   // 8 bf16 = 4 VGPR
typedef __attribute__((ext_vector_type(4))) float f4v;   // 4 f32 acc

// ---------------- build phase 1: coarse histograms (both keys) -------------
__global__ void coarse_hist(const int* __restrict__ src, const int* __restrict__ dst,
                            int* __restrict__ chd, int* __restrict__ chs,
                            int E, int NB) {
    __shared__ int hd[MAXNB], hs[MAXNB];
    int t = blockIdx.y;
    for (int i = threadIdx.x; i < MAXNB; i += 256) { hd[i] = 0; hs[i] = 0; }
    __syncthreads();
    int base = blockIdx.x * CH;
    int end = base + CH < E ? base + CH : E;
    const int* sp = src + (size_t)t * E;
    const int* dp = dst + (size_t)t * E;
    for (int i = base + threadIdx.x; i < end; i += 256) {
        atomicAdd(&hd[dp[i] >> 8], 1);
        atomicAdd(&hs[sp[i] >> 8], 1);
    }
    __syncthreads();
    for (int b = threadIdx.x; b < NB; b += 256) {
        if (hd[b]) atomicAdd(&chd[t * NB + b], hd[b]);
        if (hs[b]) atomicAdd(&chs[t * NB + b], hs[b]);
    }
}

// ---------------- build phase 2: scan coarse bins -> offsets + cursors -----
__global__ void scan_off(const int* __restrict__ chd, const int* __restrict__ chs,
                         int* __restrict__ offd, int* __restrict__ offs,
                         int* __restrict__ gcd, int* __restrict__ gcs,
                         int* __restrict__ rowptr, int NB, int N, int E) {
    __shared__ int s[MAXNB];
    int tid = threadIdx.x;
    for (int a = 0; a < 6; ++a) {
        const int* h = (a < 3) ? chd + a * NB : chs + (a - 3) * NB;
        int* off = (a < 3) ? offd + a * (NB + 1) : offs + (a - 3) * (NB + 1);
        int* gc = (a < 3) ? gcd + a * NB : gcs + (a - 3) * NB;
        s[tid] = (tid < NB) ? h[tid] : 0;
        __syncthreads();
        for (int o = 1; o < MAXNB; o <<= 1) {
            int v = (tid >= o) ? s[tid - o] : 0;
            __syncthreads();
            s[tid] += v;
            __syncthreads();
        }
        if (tid < NB) {
            off[tid + 1] = s[tid];
            if (tid == 0) off[0] = 0;
        }
        __syncthreads();
        if (tid < NB) gc[tid] = off[tid];
        __syncthreads();
    }
    if (tid < 3) rowptr[tid * (N + 1) + N] = E;
}

// ---------------- build phase 3: multi-split scatter (LDS reorder) ---------
__launch_bounds__(256)
__global__ void scatter_coarse(const int* __restrict__ src, const int* __restrict__ dst,
                               int* __restrict__ gcd, int* __restrict__ gcs,
                               int* __restrict__ dbuf, unsigned char* __restrict__ sbuf,
                               int E, int NB) {
    __shared__ int hd[MAXNB], hs[MAXNB];     // counts -> local cursors
    __shared__ int lod[MAXNB], los[MAXNB];   // inclusive scans
    __shared__ int bd[MAXNB], bs[MAXNB];     // global bases
    __shared__ int rbi[CH];                  // reordered dst records
    __shared__ unsigned char rbs[CH];        // reordered src low bytes
    const int tid = threadIdx.x;
    const int t = blockIdx.y;
    const int base = blockIdx.x * CH;
    const int end = base + CH < E ? base + CH : E;
    const int cnt = end - base;
    const int* sp = src + (size_t)t * E;
    const int* dp = dst + (size_t)t * E;

    for (int i = tid; i < MAXNB; i += 256) { hd[i] = 0; hs[i] = 0; }
    __syncthreads();
    for (int i = base + tid; i < end; i += 256) {
        atomicAdd(&hd[dp[i] >> 8], 1);
        atomicAdd(&hs[sp[i] >> 8], 1);
    }
    __syncthreads();
    for (int b = tid; b < NB; b += 256) {
        bd[b] = hd[b] ? atomicAdd(&gcd[t * NB + b], hd[b]) : 0;
        bs[b] = hs[b] ? atomicAdd(&gcs[t * NB + b], hs[b]) : 0;
    }
    lod[tid] = hd[tid]; lod[tid + 256] = hd[tid + 256];
    los[tid] = hs[tid]; los[tid + 256] = hs[tid + 256];
    __syncthreads();
    for (int o = 1; o < MAXNB; o <<= 1) {
        int a0 = lod[tid], a1 = lod[tid + 256];
        int b0 = los[tid], b1 = los[tid + 256];
        int p0 = (tid >= o) ? lod[tid - o] : 0;
        int p1 = lod[tid + 256 - o];
        int q0 = (tid >= o) ? los[tid - o] : 0;
        int q1 = los[tid + 256 - o];
        __syncthreads();
        lod[tid] = a0 + p0; lod[tid + 256] = a1 + p1;
        los[tid] = b0 + q0; los[tid + 256] = b1 + q1;
        __syncthreads();
    }
    hd[tid] = lod[tid] - hd[tid]; hd[tid + 256] = lod[tid + 256] - hd[tid + 256];
    hs[tid] = los[tid] - hs[tid]; hs[tid + 256] = los[tid + 256] - hs[tid + 256];
    __syncthreads();
    for (int i = base + tid; i < end; i += 256) {
        int sv = sp[i], dv = dp[i];
        int lp = atomicAdd(&hd[dv >> 8], 1);
        rbi[lp] = (sv << 8) | (dv & 255);
        int ls = atomicAdd(&hs[sv >> 8], 1);
        rbs[ls] = (unsigned char)(sv & 255);
    }
    __syncthreads();
    for (int i = tid; i < cnt; i += 256) {
        int lo = 0, hi = NB - 1;
        while (lo < hi) { int mid = (lo + hi) >> 1; if (lod[mid] > i) hi = mid; else lo = mid + 1; }
        int excl = lo ? lod[lo - 1] : 0;
        dbuf[(size_t)t * E + bd[lo] + (i - excl)] = rbi[i];
    }
    for (int i = tid; i < cnt; i += 256) {
        int lo = 0, hi = NB - 1;
        while (lo < hi) { int mid = (lo + hi) >> 1; if (los[mid] > i) hi = mid; else lo = mid + 1; }
        int excl = lo ? los[lo - 1] : 0;
        sbuf[(size_t)t * E + bs[lo] + (i - excl)] = rbs[i];
    }
}

// ---------------- build phase 4a: fine histogram by src -> dro (FIRST) -----
__global__ void fine_src(const unsigned char* __restrict__ sbuf, const int* __restrict__ offs,
                         float* __restrict__ dro, int E, int N, int NB) {
    __shared__ int h[256];
    int b = blockIdx.x, t = blockIdx.y;
    int tid = threadIdx.x;
    h[tid] = 0;
    __syncthreads();
    int beg = offs[t * (NB + 1) + b], end = offs[t * (NB + 1) + b + 1];
    const unsigned char* sp = sbuf + (size_t)t * E;
    for (int i = beg + tid; i < end; i += 256) atomicAdd(&h[sp[i]], 1);
    __syncthreads();
    int node = b * 256 + tid;
    if (node < N) {
        int dg = h[tid] < 1 ? 1 : h[tid];
        dro[(size_t)t * N + node] = rsqrtf((float)dg);
    }
}

// ---------------- build phase 4b: fine sort by dst -> CSR of (src,w) -------
#define FDCAP 6656
__global__ void fine_dst(const int* __restrict__ dbuf, const int* __restrict__ offd,
                         const float* __restrict__ dro, int2* __restrict__ esrcw,
                         int* __restrict__ rowptr, float* __restrict__ dri,
                         int E, int N, int NB) {
    __shared__ int h[256], sc[256], cur[256];
    __shared__ int rb[FDCAP];
    int b = blockIdx.x, t = blockIdx.y;
    int tid = threadIdx.x;
    h[tid] = 0;
    __syncthreads();
    int beg = offd[t * (NB + 1) + b], end = offd[t * (NB + 1) + b + 1];
    int cnt = end - beg;
    const int* dp = dbuf + (size_t)t * E;
    const float* drt = dro + (size_t)t * N;
    for (int i = beg + tid; i < end; i += 256) atomicAdd(&h[dp[i] & 255], 1);
    __syncthreads();
    sc[tid] = h[tid];
    __syncthreads();
    for (int o = 1; o < 256; o <<= 1) {
        int v = (tid >= o) ? sc[tid - o] : 0;
        __syncthreads();
        sc[tid] += v;
        __syncthreads();
    }
    int excl = sc[tid] - h[tid];
    cur[tid] = excl;
    int node = b * 256 + tid;
    if (node < N) {
        rowptr[t * (N + 1) + node] = beg + excl;
        int dg = h[tid] < 1 ? 1 : h[tid];
        dri[(size_t)t * N + node] = rsqrtf((float)dg);
    }
    __syncthreads();
    if (cnt <= FDCAP) {
        for (int i = beg + tid; i < end; i += 256) {
            int v = dp[i];
            int p = atomicAdd(&cur[v & 255], 1);
            rb[p] = v >> 8;
        }
        __syncthreads();
        for (int i = tid; i < cnt; i += 256) {
            int sv = rb[i];
            esrcw[(size_t)t * E + beg + i] = make_int2(sv, __float_as_int(drt[sv]));
        }
    } else {
        for (int i = beg + tid; i < end; i += 256) {
            int v = dp[i];
            int sv = v >> 8;
            int p = beg + atomicAdd(&cur[v & 255], 1);
            esrcw[(size_t)t * E + p] = make_int2(sv, __float_as_int(drt[sv]));
        }
    }
}

// ---------------- bf16 helpers ----------------
__device__ __forceinline__ unsigned int bfr(float f) {
    unsigned int u = __float_as_uint(f);
    return (u + 0x7FFFu + ((u >> 16) & 1u)) >> 16;   // RNE
}
__device__ __forceinline__ unsigned int pack2(float lo, float hi) {
    return bfr(lo) | (bfr(hi) << 16);
}
__device__ __forceinline__ float blo(unsigned int u) { return __uint_as_float(u << 16); }
__device__ __forceinline__ float bhi(unsigned int u) { return __uint_as_float(u & 0xFFFF0000u); }

// ---------------- fp32 -> bf16 convert (initial x copy) --------------------
__global__ void cvt_bf16(const float* __restrict__ h, unsigned short* __restrict__ h2,
                         int total8) {
    int i = blockIdx.x * 256 + threadIdx.x;
    if (i >= total8) return;
    const float4* hp = (const float4*)h + (size_t)i * 2;
    float4 v0 = hp[0], v1 = hp[1];
    uint4 o;
    o.x = pack2(v0.x, v0.y);
    o.y = pack2(v0.z, v0.w);
    o.z = pack2(v1.x, v1.y);
    o.w = pack2(v1.z, v1.w);
    ((uint4*)h2)[i] = o;
}

// ---------------- weight packing: fragment-ordered bf16 --------------------
__global__ void pack_w(const float* __restrict__ gcW0, const float* __restrict__ gcW,
                       const float* __restrict__ fcW, unsigned short* __restrict__ Wg,
                       unsigned short* __restrict__ Wf) {
    int mat = blockIdx.x;   // 0..8 = gc (l*3+e), 9..11 = fc layer
    const float* srcp;
    unsigned short* dstp;
    if (mat < 9) {
        int l = mat / 3, e = mat % 3;
        srcp = (l == 0) ? gcW0 + (size_t)e * 16384
                        : gcW + ((size_t)(l - 1) * 3 + e) * 16384;
        dstp = Wg + (size_t)mat * 16384;
    } else {
        srcp = fcW + (size_t)(mat - 9) * 16384;
        dstp = Wf + (size_t)(mat - 9) * 16384;
    }
    for (int p = threadIdx.x; p < 16384; p += 256) {
        int j = p & 7;
        int ln = (p >> 3) & 63;
        int nt = (p >> 9) & 7;
        int ks = p >> 12;
        int k = ks * 32 + (ln >> 4) * 8 + j;
        int n = nt * 16 + (ln & 15);
        dstp[p] = (unsigned short)bfr(srcp[k * 128 + n]);
    }
}

// ---------------- aggregation: fused records + folded BN affine ------------
// 16 lanes/node, uint4 rows, 8 edges in flight.
// AFF==1: input h2 is PRE-BN; z = dri*(a (.) acc + b * wacc) with (a,b) from
// bnsum/gamma/beta computed in prologue (linearity of the affine).
template <int AFF>
__launch_bounds__(256)
__global__ void agg_kernel(const unsigned short* __restrict__ h2, const int* __restrict__ rowptrB,
                           const int2* __restrict__ esrcwB, const float* __restrict__ driB,
                           const float* __restrict__ bnsum, const float* __restrict__ gamma,
                           const float* __restrict__ beta, float invn,
                           unsigned short* __restrict__ zB, int N, int E) {
    __shared__ float lss[256];
    if (AFF) {
        int tid = threadIdx.x;
        if (tid < 128) {
            float mean = bnsum[tid] * invn;
            float var = bnsum[128 + tid] * invn - mean * mean;
            float sc = gamma[tid] * rsqrtf(var + EPSV);
            lss[tid] = sc;
            lss[128 + tid] = beta[tid] - mean * sc;
        }
        __syncthreads();
    }
    const int e = blockIdx.y;
    const int* rowptr = rowptrB + e * (N + 1);
    const int2* esrcw = esrcwB + (size_t)e * E;
    const float* dri = driB + (size_t)e * N;
    unsigned short* z = zB + (size_t)e * N * 128;

    int idx = blockIdx.x * 256 + threadIdx.x;
    int node = idx >> 4;
    int lq = idx & 15;
    if (node >= N) return;
    int beg = rowptr[node], end = rowptr[node + 1];
    const uint4* hp = (const uint4*)h2 + lq;   // row s at hp[s*16]
    float a0 = 0.f, a1 = 0.f, a2 = 0.f, a3 = 0.f, a4 = 0.f, a5 = 0.f, a6 = 0.f, a7 = 0.f;
    float wacc = 0.f;
    int j = beg;
    for (; j + 8 <= end; j += 8) {
        int2 r[8];
#pragma unroll
        for (int q = 0; q < 8; ++q) r[q] = esrcw[j + q];
        uint4 u[8];
#pragma unroll
        for (int q = 0; q < 8; ++q) u[q] = hp[(size_t)r[q].x * 16];
#pragma unroll
        for (int q = 0; q < 8; ++q) {
            float w = __int_as_float(r[q].y);
            if (AFF) wacc += w;
            a0 += w * blo(u[q].x); a1 += w * bhi(u[q].x);
            a2 += w * blo(u[q].y); a3 += w * bhi(u[q].y);
            a4 += w * blo(u[q].z); a5 += w * bhi(u[q].z);
            a6 += w * blo(u[q].w); a7 += w * bhi(u[q].w);
        }
    }
    for (; j + 4 <= end; j += 4) {
        int2 r[4];
#pragma unroll
        for (int q = 0; q < 4; ++q) r[q] = esrcw[j + q];
        uint4 u[4];
#pragma unroll
        for (int q = 0; q < 4; ++q) u[q] = hp[(size_t)r[q].x * 16];
#pragma unroll
        for (int q = 0; q < 4; ++q) {
            float w = __int_as_float(r[q].y);
            if (AFF) wacc += w;
            a0 += w * blo(u[q].x); a1 += w * bhi(u[q].x);
            a2 += w * blo(u[q].y); a3 += w * bhi(u[q].y);
            a4 += w * blo(u[q].z); a5 += w * bhi(u[q].z);
            a6 += w * blo(u[q].w); a7 += w * bhi(u[q].w);
        }
    }
    for (; j < end; ++j) {
        int2 r0 = esrcw[j];
        float w = __int_as_float(r0.y);
        if (AFF) wacc += w;
        uint4 u0 = hp[(size_t)r0.x * 16];
        a0 += w * blo(u0.x); a1 += w * bhi(u0.x);
        a2 += w * blo(u0.y); a3 += w * bhi(u0.y);
        a4 += w * blo(u0.z); a5 += w * bhi(u0.z);
        a6 += w * blo(u0.w); a7 += w * bhi(u0.w);
    }
    float scl = dri[node];
    if (AFF) {
        const float* ap = &lss[lq * 8];
        const float* bp = &lss[128 + lq * 8];
        a0 = ap[0] * a0 + bp[0] * wacc;
        a1 = ap[1] * a1 + bp[1] * wacc;
        a2 = ap[2] * a2 + bp[2] * wacc;
        a3 = ap[3] * a3 + bp[3] * wacc;
        a4 = ap[4] * a4 + bp[4] * wacc;
        a5 = ap[5] * a5 + bp[5] * wacc;
        a6 = ap[6] * a6 + bp[6] * wacc;
        a7 = ap[7] * a7 + bp[7] * wacc;
    }
    uint4 o;
    o.x = pack2(a0 * scl, a1 * scl);
    o.y = pack2(a2 * scl, a3 * scl);
    o.z = pack2(a4 * scl, a5 * scl);
    o.w = pack2(a6 * scl, a7 * scl);
    ((uint4*)z)[(size_t)node * 16 + lq] = o;
}

// ---------------- hetero MFMA GEMM: C = [z0|z1|z2] @ Wcat + sum(bias) ------
__launch_bounds__(256)
__global__ void mfma_gc(const unsigned short* __restrict__ zB,
                        const unsigned short* __restrict__ Wp,
                        const float* __restrict__ b3,
                        unsigned short* __restrict__ C, int M) {
    const int tid = threadIdx.x;
    const int l = tid & 63;
    const int wv = tid >> 6;
    const int wm = wv >> 1, wn = wv & 1;
    const int m0 = blockIdx.x * 128;
    const int lr = l & 15;
    const int lk = (l >> 4) * 8;
    f4v acc[4][4];
#pragma unroll
    for (int i = 0; i < 4; ++i)
#pragma unroll
        for (int j = 0; j < 4; ++j) acc[i][j] = (f4v){0.f, 0.f, 0.f, 0.f};

    int rowb[4];
#pragma unroll
    for (int mt = 0; mt < 4; ++mt) {
        int r = m0 + wm * 64 + mt * 16 + lr;
        rowb[mt] = (r < M) ? r : (M - 1);
    }
#pragma unroll
    for (int e = 0; e < 3; ++e) {
        const unsigned short* zp = zB + (size_t)e * M * 128;
        const unsigned short* wp = Wp + (size_t)e * 16384;
#pragma unroll
        for (int ks = 0; ks < 4; ++ks) {
            s8v a[4], b[4];
#pragma unroll
            for (int mt = 0; mt < 4; ++mt)
                a[mt] = *(const s8v*)(zp + (size_t)rowb[mt] * 128 + ks * 32 + lk);
#pragma unroll
            for (int nt = 0; nt < 4; ++nt)
                b[nt] = *(const s8v*)(wp + ks * 4096 + (wn * 4 + nt) * 512 + l * 8);
#pragma unroll
            for (int mt = 0; mt < 4; ++mt)
#pragma unroll
                for (int nt = 0; nt < 4; ++nt)
                    acc[mt][nt] = __builtin_amdgcn_mfma_f32_16x16x32_bf16(
                        a[mt], b[nt], acc[mt][nt], 0, 0, 0);
        }
    }
    float bs[4];
    int col[4];
#pragma unroll
    for (int nt = 0; nt < 4; ++nt) {
        col[nt] = wn * 64 + nt * 16 + lr;
        bs[nt] = b3[col[nt]] + b3[128 + col[nt]] + b3[256 + col[nt]];
    }
#pragma unroll
    for (int mt = 0; mt < 4; ++mt) {
#pragma unroll
        for (int r = 0; r < 4; ++r) {
            int row = m0 + wm * 64 + mt * 16 + (l >> 4) * 4 + r;
            if (row < M) {
                unsigned short* cp = C + (size_t)row * 128;
#pragma unroll
                for (int nt = 0; nt < 4; ++nt)
                    cp[col[nt]] = (unsigned short)bfr(acc[mt][nt][r] + bs[nt]);
            }
        }
    }
}

// ---------------- FC MFMA GEMM + ReLU + BN stats ---------------------------
template <int MODE>
__launch_bounds__(256)
__global__ void mfma_fc(const unsigned short* __restrict__ A,
                        const unsigned short* __restrict__ Wp,
                        const float* __restrict__ bias,
                        unsigned short* __restrict__ outb, float* __restrict__ outf,
                        float* __restrict__ bnsum, int M) {
    __shared__ float red[256];
    const int tid = threadIdx.x;
    const int l = tid & 63;
    const int wv = tid >> 6;
    const int wm = wv >> 1, wn = wv & 1;
    const int m0 = blockIdx.x * 128;
    const int lr = l & 15;
    const int lk = (l >> 4) * 8;
    f4v acc[4][4];
#pragma unroll
    for (int i = 0; i < 4; ++i)
#pragma unroll
        for (int j = 0; j < 4; ++j) acc[i][j] = (f4v){0.f, 0.f, 0.f, 0.f};

    int rowb[4];
#pragma unroll
    for (int mt = 0; mt < 4; ++mt) {
        int r = m0 + wm * 64 + mt * 16 + lr;
        rowb[mt] = (r < M) ? r : (M - 1);
    }
#pragma unroll
    for (int ks = 0; ks < 4; ++ks) {
        s8v a[4], b[4];
#pragma unroll
        for (int mt = 0; mt < 4; ++mt)
            a[mt] = *(const s8v*)(A + (size_t)rowb[mt] * 128 + ks * 32 + lk);
#pragma unroll
        for (int nt = 0; nt < 4; ++nt)
            b[nt] = *(const s8v*)(Wp + ks * 4096 + (wn * 4 + nt) * 512 + l * 8);
#pragma unroll
        for (int mt = 0; mt < 4; ++mt)
#pragma unroll
            for (int nt = 0; nt < 4; ++nt)
                acc[mt][nt] = __builtin_amdgcn_mfma_f32_16x16x32_bf16(
                    a[mt], b[nt], acc[mt][nt], 0, 0, 0);
    }

    float bv[4], cs[4] = {}, cq[4] = {};
    int col[4];
#pragma unroll
    for (int nt = 0; nt < 4; ++nt) {
        col[nt] = wn * 64 + nt * 16 + lr;
        bv[nt] = bias[col[nt]];
    }
#pragma unroll
    for (int mt = 0; mt < 4; ++mt) {
#pragma unroll
        for (int r = 0; r < 4; ++r) {
            int row = m0 + wm * 64 + mt * 16 + (l >> 4) * 4 + r;
            if (row < M) {
#pragma unroll
                for (int nt = 0; nt < 4; ++nt) {
                    float v = acc[mt][nt][r] + bv[nt];
                    v = v > 0.f ? v : 0.f;
                    cs[nt] += v;
                    cq[nt] += v * v;
                    if (MODE == 0)
                        outb[(size_t)row * 128 + col[nt]] = (unsigned short)bfr(v);
                    else
                        outf[(size_t)row * 128 + col[nt]] = v;
                }
            }
        }
    }
    red[tid] = 0.f;
    __syncthreads();
#pragma unroll
    for (int nt = 0; nt < 4; ++nt) {
        atomicAdd(&red[col[nt]], cs[nt]);
        atomicAdd(&red[128 + col[nt]], cq[nt]);
    }
    __syncthreads();
    if (tid < 128) {
        atomicAdd(&bnsum[tid], red[tid]);
        atomicAdd(&bnsum[128 + tid], red[128 + tid]);
    }
}

// ---------------- final BN apply (fp32 out) --------------------------------
__global__ void bn_apply(float* __restrict__ h, const float* __restrict__ bnsum,
                         const float* __restrict__ gamma, const float* __restrict__ beta,
                         float invn, int total4) {
    __shared__ float lss[256];
    int tid = threadIdx.x;
    if (tid < 128) {
        float mean = bnsum[tid] * invn;
        float var = bnsum[128 + tid] * invn - mean * mean;
        float sc = gamma[tid] * rsqrtf(var + EPSV);
        lss[tid] = sc;
        lss[128 + tid] = beta[tid] - mean * sc;
    }
    __syncthreads();
    int i = blockIdx.x * 256 + tid;
    if (i >= total4) return;
    int c4 = (i & 31) * 4;
    float4 sc = *(const float4*)&lss[c4];
    float4 sh = *(const float4*)&lss[128 + c4];
    float4 v = ((float4*)h)[i];
    v.x = v.x * sc.x + sh.x;
    v.y = v.y * sc.y + sh.y;
    v.z = v.z * sc.z + sh.z;
    v.w = v.w * sc.w + sh.w;
    ((float4*)h)[i] = v;
}

// ---------------------------------------------------------------------------
extern "C" void kernel_launch(void* const* d_in, const int* in_sizes, int n_in,
                              void* d_out, int out_size, void* d_ws, size_t ws_size,
                              hipStream_t stream) {
    const float* x    = (const float*)d_in[0];
    const int*   src  = (const int*)d_in[1];
    const int*   dst  = (const int*)d_in[2];
    const float* gcW0 = (const float*)d_in[3];
    const float* gcb0 = (const float*)d_in[4];
    const float* gcW  = (const float*)d_in[5];
    const float* gcb  = (const float*)d_in[6];
    const float* fcW  = (const float*)d_in[7];
    const float* fcb  = (const float*)d_in[8];
    const float* bng  = (const float*)d_in[9];
    const float* bnb  = (const float*)d_in[10];
    float* out = (float*)d_out;

    const int N = in_sizes[0] / 128;
    const int E = in_sizes[1] / 3;
    const int NB = (N + 255) / 256;   // <= MAXNB for this problem size

    char* w = (char*)d_ws;
    auto alloc = [&](size_t bytes) -> char* {
        char* p = w;
        w += (bytes + 255) & ~(size_t)255;
        return p;
    };
    unsigned short* zB    = (unsigned short*)alloc((size_t)3 * N * 128 * 2);  // z0|z1|z2
    unsigned short* gcout = (unsigned short*)alloc((size_t)N * 128 * 2);
    unsigned short* h2    = (unsigned short*)alloc((size_t)N * 128 * 2);
    unsigned short* Wg    = (unsigned short*)alloc((size_t)9 * 16384 * 2);
    unsigned short* Wf    = (unsigned short*)alloc((size_t)3 * 16384 * 2);
    int2*  esrcw  = (int2*)alloc((size_t)3 * E * 8);
    int*   rowptr = (int*)alloc((size_t)3 * (N + 1) * 4);
    float* dro    = (float*)alloc((size_t)3 * N * 4);
    float* dri    = (float*)alloc((size_t)3 * N * 4);
    int*   chd    = (int*)alloc((size_t)3 * NB * 4);
    int*   chs    = (int*)alloc((size_t)3 * NB * 4);
    int*   offd   = (int*)alloc((size_t)3 * (NB + 1) * 4);
    int*   offs   = (int*)alloc((size_t)3 * (NB + 1) * 4);
    int*   gcd    = (int*)alloc((size_t)3 * NB * 4);
    int*   gcs    = (int*)alloc((size_t)3 * NB * 4);
    float* bnsum  = (float*)alloc(256 * 4);
    // build-only buffers alias layer buffers (build completes before first use)
    int* dbuf = (int*)zB;                         // needs 3E*4 = 19.2MB <= 76.8MB
    unsigned char* sbuf = (unsigned char*)gcout;  // needs 3E = 4.8MB <= 25.6MB

    // ---- counting-sort CSR build ----
    hipMemsetAsync(chd, 0, (size_t)3 * NB * 4, stream);
    hipMemsetAsync(chs, 0, (size_t)3 * NB * 4, stream);
    dim3 cg2((E + CH - 1) / CH, 3);
    coarse_hist<<<cg2, 256, 0, stream>>>(src, dst, chd, chs, E, NB);
    scan_off<<<1, MAXNB, 0, stream>>>(chd, chs, offd, offs, gcd, gcs, rowptr, NB, N, E);
    scatter_coarse<<<cg2, 256, 0, stream>>>(src, dst, gcd, gcs, dbuf, sbuf, E, NB);
    dim3 fg(NB, 3);
    fine_src<<<fg, 256, 0, stream>>>(sbuf, offs, dro, E, N, NB);          // dro first
    fine_dst<<<fg, 256, 0, stream>>>(dbuf, offd, dro, esrcw, rowptr, dri, E, N, NB);

    // ---- weight packing + initial bf16 x ----
    pack_w<<<12, 256, 0, stream>>>(gcW0, gcW, fcW, Wg, Wf);
    const int cvtGrid = (N * 16 + 255) / 256;
    cvt_bf16<<<cvtGrid, 256, 0, stream>>>(x, h2, N * 16);

    // ---- layers ----
    const int gemmGrid = (N + 127) / 128;
    const float invn = 1.0f / (float)N;
    dim3 aggG((N * 16 + 255) / 256, 3);

    for (int l = 0; l < 3; ++l) {
        const float* bl = (l == 0) ? gcb0 : gcb + (size_t)(l - 1) * 3 * 128;
        if (l == 0)
            agg_kernel<0><<<aggG, 256, 0, stream>>>(h2, rowptr, esrcw, dri,
                                                    nullptr, nullptr, nullptr, invn,
                                                    zB, N, E);
        else
            agg_kernel<1><<<aggG, 256, 0, stream>>>(h2, rowptr, esrcw, dri,
                                                    bnsum, bng + (size_t)(l - 1) * 128,
                                                    bnb + (size_t)(l - 1) * 128, invn,
                                                    zB, N, E);
        mfma_gc<<<gemmGrid, 256, 0, stream>>>(zB, Wg + (size_t)l * 3 * 16384, bl, gcout, N);
        hipMemsetAsync(bnsum, 0, 256 * 4, stream);
        if (l < 2)
            mfma_fc<0><<<gemmGrid, 256, 0, stream>>>(gcout, Wf + (size_t)l * 16384,
                                                     fcb + (size_t)l * 128, h2, nullptr,
                                                     bnsum, N);
        else
            mfma_fc<1><<<gemmGrid, 256, 0, stream>>>(gcout, Wf + (size_t)l * 16384,
                                                     fcb + (size_t)l * 128, nullptr, out,
                                                     bnsum, N);
    }
    bn_apply<<<(N * 32 + 255) / 256, 256, 0, stream>>>(out, bnsum, bng + 2 * 128,
                                                       bnb + 2 * 128, invn, N * 32);
}

// Round 10
// 927.781 us; speedup vs baseline: 3.0099x; 1.0687x over previous
//
#include <hip/hip_runtime.h>

// ---------------------------------------------------------------------------
// Encoder: 3-layer HeteroGraphConv(3 edge types) -> FC -> ReLU -> BatchNorm
// Round 10: revert gather table to bf16 (int8 failed absmax by 8%); keep
// packed 4B edge records (12-bit edge weight, rel err 0.08%); NEW:
//   * agg: 16 row-loads in flight per lane (deeper MLP on the random gather)
//   * mfma_layer: gc GEMM + fc GEMM fused in one kernel; gcout tile passes
//     through swizzled LDS (no HBM round-trip, 2 fewer launches/layer)
// ---------------------------------------------------------------------------

#define EPSV 1e-5f
#define CH 4096      // edges per block in coarse passes
#define MAXNB 512    // max coarse bins (N <= 131072; also requires N < 2^20)

typedef __attribute__((ext_vector_type(8))) short s8v;   // 8 bf16 = 4 VGPR
typedef __attribute__((ext_vector_type(4))) float f4v;   // 4 f32 acc

// ---------------- build phase 1: coarse histograms (both keys) -------------
__global__ void coarse_hist(const int* __restrict__ src, const int* __restrict__ dst,
                            int* __restrict__ chd, int* __restrict__ chs,
                            int E, int NB) {
    __shared__ int hd[MAXNB], hs[MAXNB];
    int t = blockIdx.y;
    for (int i = threadIdx.x; i < MAXNB; i += 256) { hd[i] = 0; hs[i] = 0; }
    __syncthreads();
    int base = blockIdx.x * CH;
    int end = base + CH < E ? base + CH : E;
    const int* sp = src + (size_t)t * E;
    const int* dp = dst + (size_t)t * E;
    for (int i = base + threadIdx.x; i < end; i += 256) {
        atomicAdd(&hd[dp[i] >> 8], 1);
        atomicAdd(&hs[sp[i] >> 8], 1);
    }
    __syncthreads();
    for (int b = threadIdx.x; b < NB; b += 256) {
        if (hd[b]) atomicAdd(&chd[t * NB + b], hd[b]);
        if (hs[b]) atomicAdd(&chs[t * NB + b], hs[b]);
    }
}

// ---------------- build phase 2: scan coarse bins -> offsets + cursors -----
__global__ void scan_off(const int* __restrict__ chd, const int* __restrict__ chs,
                         int* __restrict__ offd, int* __restrict__ offs,
                         int* __restrict__ gcd, int* __restrict__ gcs,
                         int* __restrict__ rowptr, int NB, int N, int E) {
    __shared__ int s[MAXNB];
    int tid = threadIdx.x;
    for (int a = 0; a < 6; ++a) {
        const int* h = (a < 3) ? chd + a * NB : chs + (a - 3) * NB;
        int* off = (a < 3) ? offd + a * (NB + 1) : offs + (a - 3) * (NB + 1);
        int* gc = (a < 3) ? gcd + a * NB : gcs + (a - 3) * NB;
        s[tid] = (tid < NB) ? h[tid] : 0;
        __syncthreads();
        for (int o = 1; o < MAXNB; o <<= 1) {
            int v = (tid >= o) ? s[tid - o] : 0;
            __syncthreads();
            s[tid] += v;
            __syncthreads();
        }
        if (tid < NB) {
            off[tid + 1] = s[tid];
            if (tid == 0) off[0] = 0;
        }
        __syncthreads();
        if (tid < NB) gc[tid] = off[tid];
        __syncthreads();
    }
    if (tid < 3) rowptr[tid * (N + 1) + N] = E;
}

// ---------------- build phase 3: multi-split scatter (LDS reorder) ---------
__launch_bounds__(256)
__global__ void scatter_coarse(const int* __restrict__ src, const int* __restrict__ dst,
                               int* __restrict__ gcd, int* __restrict__ gcs,
                               int* __restrict__ dbuf, unsigned char* __restrict__ sbuf,
                               int E, int NB) {
    __shared__ int hd[MAXNB], hs[MAXNB];
    __shared__ int lod[MAXNB], los[MAXNB];
    __shared__ int bd[MAXNB], bs[MAXNB];
    __shared__ int rbi[CH];
    __shared__ unsigned char rbs[CH];
    const int tid = threadIdx.x;
    const int t = blockIdx.y;
    const int base = blockIdx.x * CH;
    const int end = base + CH < E ? base + CH : E;
    const int cnt = end - base;
    const int* sp = src + (size_t)t * E;
    const int* dp = dst + (size_t)t * E;

    for (int i = tid; i < MAXNB; i += 256) { hd[i] = 0; hs[i] = 0; }
    __syncthreads();
    for (int i = base + tid; i < end; i += 256) {
        atomicAdd(&hd[dp[i] >> 8], 1);
        atomicAdd(&hs[sp[i] >> 8], 1);
    }
    __syncthreads();
    for (int b = tid; b < NB; b += 256) {
        bd[b] = hd[b] ? atomicAdd(&gcd[t * NB + b], hd[b]) : 0;
        bs[b] = hs[b] ? atomicAdd(&gcs[t * NB + b], hs[b]) : 0;
    }
    lod[tid] = hd[tid]; lod[tid + 256] = hd[tid + 256];
    los[tid] = hs[tid]; los[tid + 256] = hs[tid + 256];
    __syncthreads();
    for (int o = 1; o < MAXNB; o <<= 1) {
        int a0 = lod[tid], a1 = lod[tid + 256];
        int b0 = los[tid], b1 = los[tid + 256];
        int p0 = (tid >= o) ? lod[tid - o] : 0;
        int p1 = lod[tid + 256 - o];
        int q0 = (tid >= o) ? los[tid - o] : 0;
        int q1 = los[tid + 256 - o];
        __syncthreads();
        lod[tid] = a0 + p0; lod[tid + 256] = a1 + p1;
        los[tid] = b0 + q0; los[tid + 256] = b1 + q1;
        __syncthreads();
    }
    hd[tid] = lod[tid] - hd[tid]; hd[tid + 256] = lod[tid + 256] - hd[tid + 256];
    hs[tid] = los[tid] - hs[tid]; hs[tid + 256] = los[tid + 256] - hs[tid + 256];
    __syncthreads();
    for (int i = base + tid; i < end; i += 256) {
        int sv = sp[i], dv = dp[i];
        int lp = atomicAdd(&hd[dv >> 8], 1);
        rbi[lp] = (sv << 8) | (dv & 255);
        int ls = atomicAdd(&hs[sv >> 8], 1);
        rbs[ls] = (unsigned char)(sv & 255);
    }
    __syncthreads();
    for (int i = tid; i < cnt; i += 256) {
        int lo = 0, hi = NB - 1;
        while (lo < hi) { int mid = (lo + hi) >> 1; if (lod[mid] > i) hi = mid; else lo = mid + 1; }
        int excl = lo ? lod[lo - 1] : 0;
        dbuf[(size_t)t * E + bd[lo] + (i - excl)] = rbi[i];
    }
    for (int i = tid; i < cnt; i += 256) {
        int lo = 0, hi = NB - 1;
        while (lo < hi) { int mid = (lo + hi) >> 1; if (los[mid] > i) hi = mid; else lo = mid + 1; }
        int excl = lo ? los[lo - 1] : 0;
        sbuf[(size_t)t * E + bs[lo] + (i - excl)] = rbs[i];
    }
}

// ---------------- build phase 4a: fine histogram by src -> dro (FIRST) -----
__global__ void fine_src(const unsigned char* __restrict__ sbuf, const int* __restrict__ offs,
                         float* __restrict__ dro, int E, int N, int NB) {
    __shared__ int h[256];
    int b = blockIdx.x, t = blockIdx.y;
    int tid = threadIdx.x;
    h[tid] = 0;
    __syncthreads();
    int beg = offs[t * (NB + 1) + b], end = offs[t * (NB + 1) + b + 1];
    const unsigned char* sp = sbuf + (size_t)t * E;
    for (int i = beg + tid; i < end; i += 256) atomicAdd(&h[sp[i]], 1);
    __syncthreads();
    int node = b * 256 + tid;
    if (node < N) {
        int dg = h[tid] < 1 ? 1 : h[tid];
        dro[(size_t)t * N + node] = rsqrtf((float)dg);
    }
}

// ---------------- build phase 4b: fine sort by dst -> records src|wq<<20 ---
#define FDCAP 6656
__global__ void fine_dst(const int* __restrict__ dbuf, const int* __restrict__ offd,
                         const float* __restrict__ dro, int* __restrict__ erec,
                         int* __restrict__ rowptr, float* __restrict__ dri,
                         int E, int N, int NB) {
    __shared__ int h[256], sc[256], cur[256];
    __shared__ int rb[FDCAP];
    int b = blockIdx.x, t = blockIdx.y;
    int tid = threadIdx.x;
    h[tid] = 0;
    __syncthreads();
    int beg = offd[t * (NB + 1) + b], end = offd[t * (NB + 1) + b + 1];
    int cnt = end - beg;
    const int* dp = dbuf + (size_t)t * E;
    const float* drt = dro + (size_t)t * N;
    for (int i = beg + tid; i < end; i += 256) atomicAdd(&h[dp[i] & 255], 1);
    __syncthreads();
    sc[tid] = h[tid];
    __syncthreads();
    for (int o = 1; o < 256; o <<= 1) {
        int v = (tid >= o) ? sc[tid - o] : 0;
        __syncthreads();
        sc[tid] += v;
        __syncthreads();
    }
    int excl = sc[tid] - h[tid];
    cur[tid] = excl;
    int node = b * 256 + tid;
    if (node < N) {
        rowptr[t * (N + 1) + node] = beg + excl;
        int dg = h[tid] < 1 ? 1 : h[tid];
        dri[(size_t)t * N + node] = rsqrtf((float)dg);
    }
    __syncthreads();
    if (cnt <= FDCAP) {
        for (int i = beg + tid; i < end; i += 256) {
            int v = dp[i];
            int p = atomicAdd(&cur[v & 255], 1);
            rb[p] = v >> 8;
        }
        __syncthreads();
        for (int i = tid; i < cnt; i += 256) {
            int sv = rb[i];
            int wq = (int)(drt[sv] * 4095.0f + 0.5f);   // 12-bit weight
            erec[(size_t)t * E + beg + i] = sv | (wq << 20);
        }
    } else {
        for (int i = beg + tid; i < end; i += 256) {
            int v = dp[i];
            int sv = v >> 8;
            int wq = (int)(drt[sv] * 4095.0f + 0.5f);
            int p = beg + atomicAdd(&cur[v & 255], 1);
            erec[(size_t)t * E + p] = sv | (wq << 20);
        }
    }
}

// ---------------- bf16 helpers ----------------
__device__ __forceinline__ unsigned int bfr(float f) {
    unsigned int u = __float_as_uint(f);
    return (u + 0x7FFFu + ((u >> 16) & 1u)) >> 16;   // RNE
}
__device__ __forceinline__ unsigned int pack2(float lo, float hi) {
    return bfr(lo) | (bfr(hi) << 16);
}
__device__ __forceinline__ float blo(unsigned int u) { return __uint_as_float(u << 16); }
__device__ __forceinline__ float bhi(unsigned int u) { return __uint_as_float(u & 0xFFFF0000u); }

// ---------------- fp32 -> bf16 convert (initial x copy) --------------------
__global__ void cvt_bf16(const float* __restrict__ h, unsigned short* __restrict__ h2,
                         int total8) {
    int i = blockIdx.x * 256 + threadIdx.x;
    if (i >= total8) return;
    const float4* hp = (const float4*)h + (size_t)i * 2;
    float4 v0 = hp[0], v1 = hp[1];
    uint4 o;
    o.x = pack2(v0.x, v0.y);
    o.y = pack2(v0.z, v0.w);
    o.z = pack2(v1.x, v1.y);
    o.w = pack2(v1.z, v1.w);
    ((uint4*)h2)[i] = o;
}

// ---------------- weight packing: fragment-ordered bf16 --------------------
__global__ void pack_w(const float* __restrict__ gcW0, const float* __restrict__ gcW,
                       const float* __restrict__ fcW, unsigned short* __restrict__ Wg,
                       unsigned short* __restrict__ Wf) {
    int mat = blockIdx.x;   // 0..8 = gc (l*3+e), 9..11 = fc layer
    const float* srcp;
    unsigned short* dstp;
    if (mat < 9) {
        int l = mat / 3, e = mat % 3;
        srcp = (l == 0) ? gcW0 + (size_t)e * 16384
                        : gcW + ((size_t)(l - 1) * 3 + e) * 16384;
        dstp = Wg + (size_t)mat * 16384;
    } else {
        srcp = fcW + (size_t)(mat - 9) * 16384;
        dstp = Wf + (size_t)(mat - 9) * 16384;
    }
    for (int p = threadIdx.x; p < 16384; p += 256) {
        int j = p & 7;
        int ln = (p >> 3) & 63;
        int nt = (p >> 9) & 7;
        int ks = p >> 12;
        int k = ks * 32 + (ln >> 4) * 8 + j;
        int n = nt * 16 + (ln & 15);
        dstp[p] = (unsigned short)bfr(srcp[k * 128 + n]);
    }
}

// ---------------- aggregation: bf16 gather, 16 rows in flight --------------
// 16 lanes/node, uint4 (8 bf16) per lane. Records = src | wq<<20 (w = wq/4095).
// AFF==1: input h2 is PRE-BN; BN affine folded via linearity (wacc term).
template <int AFF>
__launch_bounds__(256)
__global__ void agg_kernel(const unsigned short* __restrict__ h2, const int* __restrict__ rowptrB,
                           const int* __restrict__ erecB, const float* __restrict__ driB,
                           const float* __restrict__ bnsum, const float* __restrict__ gamma,
                           const float* __restrict__ beta, float invn,
                           unsigned short* __restrict__ zB, int N, int E) {
    __shared__ float lss[256];
    if (AFF) {
        int tid = threadIdx.x;
        if (tid < 128) {
            float mean = bnsum[tid] * invn;
            float var = bnsum[128 + tid] * invn - mean * mean;
            float sc = gamma[tid] * rsqrtf(var + EPSV);
            lss[tid] = sc;
            lss[128 + tid] = beta[tid] - mean * sc;
        }
        __syncthreads();
    }
    const int e = blockIdx.y;
    const int* rowptr = rowptrB + e * (N + 1);
    const int* erec = erecB + (size_t)e * E;
    const float* dri = driB + (size_t)e * N;
    unsigned short* z = zB + (size_t)e * N * 128;

    int idx = blockIdx.x * 256 + threadIdx.x;
    int node = idx >> 4;
    int lq = idx & 15;
    if (node >= N) return;
    int beg = rowptr[node], end = rowptr[node + 1];
    const uint4* hp = (const uint4*)h2 + lq;   // row s at hp[s*16]
    float a0 = 0.f, a1 = 0.f, a2 = 0.f, a3 = 0.f, a4 = 0.f, a5 = 0.f, a6 = 0.f, a7 = 0.f;
    float wacc = 0.f;
    const float IW = 1.0f / 4095.0f;

    int j = beg;
    for (; j + 16 <= end; j += 16) {
        int r[16];
#pragma unroll
        for (int q = 0; q < 16; ++q) r[q] = erec[j + q];
        uint4 u[16];
#pragma unroll
        for (int q = 0; q < 16; ++q) u[q] = hp[(size_t)(r[q] & 0xFFFFF) * 16];
#pragma unroll
        for (int q = 0; q < 16; ++q) {
            float w = (float)((unsigned)r[q] >> 20) * IW;
            if (AFF) wacc += w;
            a0 += w * blo(u[q].x); a1 += w * bhi(u[q].x);
            a2 += w * blo(u[q].y); a3 += w * bhi(u[q].y);
            a4 += w * blo(u[q].z); a5 += w * bhi(u[q].z);
            a6 += w * blo(u[q].w); a7 += w * bhi(u[q].w);
        }
    }
    for (; j + 4 <= end; j += 4) {
        int r[4];
#pragma unroll
        for (int q = 0; q < 4; ++q) r[q] = erec[j + q];
        uint4 u[4];
#pragma unroll
        for (int q = 0; q < 4; ++q) u[q] = hp[(size_t)(r[q] & 0xFFFFF) * 16];
#pragma unroll
        for (int q = 0; q < 4; ++q) {
            float w = (float)((unsigned)r[q] >> 20) * IW;
            if (AFF) wacc += w;
            a0 += w * blo(u[q].x); a1 += w * bhi(u[q].x);
            a2 += w * blo(u[q].y); a3 += w * bhi(u[q].y);
            a4 += w * blo(u[q].z); a5 += w * bhi(u[q].z);
            a6 += w * blo(u[q].w); a7 += w * bhi(u[q].w);
        }
    }
    for (; j < end; ++j) {
        int r0 = erec[j];
        float w = (float)((unsigned)r0 >> 20) * IW;
        if (AFF) wacc += w;
        uint4 u0 = hp[(size_t)(r0 & 0xFFFFF) * 16];
        a0 += w * blo(u0.x); a1 += w * bhi(u0.x);
        a2 += w * blo(u0.y); a3 += w * bhi(u0.y);
        a4 += w * blo(u0.z); a5 += w * bhi(u0.z);
        a6 += w * blo(u0.w); a7 += w * bhi(u0.w);
    }
    float scl = dri[node];
    if (AFF) {
        const float* ap = &lss[lq * 8];
        const float* bp = &lss[128 + lq * 8];
        a0 = ap[0] * a0 + bp[0] * wacc;
        a1 = ap[1] * a1 + bp[1] * wacc;
        a2 = ap[2] * a2 + bp[2] * wacc;
        a3 = ap[3] * a3 + bp[3] * wacc;
        a4 = ap[4] * a4 + bp[4] * wacc;
        a5 = ap[5] * a5 + bp[5] * wacc;
        a6 = ap[6] * a6 + bp[6] * wacc;
        a7 = ap[7] * a7 + bp[7] * wacc;
    }
    uint4 o;
    o.x = pack2(a0 * scl, a1 * scl);
    o.y = pack2(a2 * scl, a3 * scl);
    o.z = pack2(a4 * scl, a5 * scl);
    o.w = pack2(a6 * scl, a7 * scl);
    ((uint4*)z)[(size_t)node * 16 + lq] = o;
}

// ---------------- fused layer GEMM: gc (K=384) -> LDS -> fc + ReLU + BN ----
// gcout tile lives in swizzled LDS (chunk' = chunk ^ (row&15), 16B chunks).
// MODE 0: write bf16 pre-BN h into outb; MODE 1: write fp32 into outf.
template <int MODE>
__launch_bounds__(256)
__global__ void mfma_layer(const unsigned short* __restrict__ zB,
                           const unsigned short* __restrict__ Wgp,
                           const float* __restrict__ b3,
                           const unsigned short* __restrict__ Wfp,
                           const float* __restrict__ fcb,
                           unsigned short* __restrict__ outb, float* __restrict__ outf,
                           float* __restrict__ bnsum, int M) {
    __shared__ unsigned short T[128 * 128];   // swizzled gcout tile (32KB)
    __shared__ float red[256];
    const int tid = threadIdx.x;
    const int l = tid & 63;
    const int wv = tid >> 6;
    const int wm = wv >> 1, wn = wv & 1;
    const int m0 = blockIdx.x * 128;
    const int lr = l & 15;
    const int lk = (l >> 4) * 8;

    int rowb[4];
#pragma unroll
    for (int mt = 0; mt < 4; ++mt) {
        int r = m0 + wm * 64 + mt * 16 + lr;
        rowb[mt] = (r < M) ? r : (M - 1);
    }

    // ---- phase 1: gcout = [z0|z1|z2] @ Wg + sum(bias) ----
    {
        f4v acc[4][4];
#pragma unroll
        for (int i = 0; i < 4; ++i)
#pragma unroll
            for (int j = 0; j < 4; ++j) acc[i][j] = (f4v){0.f, 0.f, 0.f, 0.f};
#pragma unroll
        for (int e = 0; e < 3; ++e) {
            const unsigned short* zp = zB + (size_t)e * M * 128;
            const unsigned short* wp = Wgp + (size_t)e * 16384;
#pragma unroll
            for (int ks = 0; ks < 4; ++ks) {
                s8v a[4], b[4];
#pragma unroll
                for (int mt = 0; mt < 4; ++mt)
                    a[mt] = *(const s8v*)(zp + (size_t)rowb[mt] * 128 + ks * 32 + lk);
#pragma unroll
                for (int nt = 0; nt < 4; ++nt)
                    b[nt] = *(const s8v*)(wp + ks * 4096 + (wn * 4 + nt) * 512 + l * 8);
#pragma unroll
                for (int mt = 0; mt < 4; ++mt)
#pragma unroll
                    for (int nt = 0; nt < 4; ++nt)
                        acc[mt][nt] = __builtin_amdgcn_mfma_f32_16x16x32_bf16(
                            a[mt], b[nt], acc[mt][nt], 0, 0, 0);
            }
        }
        float bs[4];
        int col[4];
#pragma unroll
        for (int nt = 0; nt < 4; ++nt) {
            col[nt] = wn * 64 + nt * 16 + lr;
            bs[nt] = b3[col[nt]] + b3[128 + col[nt]] + b3[256 + col[nt]];
        }
        // write tile to swizzled LDS (all local rows, even M-clamped ones)
#pragma unroll
        for (int mt = 0; mt < 4; ++mt) {
#pragma unroll
            for (int r = 0; r < 4; ++r) {
                int rl = wm * 64 + mt * 16 + (l >> 4) * 4 + r;
#pragma unroll
                for (int nt = 0; nt < 4; ++nt) {
                    int c = col[nt];
                    int chunk = (c >> 3) ^ (rl & 15);
                    T[rl * 128 + chunk * 8 + (c & 7)] =
                        (unsigned short)bfr(acc[mt][nt][r] + bs[nt]);
                }
            }
        }
    }
    __syncthreads();

    // ---- phase 2: h = relu(gcout @ Wf + fcb), BN stats ----
    f4v acc2[4][4];
#pragma unroll
    for (int i = 0; i < 4; ++i)
#pragma unroll
        for (int j = 0; j < 4; ++j) acc2[i][j] = (f4v){0.f, 0.f, 0.f, 0.f};
#pragma unroll
    for (int ks = 0; ks < 4; ++ks) {
        s8v a[4], b[4];
#pragma unroll
        for (int mt = 0; mt < 4; ++mt) {
            int rl = wm * 64 + mt * 16 + lr;
            int chunk = (ks * 4 + (l >> 4)) ^ lr;   // rl & 15 == lr
            a[mt] = *(const s8v*)&T[rl * 128 + chunk * 8];
        }
#pragma unroll
        for (int nt = 0; nt < 4; ++nt)
            b[nt] = *(const s8v*)(Wfp + ks * 4096 + (wn * 4 + nt) * 512 + l * 8);
#pragma unroll
        for (int mt = 0; mt < 4; ++mt)
#pragma unroll
            for (int nt = 0; nt < 4; ++nt)
                acc2[mt][nt] = __builtin_amdgcn_mfma_f32_16x16x32_bf16(
                    a[mt], b[nt], acc2[mt][nt], 0, 0, 0);
    }

    float bv[4], cs[4] = {}, cq[4] = {};
    int col[4];
#pragma unroll
    for (int nt = 0; nt < 4; ++nt) {
        col[nt] = wn * 64 + nt * 16 + lr;
        bv[nt] = fcb[col[nt]];
    }
#pragma unroll
    for (int mt = 0; mt < 4; ++mt) {
#pragma unroll
        for (int r = 0; r < 4; ++r) {
            int row = m0 + wm * 64 + mt * 16 + (l >> 4) * 4 + r;
            if (row < M) {
#pragma unroll
                for (int nt = 0; nt < 4; ++nt) {
                    float v = acc2[mt][nt][r] + bv[nt];
                    v = v > 0.f ? v : 0.f;
                    cs[nt] += v;
                    cq[nt] += v * v;
                    if (MODE == 0)
                        outb[(size_t)row * 128 + col[nt]] = (unsigned short)bfr(v);
                    else
                        outf[(size_t)row * 128 + col[nt]] = v;
                }
            }
        }
    }
    red[tid] = 0.f;
    __syncthreads();
#pragma unroll
    for (int nt = 0; nt < 4; ++nt) {
        atomicAdd(&red[col[nt]], cs[nt]);
        atomicAdd(&red[128 + col[nt]], cq[nt]);
    }
    __syncthreads();
    if (tid < 128) {
        atomicAdd(&bnsum[tid], red[tid]);
        atomicAdd(&bnsum[128 + tid], red[128 + tid]);
    }
}

// ---------------- final BN apply (fp32 out) --------------------------------
__global__ void bn_apply(float* __restrict__ h, const float* __restrict__ bnsum,
                         const float* __restrict__ gamma, const float* __restrict__ beta,
                         float invn, int total4) {
    __shared__ float lss[256];
    int tid = threadIdx.x;
    if (tid < 128) {
        float mean = bnsum[tid] * invn;
        float var = bnsum[128 + tid] * invn - mean * mean;
        float sc = gamma[tid] * rsqrtf(var + EPSV);
        lss[tid] = sc;
        lss[128 + tid] = beta[tid] - mean * sc;
    }
    __syncthreads();
    int i = blockIdx.x * 256 + tid;
    if (i >= total4) return;
    int c4 = (i & 31) * 4;
    float4 sc = *(const float4*)&lss[c4];
    float4 sh = *(const float4*)&lss[128 + c4];
    float4 v = ((float4*)h)[i];
    v.x = v.x * sc.x + sh.x;
    v.y = v.y * sc.y + sh.y;
    v.z = v.z * sc.z + sh.z;
    v.w = v.w * sc.w + sh.w;
    ((float4*)h)[i] = v;
}

// ---------------------------------------------------------------------------
extern "C" void kernel_launch(void* const* d_in, const int* in_sizes, int n_in,
                              void* d_out, int out_size, void* d_ws, size_t ws_size,
                              hipStream_t stream) {
    const float* x    = (const float*)d_in[0];
    const int*   src  = (const int*)d_in[1];
    const int*   dst  = (const int*)d_in[2];
    const float* gcW0 = (const float*)d_in[3];
    const float* gcb0 = (const float*)d_in[4];
    const float* gcW  = (const float*)d_in[5];
    const float* gcb  = (const float*)d_in[6];
    const float* fcW  = (const float*)d_in[7];
    const float* fcb  = (const float*)d_in[8];
    const float* bng  = (const float*)d_in[9];
    const float* bnb  = (const float*)d_in[10];
    float* out = (float*)d_out;

    const int N = in_sizes[0] / 128;
    const int E = in_sizes[1] / 3;
    const int NB = (N + 255) / 256;   // <= MAXNB for this problem size

    char* w = (char*)d_ws;
    auto alloc = [&](size_t bytes) -> char* {
        char* p = w;
        w += (bytes + 255) & ~(size_t)255;
        return p;
    };
    unsigned short* zB    = (unsigned short*)alloc((size_t)3 * N * 128 * 2);  // z0|z1|z2
    unsigned short* h2    = (unsigned short*)alloc((size_t)N * 128 * 2);
    unsigned short* Wg    = (unsigned short*)alloc((size_t)9 * 16384 * 2);
    unsigned short* Wf    = (unsigned short*)alloc((size_t)3 * 16384 * 2);
    int*   erec   = (int*)alloc((size_t)3 * E * 4);
    int*   rowptr = (int*)alloc((size_t)3 * (N + 1) * 4);
    float* dro    = (float*)alloc((size_t)3 * N * 4);
    float* dri    = (float*)alloc((size_t)3 * N * 4);
    int*   chd    = (int*)alloc((size_t)3 * NB * 4);
    int*   chs    = (int*)alloc((size_t)3 * NB * 4);
    int*   offd   = (int*)alloc((size_t)3 * (NB + 1) * 4);
    int*   offs   = (int*)alloc((size_t)3 * (NB + 1) * 4);
    int*   gcd    = (int*)alloc((size_t)3 * NB * 4);
    int*   gcs    = (int*)alloc((size_t)3 * NB * 4);
    float* bnsum  = (float*)alloc(256 * 4);
    // build-only buffers alias zB (build completes before agg writes zB)
    int* dbuf = (int*)zB;                                  // 3E*4 = 19.2MB
    unsigned char* sbuf = (unsigned char*)(dbuf + (size_t)3 * E);  // 3E = 4.8MB (total 24MB <= 76.8MB)

    // ---- counting-sort CSR build ----
    hipMemsetAsync(chd, 0, (size_t)3 * NB * 4, stream);
    hipMemsetAsync(chs, 0, (size_t)3 * NB * 4, stream);
    dim3 cg2((E + CH - 1) / CH, 3);
    coarse_hist<<<cg2, 256, 0, stream>>>(src, dst, chd, chs, E, NB);
    scan_off<<<1, MAXNB, 0, stream>>>(chd, chs, offd, offs, gcd, gcs, rowptr, NB, N, E);
    scatter_coarse<<<cg2, 256, 0, stream>>>(src, dst, gcd, gcs, dbuf, sbuf, E, NB);
    dim3 fg(NB, 3);
    fine_src<<<fg, 256, 0, stream>>>(sbuf, offs, dro, E, N, NB);          // dro first
    fine_dst<<<fg, 256, 0, stream>>>(dbuf, offd, dro, erec, rowptr, dri, E, N, NB);

    // ---- weight packing + initial bf16 x ----
    pack_w<<<12, 256, 0, stream>>>(gcW0, gcW, fcW, Wg, Wf);
    const int cvtGrid = (N * 16 + 255) / 256;
    cvt_bf16<<<cvtGrid, 256, 0, stream>>>(x, h2, N * 16);

    // ---- layers ----
    const int gemmGrid = (N + 127) / 128;
    const float invn = 1.0f / (float)N;
    dim3 aggG((N * 16 + 255) / 256, 3);

    for (int l = 0; l < 3; ++l) {
        const float* bl = (l == 0) ? gcb0 : gcb + (size_t)(l - 1) * 3 * 128;
        if (l == 0)
            agg_kernel<0><<<aggG, 256, 0, stream>>>(h2, rowptr, erec, dri,
                                                    nullptr, nullptr, nullptr, invn,
                                                    zB, N, E);
        else
            agg_kernel<1><<<aggG, 256, 0, stream>>>(h2, rowptr, erec, dri,
                                                    bnsum, bng + (size_t)(l - 1) * 128,
                                                    bnb + (size_t)(l - 1) * 128, invn,
                                                    zB, N, E);
        hipMemsetAsync(bnsum, 0, 256 * 4, stream);
        if (l < 2)
            mfma_layer<0><<<gemmGrid, 256, 0, stream>>>(zB, Wg + (size_t)l * 3 * 16384, bl,
                                                        Wf + (size_t)l * 16384,
                                                        fcb + (size_t)l * 128,
                                                        h2, nullptr, bnsum, N);
        else
            mfma_layer<1><<<gemmGrid, 256, 0, stream>>>(zB, Wg + (size_t)l * 3 * 16384, bl,
                                                        Wf + (size_t)l * 16384,
                                                        fcb + (size_t)l * 128,
                                                        nullptr, out, bnsum, N);
    }
    bn_apply<<<(N * 32 + 255) / 256, 256, 0, stream>>>(out, bnsum, bng + 2 * 128,
                                                       bnb + 2 * 128, invn, N * 32);
}